// Round 2
// baseline (11983.213 us; speedup 1.0000x reference)
//
#include <hip/hip_runtime.h>
#include <hip/hip_bf16.h>

// GraphSAGE decoder, 4 layers. fp32 baseline, workspace-lean (~205 MB peak).
// Identity used: segment_sum(x[src]) @ W == segment_sum((x@W)[src]),
// so we aggregate over whichever of {Din, Dout} is smaller per layer:
//   L1: agg 128-d (before GEMM), L2: 256-d, L3: 128-d (after GEMM), L4: 9-d (after GEMM).
// Layer-2 GEMM is in-place over the agg buffer (full-width BN=256 tile: each
// block owns its rows entirely -> no cross-block read/write race).

#define EPS 1e-5f

// ---------------- zero fill (replaces hipMemsetAsync) ----------------
__global__ __launch_bounds__(256) void zero_f4(float4* __restrict__ p, int n4) {
    int i = blockIdx.x * 256 + threadIdx.x;
    if (i < n4) p[i] = make_float4(0.f, 0.f, 0.f, 0.f);
}

// ---------------- degree / inverse count ----------------
__global__ __launch_bounds__(256) void count_edges(const int* __restrict__ dst,
                                                   float* __restrict__ cnt, int E) {
    int e = blockIdx.x * 256 + threadIdx.x;
    if (e < E) atomicAdd(&cnt[dst[e]], 1.0f);
}

__global__ __launch_bounds__(256) void invert_counts(float* __restrict__ cnt, int N) {
    int i = blockIdx.x * 256 + threadIdx.x;
    if (i < N) cnt[i] = 1.0f / fmaxf(cnt[i], 1.0f);
}

// ---------------- scatter-add aggregation (float4 per thread) ----------------
template <int LOGDV>  // Dv = D/4 float4 lanes per edge
__global__ __launch_bounds__(256) void scatter_add(const float* __restrict__ x,
                                                   const int* __restrict__ src,
                                                   const int* __restrict__ dst,
                                                   float* __restrict__ agg, int E) {
    const int Dv = 1 << LOGDV;
    long t = (long)blockIdx.x * 256 + threadIdx.x;
    int e = (int)(t >> LOGDV);
    int c = (int)(t & (Dv - 1));
    if (e >= E) return;
    int s = src[e], d = dst[e];
    float4 v = ((const float4*)x)[(long)s * Dv + c];
    float* o = &agg[((long)d * Dv + c) * 4];
    atomicAdd(o + 0, v.x);
    atomicAdd(o + 1, v.y);
    atomicAdd(o + 2, v.z);
    atomicAdd(o + 3, v.w);
}

__global__ __launch_bounds__(256) void scatter_add9(const float* __restrict__ x,
                                                    const int* __restrict__ src,
                                                    const int* __restrict__ dst,
                                                    float* __restrict__ agg, int E) {
    long t = (long)blockIdx.x * 256 + threadIdx.x;
    int e = (int)(t >> 4);
    int c = (int)(t & 15);
    if (e >= E || c >= 9) return;
    int s = src[e], d = dst[e];
    atomicAdd(&agg[(long)d * 9 + c], x[(long)s * 9 + c]);
}

// ---------------- tiled fp32 GEMM: out = (A1*inv?)@W1 [+ A2@W2] + bias ----------------
// BM=64, BN=64, BK=16, 256 threads, 4x4 per thread. out must NOT alias inputs.
__global__ __launch_bounds__(256) void sage_gemm(const float* __restrict__ A1,
                                                 const float* __restrict__ A2,
                                                 const float* __restrict__ W1,
                                                 const float* __restrict__ W2,
                                                 const float* __restrict__ bias,
                                                 const float* __restrict__ invc,
                                                 float* __restrict__ out, int M, int K,
                                                 int Dout, int two_pass, int scale_first) {
    __shared__ float As[16][68];
    __shared__ float Ws[16][68];
    const int tid = threadIdx.x;
    const int bm = blockIdx.x * 64;
    const int bn = blockIdx.y * 64;
    const int tr = (tid / 16) * 4;
    const int tc = (tid % 16) * 4;
    const int lr = tid / 4;
    const int lk = (tid % 4) * 4;
    const int wk = tid / 16;
    const int wn = (tid % 16) * 4;

    float acc[4][4] = {};
    const int npass = two_pass ? 2 : 1;
    for (int pass = 0; pass < npass; ++pass) {
        const float* A = pass ? A2 : A1;
        const float* W = pass ? W2 : W1;
        const bool scale = (pass == 0) && scale_first;
        for (int k0 = 0; k0 < K; k0 += 16) {
            int gm = bm + lr;
            float4 av = make_float4(0.f, 0.f, 0.f, 0.f);
            if (gm < M) {
                av = *(const float4*)&A[(long)gm * K + k0 + lk];
                if (scale) {
                    float s = invc[gm];
                    av.x *= s; av.y *= s; av.z *= s; av.w *= s;
                }
            }
            As[lk + 0][lr] = av.x;
            As[lk + 1][lr] = av.y;
            As[lk + 2][lr] = av.z;
            As[lk + 3][lr] = av.w;
            *(float4*)&Ws[wk][wn] = *(const float4*)&W[(long)(k0 + wk) * Dout + bn + wn];
            __syncthreads();
#pragma unroll
            for (int kk = 0; kk < 16; ++kk) {
                float4 a = *(const float4*)&As[kk][tr];
                float4 w = *(const float4*)&Ws[kk][tc];
                acc[0][0] += a.x * w.x; acc[0][1] += a.x * w.y; acc[0][2] += a.x * w.z; acc[0][3] += a.x * w.w;
                acc[1][0] += a.y * w.x; acc[1][1] += a.y * w.y; acc[1][2] += a.y * w.z; acc[1][3] += a.y * w.w;
                acc[2][0] += a.z * w.x; acc[2][1] += a.z * w.y; acc[2][2] += a.z * w.z; acc[2][3] += a.z * w.w;
                acc[3][0] += a.w * w.x; acc[3][1] += a.w * w.y; acc[3][2] += a.w * w.z; acc[3][3] += a.w * w.w;
            }
            __syncthreads();
        }
    }
    float4 bv = make_float4(0.f, 0.f, 0.f, 0.f);
    if (bias) bv = *(const float4*)&bias[bn + tc];
#pragma unroll
    for (int i = 0; i < 4; ++i) {
        int gm = bm + tr + i;
        if (gm < M) {
            float4 o;
            o.x = acc[i][0] + bv.x;
            o.y = acc[i][1] + bv.y;
            o.z = acc[i][2] + bv.z;
            o.w = acc[i][3] + bv.w;
            *(float4*)&out[(long)gm * Dout + bn + tc] = o;
        }
    }
}

// ---------------- wide in-place GEMM: out = (A1*inv)@W1 + A2@W2 + bias ----------------
// BM=32, BN=256(=Dout), BK=16, 256 threads, 4x8 per thread.
// out MAY alias A1: each block owns rows [bm,bm+32) end-to-end; writes happen
// only in the epilogue after all K reads.
__global__ __launch_bounds__(256) void sage_gemm_wide(const float* A1,
                                                      const float* __restrict__ A2,
                                                      const float* __restrict__ W1,
                                                      const float* __restrict__ W2,
                                                      const float* __restrict__ bias,
                                                      const float* __restrict__ invc,
                                                      float* out, int M, int K) {
    __shared__ float As[16][36];
    __shared__ float Ws[16][260];
    const int tid = threadIdx.x;
    const int bm = blockIdx.x * 32;
    const int tr = (tid >> 5) * 4;   // 0..28
    const int tc = (tid & 31) * 8;   // 0..248
    const int lr = tid >> 3;         // 0..31
    const int lk = (tid & 7) * 2;    // 0..14
    const int wk = tid >> 6;         // 0..3
    const int wn = (tid & 63) * 4;   // 0..252

    float acc[4][8] = {};
    for (int pass = 0; pass < 2; ++pass) {
        const float* A = pass ? A2 : A1;
        const float* W = pass ? W2 : W1;
        const bool scale = (pass == 0);
        for (int k0 = 0; k0 < K; k0 += 16) {
            int gm = bm + lr;
            float2 av = make_float2(0.f, 0.f);
            if (gm < M) {
                av = *(const float2*)&A[(long)gm * K + k0 + lk];
                if (scale) { float s = invc[gm]; av.x *= s; av.y *= s; }
            }
            As[lk + 0][lr] = av.x;
            As[lk + 1][lr] = av.y;
#pragma unroll
            for (int j = 0; j < 4; ++j) {
                *(float4*)&Ws[wk * 4 + j][wn] =
                    *(const float4*)&W[(long)(k0 + wk * 4 + j) * 256 + wn];
            }
            __syncthreads();
#pragma unroll
            for (int kk = 0; kk < 16; ++kk) {
                float4 a = *(const float4*)&As[kk][tr];
                float4 w0 = *(const float4*)&Ws[kk][tc];
                float4 w1 = *(const float4*)&Ws[kk][tc + 4];
                acc[0][0] += a.x * w0.x; acc[0][1] += a.x * w0.y; acc[0][2] += a.x * w0.z; acc[0][3] += a.x * w0.w;
                acc[0][4] += a.x * w1.x; acc[0][5] += a.x * w1.y; acc[0][6] += a.x * w1.z; acc[0][7] += a.x * w1.w;
                acc[1][0] += a.y * w0.x; acc[1][1] += a.y * w0.y; acc[1][2] += a.y * w0.z; acc[1][3] += a.y * w0.w;
                acc[1][4] += a.y * w1.x; acc[1][5] += a.y * w1.y; acc[1][6] += a.y * w1.z; acc[1][7] += a.y * w1.w;
                acc[2][0] += a.z * w0.x; acc[2][1] += a.z * w0.y; acc[2][2] += a.z * w0.z; acc[2][3] += a.z * w0.w;
                acc[2][4] += a.z * w1.x; acc[2][5] += a.z * w1.y; acc[2][6] += a.z * w1.z; acc[2][7] += a.z * w1.w;
                acc[3][0] += a.w * w0.x; acc[3][1] += a.w * w0.y; acc[3][2] += a.w * w0.z; acc[3][3] += a.w * w0.w;
                acc[3][4] += a.w * w1.x; acc[3][5] += a.w * w1.y; acc[3][6] += a.w * w1.z; acc[3][7] += a.w * w1.w;
            }
            __syncthreads();
        }
    }
    float4 bv0 = *(const float4*)&bias[tc];
    float4 bv1 = *(const float4*)&bias[tc + 4];
#pragma unroll
    for (int i = 0; i < 4; ++i) {
        int gm = bm + tr + i;
        if (gm < M) {
            float4 o0, o1;
            o0.x = acc[i][0] + bv0.x; o0.y = acc[i][1] + bv0.y;
            o0.z = acc[i][2] + bv0.z; o0.w = acc[i][3] + bv0.w;
            o1.x = acc[i][4] + bv1.x; o1.y = acc[i][5] + bv1.y;
            o1.z = acc[i][6] + bv1.z; o1.w = acc[i][7] + bv1.w;
            *(float4*)&out[(long)gm * 256 + tc] = o0;
            *(float4*)&out[(long)gm * 256 + tc + 4] = o1;
        }
    }
}

// ---------------- LayerNorm + ReLU, one 64-lane wave per row, in place ----------------
template <int D>
__global__ __launch_bounds__(256) void ln_relu(float* __restrict__ h, const float* __restrict__ g,
                                               const float* __restrict__ be, int M) {
    constexpr int PER = D / 64;
    int wave = threadIdx.x >> 6;
    int lane = threadIdx.x & 63;
    int row = blockIdx.x * 4 + wave;
    if (row >= M) return;
    float* p = &h[(long)row * D + lane * PER];
    float v[PER];
    if constexpr (PER == 4) {
        float4 ld = *(const float4*)p;
        v[0] = ld.x; v[1] = ld.y; v[2] = ld.z; v[3] = ld.w;
    } else {
        float2 ld = *(const float2*)p;
        v[0] = ld.x; v[1] = ld.y;
    }
    float s = 0.f, ss = 0.f;
#pragma unroll
    for (int i = 0; i < PER; ++i) { s += v[i]; ss += v[i] * v[i]; }
#pragma unroll
    for (int m = 32; m >= 1; m >>= 1) {
        s += __shfl_xor(s, m);
        ss += __shfl_xor(ss, m);
    }
    float mean = s / D;
    float var = ss / D - mean * mean;
    float rs = rsqrtf(var + EPS);
#pragma unroll
    for (int i = 0; i < PER; ++i) {
        int col = lane * PER + i;
        float y = (v[i] - mean) * rs * g[col] + be[col];
        v[i] = fmaxf(y, 0.f);
    }
    if constexpr (PER == 4) {
        *(float4*)p = make_float4(v[0], v[1], v[2], v[3]);
    } else {
        *(float2*)p = make_float2(v[0], v[1]);
    }
}

// ---------------- h3 = relu(LN(agg*inv + r3)), D=128 ----------------
__global__ __launch_bounds__(256) void add_ln_relu128(const float* __restrict__ agg,
                                                      const float* __restrict__ invc,
                                                      const float* __restrict__ r,
                                                      const float* __restrict__ g,
                                                      const float* __restrict__ be,
                                                      float* __restrict__ out, int M) {
    int wave = threadIdx.x >> 6;
    int lane = threadIdx.x & 63;
    int row = blockIdx.x * 4 + wave;
    if (row >= M) return;
    long base = (long)row * 128 + lane * 2;
    float2 a = *(const float2*)&agg[base];
    float2 rr = *(const float2*)&r[base];
    float iv = invc[row];
    float v[2] = {a.x * iv + rr.x, a.y * iv + rr.y};
    float s = v[0] + v[1], ss = v[0] * v[0] + v[1] * v[1];
#pragma unroll
    for (int m = 32; m >= 1; m >>= 1) {
        s += __shfl_xor(s, m);
        ss += __shfl_xor(ss, m);
    }
    float mean = s / 128.f;
    float var = ss / 128.f - mean * mean;
    float rs = rsqrtf(var + EPS);
#pragma unroll
    for (int i = 0; i < 2; ++i) {
        int col = lane * 2 + i;
        float y = (v[i] - mean) * rs * g[col] + be[col];
        v[i] = fmaxf(y, 0.f);
    }
    *(float2*)&out[base] = make_float2(v[0], v[1]);
}

// ---------------- layer 4 small GEMM: y = x@wm (Nx9), r = x@wr + b (Nx9) ----------------
__global__ __launch_bounds__(320) void gemm4(const float* __restrict__ x,
                                             const float* __restrict__ wm,
                                             const float* __restrict__ wrt,
                                             const float* __restrict__ b,
                                             float* __restrict__ y, float* __restrict__ r,
                                             int M) {
    __shared__ float xs[16][132];
    __shared__ float ws[128][20];
    int tid = threadIdx.x;
    int m0 = blockIdx.x * 16;
    for (int idx = tid; idx < 16 * 128; idx += 320) {
        int rr = idx >> 7, kk = idx & 127;
        int gm = m0 + rr;
        xs[rr][kk] = (gm < M) ? x[(long)gm * 128 + kk] : 0.f;
    }
    for (int idx = tid; idx < 128 * 18; idx += 320) {
        int kk = idx / 18, cc = idx % 18;
        ws[kk][cc] = (cc < 9) ? wm[kk * 9 + cc] : wrt[kk * 9 + cc - 9];
    }
    __syncthreads();
    if (tid < 288) {
        int rr = tid / 18, cc = tid % 18;
        float acc = 0.f;
#pragma unroll 8
        for (int kk = 0; kk < 128; ++kk) acc += xs[rr][kk] * ws[kk][cc];
        int gm = m0 + rr;
        if (gm < M) {
            if (cc < 9) y[(long)gm * 9 + cc] = acc;
            else r[(long)gm * 9 + cc - 9] = acc + b[cc - 9];
        }
    }
}

// ---------------- final: out = agg*inv + r4 ----------------
__global__ __launch_bounds__(256) void final_add(const float* __restrict__ agg,
                                                 const float* __restrict__ invc,
                                                 const float* __restrict__ r,
                                                 float* __restrict__ out, int total) {
    int idx = blockIdx.x * 256 + threadIdx.x;
    if (idx >= total) return;
    int row = idx / 9;
    out[idx] = agg[idx] * invc[row] + r[idx];
}

static inline int cdiv(long a, long b) { return (int)((a + b - 1) / b); }

extern "C" void kernel_launch(void* const* d_in, const int* in_sizes, int n_in,
                              void* d_out, int out_size, void* d_ws, size_t ws_size,
                              hipStream_t stream) {
    const int N = in_sizes[0] / 128;
    const int E = in_sizes[1] / 2;

    const float* z = (const float*)d_in[0];
    const int* ei = (const int*)d_in[1];
    const int* src = ei;
    const int* dstp = ei + E;
    const float* wm1 = (const float*)d_in[2];
    const float* wr1 = (const float*)d_in[3];
    const float* b1 = (const float*)d_in[4];
    const float* g1 = (const float*)d_in[5];
    const float* be1 = (const float*)d_in[6];
    const float* wm2 = (const float*)d_in[7];
    const float* wr2 = (const float*)d_in[8];
    const float* b2 = (const float*)d_in[9];
    const float* g2 = (const float*)d_in[10];
    const float* be2 = (const float*)d_in[11];
    const float* wm3 = (const float*)d_in[12];
    const float* wr3 = (const float*)d_in[13];
    const float* b3 = (const float*)d_in[14];
    const float* g3 = (const float*)d_in[15];
    const float* be3 = (const float*)d_in[16];
    const float* wm4 = (const float*)d_in[17];
    const float* wr4 = (const float*)d_in[18];
    const float* b4 = (const float*)d_in[19];
    float* out = (float*)d_out;

    // workspace (floats): inv[N] | bufA[N*256] | bufB[N*256]   (~205.2 MB peak)
    float* W = (float*)d_ws;
    float* inv = W;
    float* bufA = W + N;
    float* bufB = bufA + (size_t)N * 256;

    // ---- degrees ----
    zero_f4<<<cdiv(N / 4, 256), 256, 0, stream>>>((float4*)inv, N / 4);
    count_edges<<<cdiv(E, 256), 256, 0, stream>>>(dstp, inv, E);
    invert_counts<<<cdiv(N, 256), 256, 0, stream>>>(inv, N);

    // ---- layer 1: agg z (128-d, into bufB) -> h1(bufA) = relu(LN(mean@wm1 + z@wr1 + b1)) ----
    float* agg1 = bufB;
    zero_f4<<<cdiv((long)N * 32, 256), 256, 0, stream>>>((float4*)agg1, N * 32);
    scatter_add<5><<<cdiv((long)E * 32, 256), 256, 0, stream>>>(z, src, dstp, agg1, E);
    float* h1 = bufA;
    {
        dim3 g(cdiv(N, 64), 4);
        sage_gemm<<<g, 256, 0, stream>>>(agg1, z, wm1, wr1, b1, inv, h1, N, 128, 256, 1, 1);
    }
    ln_relu<256><<<cdiv(N, 4), 256, 0, stream>>>(h1, g1, be1, N);

    // ---- layer 2: agg h1 (256-d, into bufB); in-place GEMM bufB -> h2(bufB) ----
    float* agg2 = bufB;
    zero_f4<<<cdiv((long)N * 64, 256), 256, 0, stream>>>((float4*)agg2, N * 64);
    scatter_add<6><<<cdiv((long)E * 64, 256), 256, 0, stream>>>(h1, src, dstp, agg2, E);
    float* h2 = bufB;
    sage_gemm_wide<<<cdiv(N, 32), 256, 0, stream>>>(agg2, h1, wm2, wr2, b2, inv, h2, N, 256);
    ln_relu<256><<<cdiv(N, 4), 256, 0, stream>>>(h2, g2, be2, N);

    // ---- layer 3: GEMM first (Dout=128 < Din=256), then aggregate ----
    float* y3 = bufA;                    // N*128 (h1 dead after GEMM2)
    float* r3 = bufA + (size_t)N * 128;  // N*128
    {
        dim3 g(cdiv(N, 64), 2);
        sage_gemm<<<g, 256, 0, stream>>>(h2, nullptr, wm3, nullptr, nullptr, inv, y3, N, 256, 128, 0, 0);
        sage_gemm<<<g, 256, 0, stream>>>(h2, nullptr, wr3, nullptr, b3, inv, r3, N, 256, 128, 0, 0);
    }
    float* agg3 = bufB;  // h2 dead after the two GEMMs above
    zero_f4<<<cdiv((long)N * 32, 256), 256, 0, stream>>>((float4*)agg3, N * 32);
    scatter_add<5><<<cdiv((long)E * 32, 256), 256, 0, stream>>>(y3, src, dstp, agg3, E);
    float* h3 = bufB + (size_t)N * 128;
    add_ln_relu128<<<cdiv(N, 4), 256, 0, stream>>>(agg3, inv, r3, g3, be3, h3, N);

    // ---- layer 4: GEMM first (Dout=9), aggregate 9-d, final add ----
    float* y4 = bufA;                      // N*9 (y3 dead after scatter, r3 dead after add_ln)
    float* r4 = bufA + (size_t)N * 9;      // N*9
    float* agg4 = bufA + (size_t)2 * N * 9;
    gemm4<<<cdiv(N, 16), 320, 0, stream>>>(h3, wm4, wr4, b4, y4, r4, N);
    zero_f4<<<cdiv((long)N * 9 / 4, 256), 256, 0, stream>>>((float4*)agg4, N * 9 / 4);
    scatter_add9<<<cdiv((long)E * 16, 256), 256, 0, stream>>>(y4, src, dstp, agg4, E);
    final_add<<<cdiv((long)N * 9, 256), 256, 0, stream>>>(agg4, inv, r4, out, N * 9);
}

// Round 3
// 2021.996 us; speedup vs baseline: 5.9264x; 5.9264x over previous
//
#include <hip/hip_runtime.h>
#include <hip/hip_bf16.h>

// GraphSAGE decoder, 4 layers. fp32, CSR-gather aggregation (no feature atomics).
// Identity: segment_sum(x[src]) @ W == segment_sum((x@W)[src]); aggregate over
// the smaller of {Din, Dout} per layer:
//   L1: agg 128-d (before GEMM), L2: 256-d, L3: 128-d (after GEMM), L4: 9-d (after GEMM).
// CSR (rowptr/eidx) built on-device each call: histogram -> 1-block scan -> fill.

#define EPS 1e-5f

// ---------------- zero fill ----------------
__global__ __launch_bounds__(256) void zero_f4(float4* __restrict__ p, int n4) {
    int i = blockIdx.x * 256 + threadIdx.x;
    if (i < n4) p[i] = make_float4(0.f, 0.f, 0.f, 0.f);
}

// ---------------- CSR build ----------------
__global__ __launch_bounds__(256) void count_deg(const int* __restrict__ dst,
                                                 int* __restrict__ deg, int E) {
    int e = blockIdx.x * 256 + threadIdx.x;
    if (e < E) atomicAdd(&deg[dst[e]], 1);
}

// single block, 1024 threads: exclusive scan of deg -> rowptr (+cursor copy, +inv)
__global__ __launch_bounds__(1024) void build_rowptr(const int* __restrict__ deg,
                                                     int* __restrict__ rowptr,
                                                     int* __restrict__ cursor,
                                                     float* __restrict__ inv,
                                                     int N, int E) {
    __shared__ int part[1024];
    const int tid = threadIdx.x;
    const int per = (N + 1023) >> 10;
    const int start = tid * per;
    const int stop = min(start + per, N);
    int sum = 0;
    for (int i = start; i < stop; ++i) sum += deg[i];
    part[tid] = sum;
    __syncthreads();
    // Hillis-Steele inclusive scan over 1024 partials
    for (int off = 1; off < 1024; off <<= 1) {
        int v = (tid >= off) ? part[tid - off] : 0;
        __syncthreads();
        part[tid] += v;
        __syncthreads();
    }
    int run = part[tid] - sum;  // exclusive prefix
    for (int i = start; i < stop; ++i) {
        int d = deg[i];
        rowptr[i] = run;
        cursor[i] = run;
        inv[i] = 1.0f / fmaxf((float)d, 1.0f);
        run += d;
    }
    if (tid == 0) rowptr[N] = E;
}

__global__ __launch_bounds__(256) void fill_csr(const int* __restrict__ src,
                                                const int* __restrict__ dst,
                                                int* __restrict__ cursor,
                                                int* __restrict__ eidx, int E) {
    int e = blockIdx.x * 256 + threadIdx.x;
    if (e >= E) return;
    int p = atomicAdd(&cursor[dst[e]], 1);
    eidx[p] = src[e];
}

// ---------------- gather aggregation (CSR) ----------------
// D=256: one 64-lane wave per dst row, float4 per lane.
__global__ __launch_bounds__(256) void gather_agg256(const float* __restrict__ x,
                                                     const int* __restrict__ rowptr,
                                                     const int* __restrict__ eidx,
                                                     float* __restrict__ agg, int N) {
    int wave = threadIdx.x >> 6;
    int lane = threadIdx.x & 63;
    int row = blockIdx.x * 4 + wave;
    if (row >= N) return;
    int beg = rowptr[row], end = rowptr[row + 1];
    const float4* xv = (const float4*)x;
    float4 a0 = make_float4(0.f, 0.f, 0.f, 0.f);
    float4 a1 = make_float4(0.f, 0.f, 0.f, 0.f);
    int j = beg;
    for (; j + 1 < end; j += 2) {
        int s0 = eidx[j], s1 = eidx[j + 1];
        float4 v0 = xv[(long)s0 * 64 + lane];
        float4 v1 = xv[(long)s1 * 64 + lane];
        a0.x += v0.x; a0.y += v0.y; a0.z += v0.z; a0.w += v0.w;
        a1.x += v1.x; a1.y += v1.y; a1.z += v1.z; a1.w += v1.w;
    }
    if (j < end) {
        float4 v = xv[(long)eidx[j] * 64 + lane];
        a0.x += v.x; a0.y += v.y; a0.z += v.z; a0.w += v.w;
    }
    a0.x += a1.x; a0.y += a1.y; a0.z += a1.z; a0.w += a1.w;
    ((float4*)agg)[(long)row * 64 + lane] = a0;
}

// D=128: half-wave (32 lanes) per dst row, float4 per lane.
__global__ __launch_bounds__(256) void gather_agg128(const float* __restrict__ x,
                                                     const int* __restrict__ rowptr,
                                                     const int* __restrict__ eidx,
                                                     float* __restrict__ agg, int N) {
    int half = threadIdx.x >> 5;
    int lane = threadIdx.x & 31;
    int row = blockIdx.x * 8 + half;
    if (row >= N) return;
    int beg = rowptr[row], end = rowptr[row + 1];
    const float4* xv = (const float4*)x;
    float4 a0 = make_float4(0.f, 0.f, 0.f, 0.f);
    float4 a1 = make_float4(0.f, 0.f, 0.f, 0.f);
    int j = beg;
    for (; j + 1 < end; j += 2) {
        int s0 = eidx[j], s1 = eidx[j + 1];
        float4 v0 = xv[(long)s0 * 32 + lane];
        float4 v1 = xv[(long)s1 * 32 + lane];
        a0.x += v0.x; a0.y += v0.y; a0.z += v0.z; a0.w += v0.w;
        a1.x += v1.x; a1.y += v1.y; a1.z += v1.z; a1.w += v1.w;
    }
    if (j < end) {
        float4 v = xv[(long)eidx[j] * 32 + lane];
        a0.x += v.x; a0.y += v.y; a0.z += v.z; a0.w += v.w;
    }
    a0.x += a1.x; a0.y += a1.y; a0.z += a1.z; a0.w += a1.w;
    ((float4*)agg)[(long)row * 32 + lane] = a0;
}

// D=9 + fused final: out = gather_sum(y)[row]*inv + r
__global__ __launch_bounds__(256) void gather9_final(const float* __restrict__ y,
                                                     const int* __restrict__ rowptr,
                                                     const int* __restrict__ eidx,
                                                     const float* __restrict__ inv,
                                                     const float* __restrict__ r,
                                                     float* __restrict__ out, int N) {
    int idx = blockIdx.x * 256 + threadIdx.x;
    int row = idx >> 4;
    int c = idx & 15;
    if (row >= N || c >= 9) return;
    int beg = rowptr[row], end = rowptr[row + 1];
    float a = 0.f;
    for (int j = beg; j < end; ++j) a += y[(long)eidx[j] * 9 + c];
    out[(long)row * 9 + c] = a * inv[row] + r[(long)row * 9 + c];
}

// ---------------- tiled fp32 GEMM: out = (A1*inv?)@W1 [+ A2@W2] + bias ----------------
// BM=64, BN=64, BK=16, 256 threads, 4x4 per thread. out must NOT alias inputs.
__global__ __launch_bounds__(256) void sage_gemm(const float* __restrict__ A1,
                                                 const float* __restrict__ A2,
                                                 const float* __restrict__ W1,
                                                 const float* __restrict__ W2,
                                                 const float* __restrict__ bias,
                                                 const float* __restrict__ invc,
                                                 float* __restrict__ out, int M, int K,
                                                 int Dout, int two_pass, int scale_first) {
    __shared__ float As[16][68];
    __shared__ float Ws[16][68];
    const int tid = threadIdx.x;
    const int bm = blockIdx.x * 64;
    const int bn = blockIdx.y * 64;
    const int tr = (tid / 16) * 4;
    const int tc = (tid % 16) * 4;
    const int lr = tid / 4;
    const int lk = (tid % 4) * 4;
    const int wk = tid / 16;
    const int wn = (tid % 16) * 4;

    float acc[4][4] = {};
    const int npass = two_pass ? 2 : 1;
    for (int pass = 0; pass < npass; ++pass) {
        const float* A = pass ? A2 : A1;
        const float* W = pass ? W2 : W1;
        const bool scale = (pass == 0) && scale_first;
        for (int k0 = 0; k0 < K; k0 += 16) {
            int gm = bm + lr;
            float4 av = make_float4(0.f, 0.f, 0.f, 0.f);
            if (gm < M) {
                av = *(const float4*)&A[(long)gm * K + k0 + lk];
                if (scale) {
                    float s = invc[gm];
                    av.x *= s; av.y *= s; av.z *= s; av.w *= s;
                }
            }
            As[lk + 0][lr] = av.x;
            As[lk + 1][lr] = av.y;
            As[lk + 2][lr] = av.z;
            As[lk + 3][lr] = av.w;
            *(float4*)&Ws[wk][wn] = *(const float4*)&W[(long)(k0 + wk) * Dout + bn + wn];
            __syncthreads();
#pragma unroll
            for (int kk = 0; kk < 16; ++kk) {
                float4 a = *(const float4*)&As[kk][tr];
                float4 w = *(const float4*)&Ws[kk][tc];
                acc[0][0] += a.x * w.x; acc[0][1] += a.x * w.y; acc[0][2] += a.x * w.z; acc[0][3] += a.x * w.w;
                acc[1][0] += a.y * w.x; acc[1][1] += a.y * w.y; acc[1][2] += a.y * w.z; acc[1][3] += a.y * w.w;
                acc[2][0] += a.z * w.x; acc[2][1] += a.z * w.y; acc[2][2] += a.z * w.z; acc[2][3] += a.z * w.w;
                acc[3][0] += a.w * w.x; acc[3][1] += a.w * w.y; acc[3][2] += a.w * w.z; acc[3][3] += a.w * w.w;
            }
            __syncthreads();
        }
    }
    float4 bv = make_float4(0.f, 0.f, 0.f, 0.f);
    if (bias) bv = *(const float4*)&bias[bn + tc];
#pragma unroll
    for (int i = 0; i < 4; ++i) {
        int gm = bm + tr + i;
        if (gm < M) {
            float4 o;
            o.x = acc[i][0] + bv.x;
            o.y = acc[i][1] + bv.y;
            o.z = acc[i][2] + bv.z;
            o.w = acc[i][3] + bv.w;
            *(float4*)&out[(long)gm * Dout + bn + tc] = o;
        }
    }
}

// ---------------- wide in-place GEMM: out = (A1*inv)@W1 + A2@W2 + bias ----------------
// BM=32, BN=256(=Dout), BK=16, 256 threads, 4x8 per thread. out MAY alias A1.
__global__ __launch_bounds__(256) void sage_gemm_wide(const float* A1,
                                                      const float* __restrict__ A2,
                                                      const float* __restrict__ W1,
                                                      const float* __restrict__ W2,
                                                      const float* __restrict__ bias,
                                                      const float* __restrict__ invc,
                                                      float* out, int M, int K) {
    __shared__ float As[16][36];
    __shared__ float Ws[16][260];
    const int tid = threadIdx.x;
    const int bm = blockIdx.x * 32;
    const int tr = (tid >> 5) * 4;
    const int tc = (tid & 31) * 8;
    const int lr = tid >> 3;
    const int lk = (tid & 7) * 2;
    const int wk = tid >> 6;
    const int wn = (tid & 63) * 4;

    float acc[4][8] = {};
    for (int pass = 0; pass < 2; ++pass) {
        const float* A = pass ? A2 : A1;
        const float* W = pass ? W2 : W1;
        const bool scale = (pass == 0);
        for (int k0 = 0; k0 < K; k0 += 16) {
            int gm = bm + lr;
            float2 av = make_float2(0.f, 0.f);
            if (gm < M) {
                av = *(const float2*)&A[(long)gm * K + k0 + lk];
                if (scale) { float s = invc[gm]; av.x *= s; av.y *= s; }
            }
            As[lk + 0][lr] = av.x;
            As[lk + 1][lr] = av.y;
#pragma unroll
            for (int j = 0; j < 4; ++j) {
                *(float4*)&Ws[wk * 4 + j][wn] =
                    *(const float4*)&W[(long)(k0 + wk * 4 + j) * 256 + wn];
            }
            __syncthreads();
#pragma unroll
            for (int kk = 0; kk < 16; ++kk) {
                float4 a = *(const float4*)&As[kk][tr];
                float4 w0 = *(const float4*)&Ws[kk][tc];
                float4 w1 = *(const float4*)&Ws[kk][tc + 4];
                acc[0][0] += a.x * w0.x; acc[0][1] += a.x * w0.y; acc[0][2] += a.x * w0.z; acc[0][3] += a.x * w0.w;
                acc[0][4] += a.x * w1.x; acc[0][5] += a.x * w1.y; acc[0][6] += a.x * w1.z; acc[0][7] += a.x * w1.w;
                acc[1][0] += a.y * w0.x; acc[1][1] += a.y * w0.y; acc[1][2] += a.y * w0.z; acc[1][3] += a.y * w0.w;
                acc[1][4] += a.y * w1.x; acc[1][5] += a.y * w1.y; acc[1][6] += a.y * w1.z; acc[1][7] += a.y * w1.w;
                acc[2][0] += a.z * w0.x; acc[2][1] += a.z * w0.y; acc[2][2] += a.z * w0.z; acc[2][3] += a.z * w0.w;
                acc[2][4] += a.z * w1.x; acc[2][5] += a.z * w1.y; acc[2][6] += a.z * w1.z; acc[2][7] += a.z * w1.w;
                acc[3][0] += a.w * w0.x; acc[3][1] += a.w * w0.y; acc[3][2] += a.w * w0.z; acc[3][3] += a.w * w0.w;
                acc[3][4] += a.w * w1.x; acc[3][5] += a.w * w1.y; acc[3][6] += a.w * w1.z; acc[3][7] += a.w * w1.w;
            }
            __syncthreads();
        }
    }
    float4 bv0 = *(const float4*)&bias[tc];
    float4 bv1 = *(const float4*)&bias[tc + 4];
#pragma unroll
    for (int i = 0; i < 4; ++i) {
        int gm = bm + tr + i;
        if (gm < M) {
            float4 o0, o1;
            o0.x = acc[i][0] + bv0.x; o0.y = acc[i][1] + bv0.y;
            o0.z = acc[i][2] + bv0.z; o0.w = acc[i][3] + bv0.w;
            o1.x = acc[i][4] + bv1.x; o1.y = acc[i][5] + bv1.y;
            o1.z = acc[i][6] + bv1.z; o1.w = acc[i][7] + bv1.w;
            *(float4*)&out[(long)gm * 256 + tc] = o0;
            *(float4*)&out[(long)gm * 256 + tc + 4] = o1;
        }
    }
}

// ---------------- LayerNorm + ReLU, one 64-lane wave per row, in place ----------------
template <int D>
__global__ __launch_bounds__(256) void ln_relu(float* __restrict__ h, const float* __restrict__ g,
                                               const float* __restrict__ be, int M) {
    constexpr int PER = D / 64;
    int wave = threadIdx.x >> 6;
    int lane = threadIdx.x & 63;
    int row = blockIdx.x * 4 + wave;
    if (row >= M) return;
    float* p = &h[(long)row * D + lane * PER];
    float v[PER];
    if constexpr (PER == 4) {
        float4 ld = *(const float4*)p;
        v[0] = ld.x; v[1] = ld.y; v[2] = ld.z; v[3] = ld.w;
    } else {
        float2 ld = *(const float2*)p;
        v[0] = ld.x; v[1] = ld.y;
    }
    float s = 0.f, ss = 0.f;
#pragma unroll
    for (int i = 0; i < PER; ++i) { s += v[i]; ss += v[i] * v[i]; }
#pragma unroll
    for (int m = 32; m >= 1; m >>= 1) {
        s += __shfl_xor(s, m);
        ss += __shfl_xor(ss, m);
    }
    float mean = s / D;
    float var = ss / D - mean * mean;
    float rs = rsqrtf(var + EPS);
#pragma unroll
    for (int i = 0; i < PER; ++i) {
        int col = lane * PER + i;
        float y = (v[i] - mean) * rs * g[col] + be[col];
        v[i] = fmaxf(y, 0.f);
    }
    if constexpr (PER == 4) {
        *(float4*)p = make_float4(v[0], v[1], v[2], v[3]);
    } else {
        *(float2*)p = make_float2(v[0], v[1]);
    }
}

// ---------------- h3 = relu(LN(agg*inv + r3)), D=128 ----------------
__global__ __launch_bounds__(256) void add_ln_relu128(const float* __restrict__ agg,
                                                      const float* __restrict__ invc,
                                                      const float* __restrict__ r,
                                                      const float* __restrict__ g,
                                                      const float* __restrict__ be,
                                                      float* __restrict__ out, int M) {
    int wave = threadIdx.x >> 6;
    int lane = threadIdx.x & 63;
    int row = blockIdx.x * 4 + wave;
    if (row >= M) return;
    long base = (long)row * 128 + lane * 2;
    float2 a = *(const float2*)&agg[base];
    float2 rr = *(const float2*)&r[base];
    float iv = invc[row];
    float v[2] = {a.x * iv + rr.x, a.y * iv + rr.y};
    float s = v[0] + v[1], ss = v[0] * v[0] + v[1] * v[1];
#pragma unroll
    for (int m = 32; m >= 1; m >>= 1) {
        s += __shfl_xor(s, m);
        ss += __shfl_xor(ss, m);
    }
    float mean = s / 128.f;
    float var = ss / 128.f - mean * mean;
    float rs = rsqrtf(var + EPS);
#pragma unroll
    for (int i = 0; i < 2; ++i) {
        int col = lane * 2 + i;
        float y = (v[i] - mean) * rs * g[col] + be[col];
        v[i] = fmaxf(y, 0.f);
    }
    *(float2*)&out[base] = make_float2(v[0], v[1]);
}

// ---------------- layer 4 small GEMM: y = x@wm (Nx9), r = x@wr + b (Nx9) ----------------
__global__ __launch_bounds__(320) void gemm4(const float* __restrict__ x,
                                             const float* __restrict__ wm,
                                             const float* __restrict__ wrt,
                                             const float* __restrict__ b,
                                             float* __restrict__ y, float* __restrict__ r,
                                             int M) {
    __shared__ float xs[16][132];
    __shared__ float ws[128][20];
    int tid = threadIdx.x;
    int m0 = blockIdx.x * 16;
    for (int idx = tid; idx < 16 * 128; idx += 320) {
        int rr = idx >> 7, kk = idx & 127;
        int gm = m0 + rr;
        xs[rr][kk] = (gm < M) ? x[(long)gm * 128 + kk] : 0.f;
    }
    for (int idx = tid; idx < 128 * 18; idx += 320) {
        int kk = idx / 18, cc = idx % 18;
        ws[kk][cc] = (cc < 9) ? wm[kk * 9 + cc] : wrt[kk * 9 + cc - 9];
    }
    __syncthreads();
    if (tid < 288) {
        int rr = tid / 18, cc = tid % 18;
        float acc = 0.f;
#pragma unroll 8
        for (int kk = 0; kk < 128; ++kk) acc += xs[rr][kk] * ws[kk][cc];
        int gm = m0 + rr;
        if (gm < M) {
            if (cc < 9) y[(long)gm * 9 + cc] = acc;
            else r[(long)gm * 9 + cc - 9] = acc + b[cc - 9];
        }
    }
}

static inline int cdiv(long a, long b) { return (int)((a + b - 1) / b); }

extern "C" void kernel_launch(void* const* d_in, const int* in_sizes, int n_in,
                              void* d_out, int out_size, void* d_ws, size_t ws_size,
                              hipStream_t stream) {
    const int N = in_sizes[0] / 128;
    const int E = in_sizes[1] / 2;

    const float* z = (const float*)d_in[0];
    const int* ei = (const int*)d_in[1];
    const int* src = ei;
    const int* dstp = ei + E;
    const float* wm1 = (const float*)d_in[2];
    const float* wr1 = (const float*)d_in[3];
    const float* b1 = (const float*)d_in[4];
    const float* g1 = (const float*)d_in[5];
    const float* be1 = (const float*)d_in[6];
    const float* wm2 = (const float*)d_in[7];
    const float* wr2 = (const float*)d_in[8];
    const float* b2 = (const float*)d_in[9];
    const float* g2 = (const float*)d_in[10];
    const float* be2 = (const float*)d_in[11];
    const float* wm3 = (const float*)d_in[12];
    const float* wr3 = (const float*)d_in[13];
    const float* b3 = (const float*)d_in[14];
    const float* g3 = (const float*)d_in[15];
    const float* be3 = (const float*)d_in[16];
    const float* wm4 = (const float*)d_in[17];
    const float* wr4 = (const float*)d_in[18];
    const float* b4 = (const float*)d_in[19];
    float* out = (float*)d_out;

    // workspace: bufA[N*256] | bufB[N*256] | inv[N] | deg[N+4] | rowptr[N+4] | cursor[N+4] | eidx[E]
    float* Wp = (float*)d_ws;
    float* bufA = Wp;
    float* bufB = bufA + (size_t)N * 256;
    float* inv = bufB + (size_t)N * 256;
    int* deg = (int*)(inv + N);
    int* rowptr = deg + N + 4;
    int* cursor = rowptr + N + 4;
    int* eidx = cursor + N + 4;

    // ---- CSR build ----
    zero_f4<<<cdiv(N, 1024), 256, 0, stream>>>((float4*)deg, cdiv(N, 4));
    count_deg<<<cdiv(E, 256), 256, 0, stream>>>(dstp, deg, E);
    build_rowptr<<<1, 1024, 0, stream>>>(deg, rowptr, cursor, inv, N, E);
    fill_csr<<<cdiv(E, 256), 256, 0, stream>>>(src, dstp, cursor, eidx, E);

    // ---- layer 1: gather z (128-d) into bufB -> h1(bufA) ----
    float* agg1 = bufB;
    gather_agg128<<<cdiv(N, 8), 256, 0, stream>>>(z, rowptr, eidx, agg1, N);
    float* h1 = bufA;
    {
        dim3 g(cdiv(N, 64), 4);
        sage_gemm<<<g, 256, 0, stream>>>(agg1, z, wm1, wr1, b1, inv, h1, N, 128, 256, 1, 1);
    }
    ln_relu<256><<<cdiv(N, 4), 256, 0, stream>>>(h1, g1, be1, N);

    // ---- layer 2: gather h1 (256-d) into bufB; in-place wide GEMM bufB -> h2(bufB) ----
    float* agg2 = bufB;
    gather_agg256<<<cdiv(N, 4), 256, 0, stream>>>(h1, rowptr, eidx, agg2, N);
    float* h2 = bufB;
    sage_gemm_wide<<<cdiv(N, 32), 256, 0, stream>>>(agg2, h1, wm2, wr2, b2, inv, h2, N, 256);
    ln_relu<256><<<cdiv(N, 4), 256, 0, stream>>>(h2, g2, be2, N);

    // ---- layer 3: GEMM first (Dout=128), then gather ----
    float* y3 = bufA;                    // h1 dead after GEMM2
    float* r3 = bufA + (size_t)N * 128;
    {
        dim3 g(cdiv(N, 64), 2);
        sage_gemm<<<g, 256, 0, stream>>>(h2, nullptr, wm3, nullptr, nullptr, inv, y3, N, 256, 128, 0, 0);
        sage_gemm<<<g, 256, 0, stream>>>(h2, nullptr, wr3, nullptr, b3, inv, r3, N, 256, 128, 0, 0);
    }
    float* agg3 = bufB;  // h2 dead now
    gather_agg128<<<cdiv(N, 8), 256, 0, stream>>>(y3, rowptr, eidx, agg3, N);
    float* h3 = bufB + (size_t)N * 128;
    add_ln_relu128<<<cdiv(N, 4), 256, 0, stream>>>(agg3, inv, r3, g3, be3, h3, N);

    // ---- layer 4: GEMM first (Dout=9), fused gather+final ----
    float* y4 = bufA;                  // y3 dead after gather, r3 dead after add_ln
    float* r4 = bufA + (size_t)N * 9;
    gemm4<<<cdiv(N, 16), 320, 0, stream>>>(h3, wm4, wr4, b4, y4, r4, N);
    gather9_final<<<cdiv((long)N * 16, 256), 256, 0, stream>>>(y4, rowptr, eidx, inv, r4, out, N);
}

// Round 4
// 1454.598 us; speedup vs baseline: 8.2382x; 1.3901x over previous
//
#include <hip/hip_runtime.h>
#include <hip/hip_bf16.h>

// GraphSAGE decoder, 4 layers. CSR-gather aggregation (fp32), bf16-MFMA GEMMs.
// Identity: segment_sum(x[src]) @ W == segment_sum((x@W)[src]); aggregate over
// the smaller of {Din, Dout} per layer:
//   L1: agg 128-d (pre-GEMM), L2: 256-d, L3: 128-d (post-GEMM), L4: 9-d (post-GEMM).
// GEMMs: mfma_f32_16x16x32_bf16, activations cast fp32->bf16 in staging,
// weights pre-transposed+cast to bf16 W^T[Dout][K] (k-contiguous B-frags).

#define EPS 1e-5f

typedef unsigned short u16;
typedef short bf16x8_t __attribute__((ext_vector_type(8)));
typedef float f32x4_t __attribute__((ext_vector_type(4)));

// RNE fp32->bf16 packing (two floats -> one uint, low=a, high=b)
__device__ inline unsigned int bfpack(float a, float b) {
    unsigned int ua = __builtin_bit_cast(unsigned int, a);
    unsigned int ub = __builtin_bit_cast(unsigned int, b);
    ua += 0x7fffu + ((ua >> 16) & 1u);
    ub += 0x7fffu + ((ub >> 16) & 1u);
    return (ua >> 16) | (ub & 0xffff0000u);
}

__device__ inline u16 bfr(float a) {
    unsigned int u = __builtin_bit_cast(unsigned int, a);
    u += 0x7fffu + ((u >> 16) & 1u);
    return (u16)(u >> 16);
}

// ---------------- zero fill ----------------
__global__ __launch_bounds__(256) void zero_f4(float4* __restrict__ p, int n4) {
    int i = blockIdx.x * 256 + threadIdx.x;
    if (i < n4) p[i] = make_float4(0.f, 0.f, 0.f, 0.f);
}

// ---------------- weight transpose+cast: W[K][N] fp32 -> WT[N][K] bf16 ----------------
__global__ __launch_bounds__(256) void transpose_cast(const float* __restrict__ W,
                                                      u16* __restrict__ WT, int K, int N) {
    int idx = blockIdx.x * 256 + threadIdx.x;
    if (idx >= K * N) return;
    int k = idx / N, n = idx - k * N;
    WT[(long)n * K + k] = bfr(W[idx]);
}

// ---------------- CSR build ----------------
__global__ __launch_bounds__(256) void count_deg(const int* __restrict__ dst,
                                                 int* __restrict__ deg, int E) {
    int e = blockIdx.x * 256 + threadIdx.x;
    if (e < E) atomicAdd(&deg[dst[e]], 1);
}

__global__ __launch_bounds__(1024) void build_rowptr(const int* __restrict__ deg,
                                                     int* __restrict__ rowptr,
                                                     int* __restrict__ cursor,
                                                     float* __restrict__ inv,
                                                     int N, int E) {
    __shared__ int part[1024];
    const int tid = threadIdx.x;
    const int per = (N + 1023) >> 10;
    const int start = tid * per;
    const int stop = min(start + per, N);
    int sum = 0;
    for (int i = start; i < stop; ++i) sum += deg[i];
    part[tid] = sum;
    __syncthreads();
    for (int off = 1; off < 1024; off <<= 1) {
        int v = (tid >= off) ? part[tid - off] : 0;
        __syncthreads();
        part[tid] += v;
        __syncthreads();
    }
    int run = part[tid] - sum;
    for (int i = start; i < stop; ++i) {
        int d = deg[i];
        rowptr[i] = run;
        cursor[i] = run;
        inv[i] = 1.0f / fmaxf((float)d, 1.0f);
        run += d;
    }
    if (tid == 0) rowptr[N] = E;
}

__global__ __launch_bounds__(256) void fill_csr(const int* __restrict__ src,
                                                const int* __restrict__ dst,
                                                int* __restrict__ cursor,
                                                int* __restrict__ eidx, int E) {
    int e = blockIdx.x * 256 + threadIdx.x;
    if (e >= E) return;
    int p = atomicAdd(&cursor[dst[e]], 1);
    eidx[p] = src[e];
}

// ---------------- gather aggregation (CSR) ----------------
__global__ __launch_bounds__(256) void gather_agg256(const float* __restrict__ x,
                                                     const int* __restrict__ rowptr,
                                                     const int* __restrict__ eidx,
                                                     float* __restrict__ agg, int N) {
    int wave = threadIdx.x >> 6;
    int lane = threadIdx.x & 63;
    int row = blockIdx.x * 4 + wave;
    if (row >= N) return;
    int beg = rowptr[row], end = rowptr[row + 1];
    const float4* xv = (const float4*)x;
    float4 a0 = make_float4(0.f, 0.f, 0.f, 0.f);
    float4 a1 = make_float4(0.f, 0.f, 0.f, 0.f);
    int j = beg;
    for (; j + 1 < end; j += 2) {
        int s0 = eidx[j], s1 = eidx[j + 1];
        float4 v0 = xv[(long)s0 * 64 + lane];
        float4 v1 = xv[(long)s1 * 64 + lane];
        a0.x += v0.x; a0.y += v0.y; a0.z += v0.z; a0.w += v0.w;
        a1.x += v1.x; a1.y += v1.y; a1.z += v1.z; a1.w += v1.w;
    }
    if (j < end) {
        float4 v = xv[(long)eidx[j] * 64 + lane];
        a0.x += v.x; a0.y += v.y; a0.z += v.z; a0.w += v.w;
    }
    a0.x += a1.x; a0.y += a1.y; a0.z += a1.z; a0.w += a1.w;
    ((float4*)agg)[(long)row * 64 + lane] = a0;
}

__global__ __launch_bounds__(256) void gather_agg128(const float* __restrict__ x,
                                                     const int* __restrict__ rowptr,
                                                     const int* __restrict__ eidx,
                                                     float* __restrict__ agg, int N) {
    int half = threadIdx.x >> 5;
    int lane = threadIdx.x & 31;
    int row = blockIdx.x * 8 + half;
    if (row >= N) return;
    int beg = rowptr[row], end = rowptr[row + 1];
    const float4* xv = (const float4*)x;
    float4 a0 = make_float4(0.f, 0.f, 0.f, 0.f);
    float4 a1 = make_float4(0.f, 0.f, 0.f, 0.f);
    int j = beg;
    for (; j + 1 < end; j += 2) {
        int s0 = eidx[j], s1 = eidx[j + 1];
        float4 v0 = xv[(long)s0 * 32 + lane];
        float4 v1 = xv[(long)s1 * 32 + lane];
        a0.x += v0.x; a0.y += v0.y; a0.z += v0.z; a0.w += v0.w;
        a1.x += v1.x; a1.y += v1.y; a1.z += v1.z; a1.w += v1.w;
    }
    if (j < end) {
        float4 v = xv[(long)eidx[j] * 32 + lane];
        a0.x += v.x; a0.y += v.y; a0.z += v.z; a0.w += v.w;
    }
    a0.x += a1.x; a0.y += a1.y; a0.z += a1.z; a0.w += a1.w;
    ((float4*)agg)[(long)row * 32 + lane] = a0;
}

__global__ __launch_bounds__(256) void gather9_final(const float* __restrict__ y,
                                                     const int* __restrict__ rowptr,
                                                     const int* __restrict__ eidx,
                                                     const float* __restrict__ inv,
                                                     const float* __restrict__ r,
                                                     float* __restrict__ out, int N) {
    int idx = blockIdx.x * 256 + threadIdx.x;
    int row = idx >> 4;
    int c = idx & 15;
    if (row >= N || c >= 9) return;
    int beg = rowptr[row], end = rowptr[row + 1];
    float a = 0.f;
    for (int j = beg; j < end; ++j) a += y[(long)eidx[j] * 9 + c];
    out[(long)row * 9 + c] = a * inv[row] + r[(long)row * 9 + c];
}

// ---------------- MFMA GEMM (split): out = (A1*inv?)@W1 [+ A2@W2] + bias ----------------
// BM=128, BN=128 (grid.y * 128 = col offset), BK=32. 4 waves, each 64x64.
// A fp32 [M][K] cast->bf16 in staging; WT bf16 [Dout][K]. out fp32 [M][Dout].
__global__ __launch_bounds__(256) void mfma_gemm(const float* __restrict__ A1,
                                                 const float* __restrict__ A2,
                                                 const u16* __restrict__ WT1,
                                                 const u16* __restrict__ WT2,
                                                 const float* __restrict__ bias,
                                                 const float* __restrict__ invc,
                                                 float* __restrict__ out, int M, int K,
                                                 int Dout, int two_pass, int scale_first) {
    __shared__ u16 As[128 * 40];
    __shared__ u16 Ws[128 * 40];
    const int tid = threadIdx.x;
    const int bm = blockIdx.x * 128;
    const int bn = blockIdx.y * 128;
    const int l = tid & 63;
    const int w = tid >> 6;
    const int wr = (w & 1) * 64;
    const int wc = (w >> 1) * 64;
    const int ln15 = l & 15;
    const int quad = l >> 4;

    f32x4_t acc[4][4];
#pragma unroll
    for (int i = 0; i < 4; ++i)
#pragma unroll
        for (int j = 0; j < 4; ++j) acc[i][j] = (f32x4_t){0.f, 0.f, 0.f, 0.f};

    const int sr = tid >> 1;          // staging row 0..127
    const int kh = (tid & 1) * 16;    // staging k offset

    const int npass = two_pass ? 2 : 1;
    for (int pass = 0; pass < npass; ++pass) {
        const float* A = pass ? A2 : A1;
        const u16* WT = pass ? WT2 : WT1;
        const bool scale = (pass == 0) && scale_first;
        for (int k0 = 0; k0 < K; k0 += 32) {
            // stage A (fp32 -> bf16)
            float f[16];
            int gr = bm + sr;
            if (gr < M) {
                const float* ap = A + (long)gr * K + k0 + kh;
                *(float4*)(f + 0) = ((const float4*)ap)[0];
                *(float4*)(f + 4) = ((const float4*)ap)[1];
                *(float4*)(f + 8) = ((const float4*)ap)[2];
                *(float4*)(f + 12) = ((const float4*)ap)[3];
                if (scale) {
                    float s = invc[gr];
#pragma unroll
                    for (int q = 0; q < 16; ++q) f[q] *= s;
                }
            } else {
#pragma unroll
                for (int q = 0; q < 16; ++q) f[q] = 0.f;
            }
            uint4 q0 = make_uint4(bfpack(f[0], f[1]), bfpack(f[2], f[3]),
                                  bfpack(f[4], f[5]), bfpack(f[6], f[7]));
            uint4 q1 = make_uint4(bfpack(f[8], f[9]), bfpack(f[10], f[11]),
                                  bfpack(f[12], f[13]), bfpack(f[14], f[15]));
            *(uint4*)(As + sr * 40 + kh) = q0;
            *(uint4*)(As + sr * 40 + kh + 8) = q1;
            // stage W^T (already bf16)
            const u16* wp = WT + (long)(bn + sr) * K + k0 + kh;
            *(uint4*)(Ws + sr * 40 + kh) = *(const uint4*)wp;
            *(uint4*)(Ws + sr * 40 + kh + 8) = *(const uint4*)(wp + 8);
            __syncthreads();

            bf16x8_t a[4], b[4];
#pragma unroll
            for (int i = 0; i < 4; ++i)
                a[i] = *(const bf16x8_t*)(As + (wr + i * 16 + ln15) * 40 + quad * 8);
#pragma unroll
            for (int j = 0; j < 4; ++j)
                b[j] = *(const bf16x8_t*)(Ws + (wc + j * 16 + ln15) * 40 + quad * 8);
#pragma unroll
            for (int i = 0; i < 4; ++i)
#pragma unroll
                for (int j = 0; j < 4; ++j)
                    acc[i][j] = __builtin_amdgcn_mfma_f32_16x16x32_bf16(a[i], b[j], acc[i][j], 0, 0, 0);
            __syncthreads();
        }
    }

#pragma unroll
    for (int j = 0; j < 4; ++j) {
        int col = bn + wc + j * 16 + ln15;
        float bv = bias ? bias[col] : 0.f;
#pragma unroll
        for (int i = 0; i < 4; ++i) {
            int row0 = bm + wr + i * 16 + quad * 4;
            f32x4_t c = acc[i][j];
#pragma unroll
            for (int p = 0; p < 4; ++p) {
                int row = row0 + p;
                if (row < M) out[(long)row * Dout + col] = c[p] + bv;
            }
        }
    }
}

// ---------------- MFMA GEMM wide (in-place safe): out = (A1*inv)@W1 + A2@W2 + bias ----
// BM=64, BN=256 (=Dout), BK=32. 4 waves, each 32x128. out MAY alias A1 (row ownership).
__global__ __launch_bounds__(256) void mfma_gemm_wide(const float* A1,
                                                      const float* __restrict__ A2,
                                                      const u16* __restrict__ WT1,
                                                      const u16* __restrict__ WT2,
                                                      const float* __restrict__ bias,
                                                      const float* __restrict__ invc,
                                                      float* out, int M, int K) {
    __shared__ u16 As[64 * 40];
    __shared__ u16 Ws[256 * 40];
    const int tid = threadIdx.x;
    const int bm = blockIdx.x * 64;
    const int l = tid & 63;
    const int w = tid >> 6;
    const int wr = (w & 1) * 32;
    const int wc = (w >> 1) * 128;
    const int ln15 = l & 15;
    const int quad = l >> 4;

    f32x4_t acc[2][8];
#pragma unroll
    for (int i = 0; i < 2; ++i)
#pragma unroll
        for (int j = 0; j < 8; ++j) acc[i][j] = (f32x4_t){0.f, 0.f, 0.f, 0.f};

    const int ar = tid >> 2;         // A staging row 0..63
    const int akh = (tid & 3) * 8;   // A staging k offset

    for (int pass = 0; pass < 2; ++pass) {
        const float* A = pass ? A2 : A1;
        const u16* WT = pass ? WT2 : WT1;
        const bool scale = (pass == 0);
        for (int k0 = 0; k0 < K; k0 += 32) {
            // stage A: 64 rows x 32 k, 8 floats/thread
            float f[8];
            int gr = bm + ar;
            if (gr < M) {
                const float* ap = A + (long)gr * K + k0 + akh;
                *(float4*)(f + 0) = ((const float4*)ap)[0];
                *(float4*)(f + 4) = ((const float4*)ap)[1];
                if (scale) {
                    float s = invc[gr];
#pragma unroll
                    for (int q = 0; q < 8; ++q) f[q] *= s;
                }
            } else {
#pragma unroll
                for (int q = 0; q < 8; ++q) f[q] = 0.f;
            }
            uint4 q0 = make_uint4(bfpack(f[0], f[1]), bfpack(f[2], f[3]),
                                  bfpack(f[4], f[5]), bfpack(f[6], f[7]));
            *(uint4*)(As + ar * 40 + akh) = q0;
            // stage W^T: 256 rows x 32 k, 32 bf16/thread
            const u16* wp = WT + (long)tid * K + k0;
            *(uint4*)(Ws + tid * 40 + 0) = *(const uint4*)(wp + 0);
            *(uint4*)(Ws + tid * 40 + 8) = *(const uint4*)(wp + 8);
            *(uint4*)(Ws + tid * 40 + 16) = *(const uint4*)(wp + 16);
            *(uint4*)(Ws + tid * 40 + 24) = *(const uint4*)(wp + 24);
            __syncthreads();

            bf16x8_t a[2], b[8];
#pragma unroll
            for (int i = 0; i < 2; ++i)
                a[i] = *(const bf16x8_t*)(As + (wr + i * 16 + ln15) * 40 + quad * 8);
#pragma unroll
            for (int j = 0; j < 8; ++j)
                b[j] = *(const bf16x8_t*)(Ws + (wc + j * 16 + ln15) * 40 + quad * 8);
#pragma unroll
            for (int i = 0; i < 2; ++i)
#pragma unroll
                for (int j = 0; j < 8; ++j)
                    acc[i][j] = __builtin_amdgcn_mfma_f32_16x16x32_bf16(a[i], b[j], acc[i][j], 0, 0, 0);
            __syncthreads();
        }
    }

#pragma unroll
    for (int j = 0; j < 8; ++j) {
        int col = wc + j * 16 + ln15;
        float bv = bias[col];
#pragma unroll
        for (int i = 0; i < 2; ++i) {
            int row0 = bm + wr + i * 16 + quad * 4;
            f32x4_t c = acc[i][j];
#pragma unroll
            for (int p = 0; p < 4; ++p) {
                int row = row0 + p;
                if (row < M) out[(long)row * 256 + col] = c[p] + bv;
            }
        }
    }
}

// ---------------- LayerNorm + ReLU, one 64-lane wave per row, in place ----------------
template <int D>
__global__ __launch_bounds__(256) void ln_relu(float* __restrict__ h, const float* __restrict__ g,
                                               const float* __restrict__ be, int M) {
    constexpr int PER = D / 64;
    int wave = threadIdx.x >> 6;
    int lane = threadIdx.x & 63;
    int row = blockIdx.x * 4 + wave;
    if (row >= M) return;
    float* p = &h[(long)row * D + lane * PER];
    float v[PER];
    if constexpr (PER == 4) {
        float4 ld = *(const float4*)p;
        v[0] = ld.x; v[1] = ld.y; v[2] = ld.z; v[3] = ld.w;
    } else {
        float2 ld = *(const float2*)p;
        v[0] = ld.x; v[1] = ld.y;
    }
    float s = 0.f, ss = 0.f;
#pragma unroll
    for (int i = 0; i < PER; ++i) { s += v[i]; ss += v[i] * v[i]; }
#pragma unroll
    for (int m = 32; m >= 1; m >>= 1) {
        s += __shfl_xor(s, m);
        ss += __shfl_xor(ss, m);
    }
    float mean = s / D;
    float var = ss / D - mean * mean;
    float rs = rsqrtf(var + EPS);
#pragma unroll
    for (int i = 0; i < PER; ++i) {
        int col = lane * PER + i;
        float y = (v[i] - mean) * rs * g[col] + be[col];
        v[i] = fmaxf(y, 0.f);
    }
    if constexpr (PER == 4) {
        *(float4*)p = make_float4(v[0], v[1], v[2], v[3]);
    } else {
        *(float2*)p = make_float2(v[0], v[1]);
    }
}

// ---------------- h3 = relu(LN(agg*inv + r3)), D=128 ----------------
__global__ __launch_bounds__(256) void add_ln_relu128(const float* __restrict__ agg,
                                                      const float* __restrict__ invc,
                                                      const float* __restrict__ r,
                                                      const float* __restrict__ g,
                                                      const float* __restrict__ be,
                                                      float* __restrict__ out, int M) {
    int wave = threadIdx.x >> 6;
    int lane = threadIdx.x & 63;
    int row = blockIdx.x * 4 + wave;
    if (row >= M) return;
    long base = (long)row * 128 + lane * 2;
    float2 a = *(const float2*)&agg[base];
    float2 rr = *(const float2*)&r[base];
    float iv = invc[row];
    float v[2] = {a.x * iv + rr.x, a.y * iv + rr.y};
    float s = v[0] + v[1], ss = v[0] * v[0] + v[1] * v[1];
#pragma unroll
    for (int m = 32; m >= 1; m >>= 1) {
        s += __shfl_xor(s, m);
        ss += __shfl_xor(ss, m);
    }
    float mean = s / 128.f;
    float var = ss / 128.f - mean * mean;
    float rs = rsqrtf(var + EPS);
#pragma unroll
    for (int i = 0; i < 2; ++i) {
        int col = lane * 2 + i;
        float y = (v[i] - mean) * rs * g[col] + be[col];
        v[i] = fmaxf(y, 0.f);
    }
    *(float2*)&out[base] = make_float2(v[0], v[1]);
}

// ---------------- layer 4 small GEMM: y = x@wm (Nx9), r = x@wr + b (Nx9) ----------------
__global__ __launch_bounds__(320) void gemm4(const float* __restrict__ x,
                                             const float* __restrict__ wm,
                                             const float* __restrict__ wrt,
                                             const float* __restrict__ b,
                                             float* __restrict__ y, float* __restrict__ r,
                                             int M) {
    __shared__ float xs[16][132];
    __shared__ float ws[128][20];
    int tid = threadIdx.x;
    int m0 = blockIdx.x * 16;
    for (int idx = tid; idx < 16 * 128; idx += 320) {
        int rr = idx >> 7, kk = idx & 127;
        int gm = m0 + rr;
        xs[rr][kk] = (gm < M) ? x[(long)gm * 128 + kk] : 0.f;
    }
    for (int idx = tid; idx < 128 * 18; idx += 320) {
        int kk = idx / 18, cc = idx % 18;
        ws[kk][cc] = (cc < 9) ? wm[kk * 9 + cc] : wrt[kk * 9 + cc - 9];
    }
    __syncthreads();
    if (tid < 288) {
        int rr = tid / 18, cc = tid % 18;
        float acc = 0.f;
#pragma unroll 8
        for (int kk = 0; kk < 128; ++kk) acc += xs[rr][kk] * ws[kk][cc];
        int gm = m0 + rr;
        if (gm < M) {
            if (cc < 9) y[(long)gm * 9 + cc] = acc;
            else r[(long)gm * 9 + cc - 9] = acc + b[cc - 9];
        }
    }
}

static inline int cdiv(long a, long b) { return (int)((a + b - 1) / b); }

extern "C" void kernel_launch(void* const* d_in, const int* in_sizes, int n_in,
                              void* d_out, int out_size, void* d_ws, size_t ws_size,
                              hipStream_t stream) {
    const int N = in_sizes[0] / 128;
    const int E = in_sizes[1] / 2;

    const float* z = (const float*)d_in[0];
    const int* ei = (const int*)d_in[1];
    const int* src = ei;
    const int* dstp = ei + E;
    const float* wm1 = (const float*)d_in[2];
    const float* wr1 = (const float*)d_in[3];
    const float* b1 = (const float*)d_in[4];
    const float* g1 = (const float*)d_in[5];
    const float* be1 = (const float*)d_in[6];
    const float* wm2 = (const float*)d_in[7];
    const float* wr2 = (const float*)d_in[8];
    const float* b2 = (const float*)d_in[9];
    const float* g2 = (const float*)d_in[10];
    const float* be2 = (const float*)d_in[11];
    const float* wm3 = (const float*)d_in[12];
    const float* wr3 = (const float*)d_in[13];
    const float* b3 = (const float*)d_in[14];
    const float* g3 = (const float*)d_in[15];
    const float* be3 = (const float*)d_in[16];
    const float* wm4 = (const float*)d_in[17];
    const float* wr4 = (const float*)d_in[18];
    const float* b4 = (const float*)d_in[19];
    float* out = (float*)d_out;

    // ws: bufA[N*256] | bufB[N*256] | inv[N] | deg[N+4] | rowptr[N+4] | cursor[N+4]
    //     | eidx[E] | bf16 W^T buffers (512 KB)
    float* Wp = (float*)d_ws;
    float* bufA = Wp;
    float* bufB = bufA + (size_t)N * 256;
    float* inv = bufB + (size_t)N * 256;
    int* deg = (int*)(inv + N);
    int* rowptr = deg + N + 4;
    int* cursor = rowptr + N + 4;
    int* eidx = cursor + N + 4;
    u16* wt1m = (u16*)(eidx + E);
    u16* wt1r = wt1m + 256 * 128;
    u16* wt2m = wt1r + 256 * 128;
    u16* wt2r = wt2m + 256 * 256;
    u16* wt3m = wt2r + 256 * 256;
    u16* wt3r = wt3m + 128 * 256;

    // ---- CSR build + weight prep ----
    zero_f4<<<cdiv(N, 1024), 256, 0, stream>>>((float4*)deg, cdiv(N, 4));
    count_deg<<<cdiv(E, 256), 256, 0, stream>>>(dstp, deg, E);
    build_rowptr<<<1, 1024, 0, stream>>>(deg, rowptr, cursor, inv, N, E);
    fill_csr<<<cdiv(E, 256), 256, 0, stream>>>(src, dstp, cursor, eidx, E);
    transpose_cast<<<cdiv(128 * 256, 256), 256, 0, stream>>>(wm1, wt1m, 128, 256);
    transpose_cast<<<cdiv(128 * 256, 256), 256, 0, stream>>>(wr1, wt1r, 128, 256);
    transpose_cast<<<cdiv(256 * 256, 256), 256, 0, stream>>>(wm2, wt2m, 256, 256);
    transpose_cast<<<cdiv(256 * 256, 256), 256, 0, stream>>>(wr2, wt2r, 256, 256);
    transpose_cast<<<cdiv(256 * 128, 256), 256, 0, stream>>>(wm3, wt3m, 256, 128);
    transpose_cast<<<cdiv(256 * 128, 256), 256, 0, stream>>>(wr3, wt3r, 256, 128);

    // ---- layer 1: gather z (128-d) into bufB -> h1(bufA) ----
    float* agg1 = bufB;
    gather_agg128<<<cdiv(N, 8), 256, 0, stream>>>(z, rowptr, eidx, agg1, N);
    float* h1 = bufA;
    {
        dim3 g(cdiv(N, 128), 2);
        mfma_gemm<<<g, 256, 0, stream>>>(agg1, z, wt1m, wt1r, b1, inv, h1, N, 128, 256, 1, 1);
    }
    ln_relu<256><<<cdiv(N, 4), 256, 0, stream>>>(h1, g1, be1, N);

    // ---- layer 2: gather h1 (256-d) into bufB; in-place wide GEMM bufB -> h2(bufB) ----
    float* agg2 = bufB;
    gather_agg256<<<cdiv(N, 4), 256, 0, stream>>>(h1, rowptr, eidx, agg2, N);
    float* h2 = bufB;
    mfma_gemm_wide<<<cdiv(N, 64), 256, 0, stream>>>(agg2, h1, wt2m, wt2r, b2, inv, h2, N, 256);
    ln_relu<256><<<cdiv(N, 4), 256, 0, stream>>>(h2, g2, be2, N);

    // ---- layer 3: GEMM first (Dout=128), then gather ----
    float* y3 = bufA;                    // h1 dead after GEMM2
    float* r3 = bufA + (size_t)N * 128;
    {
        dim3 g(cdiv(N, 128), 1);
        mfma_gemm<<<g, 256, 0, stream>>>(h2, nullptr, wt3m, nullptr, nullptr, inv, y3, N, 256, 128, 0, 0);
        mfma_gemm<<<g, 256, 0, stream>>>(h2, nullptr, wt3r, nullptr, b3, inv, r3, N, 256, 128, 0, 0);
    }
    float* agg3 = bufB;  // h2 dead now
    gather_agg128<<<cdiv(N, 8), 256, 0, stream>>>(y3, rowptr, eidx, agg3, N);
    float* h3 = bufB + (size_t)N * 128;
    add_ln_relu128<<<cdiv(N, 4), 256, 0, stream>>>(agg3, inv, r3, g3, be3, h3, N);

    // ---- layer 4: GEMM first (Dout=9), fused gather+final ----
    float* y4 = bufA;
    float* r4 = bufA + (size_t)N * 9;
    gemm4<<<cdiv(N, 16), 320, 0, stream>>>(h3, wm4, wr4, b4, y4, r4, N);
    gather9_final<<<cdiv((long)N * 16, 256), 256, 0, stream>>>(y4, rowptr, eidx, inv, r4, out, N);
}

// Round 5
// 1190.876 us; speedup vs baseline: 10.0625x; 1.2215x over previous
//
#include <hip/hip_runtime.h>
#include <hip/hip_bf16.h>

// GraphSAGE decoder, 4 layers. CSR-gather aggregation (fp32), bf16-MFMA GEMMs.
// Identity: segment_sum(x[src]) @ W == segment_sum((x@W)[src]); aggregate over
// the smaller of {Din, Dout} per layer:
//   L1: agg 128-d (pre-GEMM), L2: 256-d, L3: 128-d (post-GEMM), L4: 9-d (post-GEMM).
// GEMMs: mfma_f32_16x16x32_bf16, activations cast fp32->bf16 in staging,
// weights pre-transposed+cast to bf16 W^T[Dout][K] (k-contiguous B-frags).
// CSR build: parallel 3-kernel scan (R4's 1-block scan was 283us on one CU).

#define EPS 1e-5f

typedef unsigned short u16;
typedef short bf16x8_t __attribute__((ext_vector_type(8)));
typedef float f32x4_t __attribute__((ext_vector_type(4)));

// RNE fp32->bf16 packing (two floats -> one uint, low=a, high=b)
__device__ inline unsigned int bfpack(float a, float b) {
    unsigned int ua = __builtin_bit_cast(unsigned int, a);
    unsigned int ub = __builtin_bit_cast(unsigned int, b);
    ua += 0x7fffu + ((ua >> 16) & 1u);
    ub += 0x7fffu + ((ub >> 16) & 1u);
    return (ua >> 16) | (ub & 0xffff0000u);
}

__device__ inline u16 bfr(float a) {
    unsigned int u = __builtin_bit_cast(unsigned int, a);
    u += 0x7fffu + ((u >> 16) & 1u);
    return (u16)(u >> 16);
}

// ---------------- zero fill ----------------
__global__ __launch_bounds__(256) void zero_f4(float4* __restrict__ p, int n4) {
    int i = blockIdx.x * 256 + threadIdx.x;
    if (i < n4) p[i] = make_float4(0.f, 0.f, 0.f, 0.f);
}

// ---------------- weight transpose+cast: W[K][N] fp32 -> WT[N][K] bf16 ----------------
__global__ __launch_bounds__(256) void transpose_cast(const float* __restrict__ W,
                                                      u16* __restrict__ WT, int K, int N) {
    int idx = blockIdx.x * 256 + threadIdx.x;
    if (idx >= K * N) return;
    int k = idx / N, n = idx - k * N;
    WT[(long)n * K + k] = bfr(W[idx]);
}

// ---------------- CSR build ----------------
__global__ __launch_bounds__(256) void count_deg(const int* __restrict__ dst,
                                                 int* __restrict__ deg, int E) {
    int e = blockIdx.x * 256 + threadIdx.x;
    if (e < E) atomicAdd(&deg[dst[e]], 1);
}

// 1024 deg entries per block -> partials[block]
__global__ __launch_bounds__(256) void partial_sums(const int* __restrict__ deg,
                                                    int* __restrict__ partials, int N) {
    __shared__ int lds[4];
    int tid = threadIdx.x;
    int base = blockIdx.x * 1024 + tid * 4;
    int s = 0;
    if (base + 3 < N) {
        int4 v = *(const int4*)(deg + base);
        s = v.x + v.y + v.z + v.w;
    } else {
        for (int i = 0; i < 4; ++i)
            if (base + i < N) s += deg[base + i];
    }
#pragma unroll
    for (int m = 32; m >= 1; m >>= 1) s += __shfl_xor(s, m);
    if ((tid & 63) == 0) lds[tid >> 6] = s;
    __syncthreads();
    if (tid == 0) partials[blockIdx.x] = lds[0] + lds[1] + lds[2] + lds[3];
}

// single block: inclusive->exclusive scan of up to 256 partials (N <= 262144)
__global__ __launch_bounds__(256) void scan_partials(int* __restrict__ partials, int nb) {
    __shared__ int lds[256];
    int tid = threadIdx.x;
    int v = (tid < nb) ? partials[tid] : 0;
    lds[tid] = v;
    __syncthreads();
    for (int off = 1; off < 256; off <<= 1) {
        int t = (tid >= off) ? lds[tid - off] : 0;
        __syncthreads();
        lds[tid] += t;
        __syncthreads();
    }
    if (tid < nb) partials[tid] = lds[tid] - v;  // exclusive
}

// block-local exclusive scan + block offset -> rowptr/cursor/inv
__global__ __launch_bounds__(256) void write_rowptr(const int* __restrict__ deg,
                                                    const int* __restrict__ partials,
                                                    int* __restrict__ rowptr,
                                                    int* __restrict__ cursor,
                                                    float* __restrict__ inv, int N, int E) {
    __shared__ int lds[256];
    int tid = threadIdx.x;
    int base = blockIdx.x * 1024 + tid * 4;
    int d[4];
    int s = 0;
#pragma unroll
    for (int i = 0; i < 4; ++i) {
        d[i] = (base + i < N) ? deg[base + i] : 0;
        s += d[i];
    }
    lds[tid] = s;
    __syncthreads();
    for (int off = 1; off < 256; off <<= 1) {
        int t = (tid >= off) ? lds[tid - off] : 0;
        __syncthreads();
        lds[tid] += t;
        __syncthreads();
    }
    int run = partials[blockIdx.x] + lds[tid] - s;  // exclusive prefix
#pragma unroll
    for (int i = 0; i < 4; ++i) {
        int idx = base + i;
        if (idx < N) {
            rowptr[idx] = run;
            cursor[idx] = run;
            inv[idx] = 1.0f / fmaxf((float)d[i], 1.0f);
            run += d[i];
        }
    }
    if (blockIdx.x == 0 && tid == 0) rowptr[N] = E;
}

__global__ __launch_bounds__(256) void fill_csr(const int* __restrict__ src,
                                                const int* __restrict__ dst,
                                                int* __restrict__ cursor,
                                                int* __restrict__ eidx, int E) {
    int e = blockIdx.x * 256 + threadIdx.x;
    if (e >= E) return;
    int p = atomicAdd(&cursor[dst[e]], 1);
    eidx[p] = src[e];
}

// ---------------- gather aggregation (CSR) ----------------
__global__ __launch_bounds__(256) void gather_agg256(const float* __restrict__ x,
                                                     const int* __restrict__ rowptr,
                                                     const int* __restrict__ eidx,
                                                     float* __restrict__ agg, int N) {
    int wave = threadIdx.x >> 6;
    int lane = threadIdx.x & 63;
    int row = blockIdx.x * 4 + wave;
    if (row >= N) return;
    int beg = rowptr[row], end = rowptr[row + 1];
    const float4* xv = (const float4*)x;
    float4 a0 = make_float4(0.f, 0.f, 0.f, 0.f);
    float4 a1 = make_float4(0.f, 0.f, 0.f, 0.f);
    int j = beg;
    for (; j + 1 < end; j += 2) {
        int s0 = eidx[j], s1 = eidx[j + 1];
        float4 v0 = xv[(long)s0 * 64 + lane];
        float4 v1 = xv[(long)s1 * 64 + lane];
        a0.x += v0.x; a0.y += v0.y; a0.z += v0.z; a0.w += v0.w;
        a1.x += v1.x; a1.y += v1.y; a1.z += v1.z; a1.w += v1.w;
    }
    if (j < end) {
        float4 v = xv[(long)eidx[j] * 64 + lane];
        a0.x += v.x; a0.y += v.y; a0.z += v.z; a0.w += v.w;
    }
    a0.x += a1.x; a0.y += a1.y; a0.z += a1.z; a0.w += a1.w;
    ((float4*)agg)[(long)row * 64 + lane] = a0;
}

__global__ __launch_bounds__(256) void gather_agg128(const float* __restrict__ x,
                                                     const int* __restrict__ rowptr,
                                                     const int* __restrict__ eidx,
                                                     float* __restrict__ agg, int N) {
    int half = threadIdx.x >> 5;
    int lane = threadIdx.x & 31;
    int row = blockIdx.x * 8 + half;
    if (row >= N) return;
    int beg = rowptr[row], end = rowptr[row + 1];
    const float4* xv = (const float4*)x;
    float4 a0 = make_float4(0.f, 0.f, 0.f, 0.f);
    float4 a1 = make_float4(0.f, 0.f, 0.f, 0.f);
    int j = beg;
    for (; j + 1 < end; j += 2) {
        int s0 = eidx[j], s1 = eidx[j + 1];
        float4 v0 = xv[(long)s0 * 32 + lane];
        float4 v1 = xv[(long)s1 * 32 + lane];
        a0.x += v0.x; a0.y += v0.y; a0.z += v0.z; a0.w += v0.w;
        a1.x += v1.x; a1.y += v1.y; a1.z += v1.z; a1.w += v1.w;
    }
    if (j < end) {
        float4 v = xv[(long)eidx[j] * 32 + lane];
        a0.x += v.x; a0.y += v.y; a0.z += v.z; a0.w += v.w;
    }
    a0.x += a1.x; a0.y += a1.y; a0.z += a1.z; a0.w += a1.w;
    ((float4*)agg)[(long)row * 32 + lane] = a0;
}

__global__ __launch_bounds__(256) void gather9_final(const float* __restrict__ y,
                                                     const int* __restrict__ rowptr,
                                                     const int* __restrict__ eidx,
                                                     const float* __restrict__ inv,
                                                     const float* __restrict__ r,
                                                     float* __restrict__ out, int N) {
    int idx = blockIdx.x * 256 + threadIdx.x;
    int row = idx >> 4;
    int c = idx & 15;
    if (row >= N || c >= 9) return;
    int beg = rowptr[row], end = rowptr[row + 1];
    float a = 0.f;
    for (int j = beg; j < end; ++j) a += y[(long)eidx[j] * 9 + c];
    out[(long)row * 9 + c] = a * inv[row] + r[(long)row * 9 + c];
}

// ---------------- MFMA GEMM (split): out = (A1*inv?)@W1 [+ A2@W2] + bias ----------------
// BM=128, BN=128, BK=32. 4 waves, each 64x64.
__global__ __launch_bounds__(256) void mfma_gemm(const float* __restrict__ A1,
                                                 const float* __restrict__ A2,
                                                 const u16* __restrict__ WT1,
                                                 const u16* __restrict__ WT2,
                                                 const float* __restrict__ bias,
                                                 const float* __restrict__ invc,
                                                 float* __restrict__ out, int M, int K,
                                                 int Dout, int two_pass, int scale_first) {
    __shared__ u16 As[128 * 40];
    __shared__ u16 Ws[128 * 40];
    const int tid = threadIdx.x;
    const int bm = blockIdx.x * 128;
    const int bn = blockIdx.y * 128;
    const int l = tid & 63;
    const int w = tid >> 6;
    const int wr = (w & 1) * 64;
    const int wc = (w >> 1) * 64;
    const int ln15 = l & 15;
    const int quad = l >> 4;

    f32x4_t acc[4][4];
#pragma unroll
    for (int i = 0; i < 4; ++i)
#pragma unroll
        for (int j = 0; j < 4; ++j) acc[i][j] = (f32x4_t){0.f, 0.f, 0.f, 0.f};

    const int sr = tid >> 1;
    const int kh = (tid & 1) * 16;

    const int npass = two_pass ? 2 : 1;
    for (int pass = 0; pass < npass; ++pass) {
        const float* A = pass ? A2 : A1;
        const u16* WT = pass ? WT2 : WT1;
        const bool scale = (pass == 0) && scale_first;
        for (int k0 = 0; k0 < K; k0 += 32) {
            float f[16];
            int gr = bm + sr;
            if (gr < M) {
                const float* ap = A + (long)gr * K + k0 + kh;
                *(float4*)(f + 0) = ((const float4*)ap)[0];
                *(float4*)(f + 4) = ((const float4*)ap)[1];
                *(float4*)(f + 8) = ((const float4*)ap)[2];
                *(float4*)(f + 12) = ((const float4*)ap)[3];
                if (scale) {
                    float s = invc[gr];
#pragma unroll
                    for (int q = 0; q < 16; ++q) f[q] *= s;
                }
            } else {
#pragma unroll
                for (int q = 0; q < 16; ++q) f[q] = 0.f;
            }
            uint4 q0 = make_uint4(bfpack(f[0], f[1]), bfpack(f[2], f[3]),
                                  bfpack(f[4], f[5]), bfpack(f[6], f[7]));
            uint4 q1 = make_uint4(bfpack(f[8], f[9]), bfpack(f[10], f[11]),
                                  bfpack(f[12], f[13]), bfpack(f[14], f[15]));
            *(uint4*)(As + sr * 40 + kh) = q0;
            *(uint4*)(As + sr * 40 + kh + 8) = q1;
            const u16* wp = WT + (long)(bn + sr) * K + k0 + kh;
            *(uint4*)(Ws + sr * 40 + kh) = *(const uint4*)wp;
            *(uint4*)(Ws + sr * 40 + kh + 8) = *(const uint4*)(wp + 8);
            __syncthreads();

            bf16x8_t a[4], b[4];
#pragma unroll
            for (int i = 0; i < 4; ++i)
                a[i] = *(const bf16x8_t*)(As + (wr + i * 16 + ln15) * 40 + quad * 8);
#pragma unroll
            for (int j = 0; j < 4; ++j)
                b[j] = *(const bf16x8_t*)(Ws + (wc + j * 16 + ln15) * 40 + quad * 8);
#pragma unroll
            for (int i = 0; i < 4; ++i)
#pragma unroll
                for (int j = 0; j < 4; ++j)
                    acc[i][j] = __builtin_amdgcn_mfma_f32_16x16x32_bf16(a[i], b[j], acc[i][j], 0, 0, 0);
            __syncthreads();
        }
    }

#pragma unroll
    for (int j = 0; j < 4; ++j) {
        int col = bn + wc + j * 16 + ln15;
        float bv = bias ? bias[col] : 0.f;
#pragma unroll
        for (int i = 0; i < 4; ++i) {
            int row0 = bm + wr + i * 16 + quad * 4;
            f32x4_t c = acc[i][j];
#pragma unroll
            for (int p = 0; p < 4; ++p) {
                int row = row0 + p;
                if (row < M) out[(long)row * Dout + col] = c[p] + bv;
            }
        }
    }
}

// ---------------- MFMA GEMM wide (in-place safe): out = (A1*inv)@W1 + A2@W2 + bias ----
// BM=64, BN=256 (=Dout), BK=32. out MAY alias A1 (row ownership).
__global__ __launch_bounds__(256) void mfma_gemm_wide(const float* A1,
                                                      const float* __restrict__ A2,
                                                      const u16* __restrict__ WT1,
                                                      const u16* __restrict__ WT2,
                                                      const float* __restrict__ bias,
                                                      const float* __restrict__ invc,
                                                      float* out, int M, int K) {
    __shared__ u16 As[64 * 40];
    __shared__ u16 Ws[256 * 40];
    const int tid = threadIdx.x;
    const int bm = blockIdx.x * 64;
    const int l = tid & 63;
    const int w = tid >> 6;
    const int wr = (w & 1) * 32;
    const int wc = (w >> 1) * 128;
    const int ln15 = l & 15;
    const int quad = l >> 4;

    f32x4_t acc[2][8];
#pragma unroll
    for (int i = 0; i < 2; ++i)
#pragma unroll
        for (int j = 0; j < 8; ++j) acc[i][j] = (f32x4_t){0.f, 0.f, 0.f, 0.f};

    const int ar = tid >> 2;
    const int akh = (tid & 3) * 8;

    for (int pass = 0; pass < 2; ++pass) {
        const float* A = pass ? A2 : A1;
        const u16* WT = pass ? WT2 : WT1;
        const bool scale = (pass == 0);
        for (int k0 = 0; k0 < K; k0 += 32) {
            float f[8];
            int gr = bm + ar;
            if (gr < M) {
                const float* ap = A + (long)gr * K + k0 + akh;
                *(float4*)(f + 0) = ((const float4*)ap)[0];
                *(float4*)(f + 4) = ((const float4*)ap)[1];
                if (scale) {
                    float s = invc[gr];
#pragma unroll
                    for (int q = 0; q < 8; ++q) f[q] *= s;
                }
            } else {
#pragma unroll
                for (int q = 0; q < 8; ++q) f[q] = 0.f;
            }
            uint4 q0 = make_uint4(bfpack(f[0], f[1]), bfpack(f[2], f[3]),
                                  bfpack(f[4], f[5]), bfpack(f[6], f[7]));
            *(uint4*)(As + ar * 40 + akh) = q0;
            const u16* wp = WT + (long)tid * K + k0;
            *(uint4*)(Ws + tid * 40 + 0) = *(const uint4*)(wp + 0);
            *(uint4*)(Ws + tid * 40 + 8) = *(const uint4*)(wp + 8);
            *(uint4*)(Ws + tid * 40 + 16) = *(const uint4*)(wp + 16);
            *(uint4*)(Ws + tid * 40 + 24) = *(const uint4*)(wp + 24);
            __syncthreads();

            bf16x8_t a[2], b[8];
#pragma unroll
            for (int i = 0; i < 2; ++i)
                a[i] = *(const bf16x8_t*)(As + (wr + i * 16 + ln15) * 40 + quad * 8);
#pragma unroll
            for (int j = 0; j < 8; ++j)
                b[j] = *(const bf16x8_t*)(Ws + (wc + j * 16 + ln15) * 40 + quad * 8);
#pragma unroll
            for (int i = 0; i < 2; ++i)
#pragma unroll
                for (int j = 0; j < 8; ++j)
                    acc[i][j] = __builtin_amdgcn_mfma_f32_16x16x32_bf16(a[i], b[j], acc[i][j], 0, 0, 0);
            __syncthreads();
        }
    }

#pragma unroll
    for (int j = 0; j < 8; ++j) {
        int col = wc + j * 16 + ln15;
        float bv = bias[col];
#pragma unroll
        for (int i = 0; i < 2; ++i) {
            int row0 = bm + wr + i * 16 + quad * 4;
            f32x4_t c = acc[i][j];
#pragma unroll
            for (int p = 0; p < 4; ++p) {
                int row = row0 + p;
                if (row < M) out[(long)row * 256 + col] = c[p] + bv;
            }
        }
    }
}

// ---------------- LayerNorm + ReLU, one 64-lane wave per row, in place ----------------
template <int D>
__global__ __launch_bounds__(256) void ln_relu(float* __restrict__ h, const float* __restrict__ g,
                                               const float* __restrict__ be, int M) {
    constexpr int PER = D / 64;
    int wave = threadIdx.x >> 6;
    int lane = threadIdx.x & 63;
    int row = blockIdx.x * 4 + wave;
    if (row >= M) return;
    float* p = &h[(long)row * D + lane * PER];
    float v[PER];
    if constexpr (PER == 4) {
        float4 ld = *(const float4*)p;
        v[0] = ld.x; v[1] = ld.y; v[2] = ld.z; v[3] = ld.w;
    } else {
        float2 ld = *(const float2*)p;
        v[0] = ld.x; v[1] = ld.y;
    }
    float s = 0.f, ss = 0.f;
#pragma unroll
    for (int i = 0; i < PER; ++i) { s += v[i]; ss += v[i] * v[i]; }
#pragma unroll
    for (int m = 32; m >= 1; m >>= 1) {
        s += __shfl_xor(s, m);
        ss += __shfl_xor(ss, m);
    }
    float mean = s / D;
    float var = ss / D - mean * mean;
    float rs = rsqrtf(var + EPS);
#pragma unroll
    for (int i = 0; i < PER; ++i) {
        int col = lane * PER + i;
        float y = (v[i] - mean) * rs * g[col] + be[col];
        v[i] = fmaxf(y, 0.f);
    }
    if constexpr (PER == 4) {
        *(float4*)p = make_float4(v[0], v[1], v[2], v[3]);
    } else {
        *(float2*)p = make_float2(v[0], v[1]);
    }
}

// ---------------- h3 = relu(LN(agg*inv + r3)), D=128 ----------------
__global__ __launch_bounds__(256) void add_ln_relu128(const float* __restrict__ agg,
                                                      const float* __restrict__ invc,
                                                      const float* __restrict__ r,
                                                      const float* __restrict__ g,
                                                      const float* __restrict__ be,
                                                      float* __restrict__ out, int M) {
    int wave = threadIdx.x >> 6;
    int lane = threadIdx.x & 63;
    int row = blockIdx.x * 4 + wave;
    if (row >= M) return;
    long base = (long)row * 128 + lane * 2;
    float2 a = *(const float2*)&agg[base];
    float2 rr = *(const float2*)&r[base];
    float iv = invc[row];
    float v[2] = {a.x * iv + rr.x, a.y * iv + rr.y};
    float s = v[0] + v[1], ss = v[0] * v[0] + v[1] * v[1];
#pragma unroll
    for (int m = 32; m >= 1; m >>= 1) {
        s += __shfl_xor(s, m);
        ss += __shfl_xor(ss, m);
    }
    float mean = s / 128.f;
    float var = ss / 128.f - mean * mean;
    float rs = rsqrtf(var + EPS);
#pragma unroll
    for (int i = 0; i < 2; ++i) {
        int col = lane * 2 + i;
        float y = (v[i] - mean) * rs * g[col] + be[col];
        v[i] = fmaxf(y, 0.f);
    }
    *(float2*)&out[base] = make_float2(v[0], v[1]);
}

// ---------------- layer 4 small GEMM: y = x@wm (Nx9), r = x@wr + b (Nx9) ----------------
__global__ __launch_bounds__(320) void gemm4(const float* __restrict__ x,
                                             const float* __restrict__ wm,
                                             const float* __restrict__ wrt,
                                             const float* __restrict__ b,
                                             float* __restrict__ y, float* __restrict__ r,
                                             int M) {
    __shared__ float xs[16][132];
    __shared__ float ws[128][20];
    int tid = threadIdx.x;
    int m0 = blockIdx.x * 16;
    for (int idx = tid; idx < 16 * 128; idx += 320) {
        int rr = idx >> 7, kk = idx & 127;
        int gm = m0 + rr;
        xs[rr][kk] = (gm < M) ? x[(long)gm * 128 + kk] : 0.f;
    }
    for (int idx = tid; idx < 128 * 18; idx += 320) {
        int kk = idx / 18, cc = idx % 18;
        ws[kk][cc] = (cc < 9) ? wm[kk * 9 + cc] : wrt[kk * 9 + cc - 9];
    }
    __syncthreads();
    if (tid < 288) {
        int rr = tid / 18, cc = tid % 18;
        float acc = 0.f;
#pragma unroll 8
        for (int kk = 0; kk < 128; ++kk) acc += xs[rr][kk] * ws[kk][cc];
        int gm = m0 + rr;
        if (gm < M) {
            if (cc < 9) y[(long)gm * 9 + cc] = acc;
            else r[(long)gm * 9 + cc - 9] = acc + b[cc - 9];
        }
    }
}

static inline int cdiv(long a, long b) { return (int)((a + b - 1) / b); }

extern "C" void kernel_launch(void* const* d_in, const int* in_sizes, int n_in,
                              void* d_out, int out_size, void* d_ws, size_t ws_size,
                              hipStream_t stream) {
    const int N = in_sizes[0] / 128;
    const int E = in_sizes[1] / 2;

    const float* z = (const float*)d_in[0];
    const int* ei = (const int*)d_in[1];
    const int* src = ei;
    const int* dstp = ei + E;
    const float* wm1 = (const float*)d_in[2];
    const float* wr1 = (const float*)d_in[3];
    const float* b1 = (const float*)d_in[4];
    const float* g1 = (const float*)d_in[5];
    const float* be1 = (const float*)d_in[6];
    const float* wm2 = (const float*)d_in[7];
    const float* wr2 = (const float*)d_in[8];
    const float* b2 = (const float*)d_in[9];
    const float* g2 = (const float*)d_in[10];
    const float* be2 = (const float*)d_in[11];
    const float* wm3 = (const float*)d_in[12];
    const float* wr3 = (const float*)d_in[13];
    const float* b3 = (const float*)d_in[14];
    const float* g3 = (const float*)d_in[15];
    const float* be3 = (const float*)d_in[16];
    const float* wm4 = (const float*)d_in[17];
    const float* wr4 = (const float*)d_in[18];
    const float* b4 = (const float*)d_in[19];
    float* out = (float*)d_out;

    // ws: bufA[N*256] | bufB[N*256] | inv[N] | deg[N+4] | rowptr[N+4] | cursor[N+4]
    //     | eidx[E] | partials[256] | bf16 W^T buffers (512 KB)
    float* Wp = (float*)d_ws;
    float* bufA = Wp;
    float* bufB = bufA + (size_t)N * 256;
    float* inv = bufB + (size_t)N * 256;
    int* deg = (int*)(inv + N);
    int* rowptr = deg + N + 4;
    int* cursor = rowptr + N + 4;
    int* eidx = cursor + N + 4;
    int* partials = eidx + E;
    u16* wt1m = (u16*)(partials + 256);
    u16* wt1r = wt1m + 256 * 128;
    u16* wt2m = wt1r + 256 * 128;
    u16* wt2r = wt2m + 256 * 256;
    u16* wt3m = wt2r + 256 * 256;
    u16* wt3r = wt3m + 128 * 256;

    const int nscan = cdiv(N, 1024);  // blocks for scan kernels (N<=262144 -> <=256)

    // ---- CSR build + weight prep ----
    zero_f4<<<cdiv(N, 1024), 256, 0, stream>>>((float4*)deg, cdiv(N, 4));
    count_deg<<<cdiv(E, 256), 256, 0, stream>>>(dstp, deg, E);
    partial_sums<<<nscan, 256, 0, stream>>>(deg, partials, N);
    scan_partials<<<1, 256, 0, stream>>>(partials, nscan);
    write_rowptr<<<nscan, 256, 0, stream>>>(deg, partials, rowptr, cursor, inv, N, E);
    fill_csr<<<cdiv(E, 256), 256, 0, stream>>>(src, dstp, cursor, eidx, E);
    transpose_cast<<<cdiv(128 * 256, 256), 256, 0, stream>>>(wm1, wt1m, 128, 256);
    transpose_cast<<<cdiv(128 * 256, 256), 256, 0, stream>>>(wr1, wt1r, 128, 256);
    transpose_cast<<<cdiv(256 * 256, 256), 256, 0, stream>>>(wm2, wt2m, 256, 256);
    transpose_cast<<<cdiv(256 * 256, 256), 256, 0, stream>>>(wr2, wt2r, 256, 256);
    transpose_cast<<<cdiv(256 * 128, 256), 256, 0, stream>>>(wm3, wt3m, 256, 128);
    transpose_cast<<<cdiv(256 * 128, 256), 256, 0, stream>>>(wr3, wt3r, 256, 128);

    // ---- layer 1: gather z (128-d) into bufB -> h1(bufA) ----
    float* agg1 = bufB;
    gather_agg128<<<cdiv(N, 8), 256, 0, stream>>>(z, rowptr, eidx, agg1, N);
    float* h1 = bufA;
    {
        dim3 g(cdiv(N, 128), 2);
        mfma_gemm<<<g, 256, 0, stream>>>(agg1, z, wt1m, wt1r, b1, inv, h1, N, 128, 256, 1, 1);
    }
    ln_relu<256><<<cdiv(N, 4), 256, 0, stream>>>(h1, g1, be1, N);

    // ---- layer 2: gather h1 (256-d) into bufB; in-place wide GEMM bufB -> h2(bufB) ----
    float* agg2 = bufB;
    gather_agg256<<<cdiv(N, 4), 256, 0, stream>>>(h1, rowptr, eidx, agg2, N);
    float* h2 = bufB;
    mfma_gemm_wide<<<cdiv(N, 64), 256, 0, stream>>>(agg2, h1, wt2m, wt2r, b2, inv, h2, N, 256);
    ln_relu<256><<<cdiv(N, 4), 256, 0, stream>>>(h2, g2, be2, N);

    // ---- layer 3: GEMM first (Dout=128), then gather ----
    float* y3 = bufA;
    float* r3 = bufA + (size_t)N * 128;
    {
        dim3 g(cdiv(N, 128), 1);
        mfma_gemm<<<g, 256, 0, stream>>>(h2, nullptr, wt3m, nullptr, nullptr, inv, y3, N, 256, 128, 0, 0);
        mfma_gemm<<<g, 256, 0, stream>>>(h2, nullptr, wt3r, nullptr, b3, inv, r3, N, 256, 128, 0, 0);
    }
    float* agg3 = bufB;
    gather_agg128<<<cdiv(N, 8), 256, 0, stream>>>(y3, rowptr, eidx, agg3, N);
    float* h3 = bufB + (size_t)N * 128;
    add_ln_relu128<<<cdiv(N, 4), 256, 0, stream>>>(agg3, inv, r3, g3, be3, h3, N);

    // ---- layer 4: GEMM first (Dout=9), fused gather+final ----
    float* y4 = bufA;
    float* r4 = bufA + (size_t)N * 9;
    gemm4<<<cdiv(N, 16), 320, 0, stream>>>(h3, wm4, wr4, b4, y4, r4, N);
    gather9_final<<<cdiv((long)N * 16, 256), 256, 0, stream>>>(y4, rowptr, eidx, inv, r4, out, N);
}

// Round 6
// 929.763 us; speedup vs baseline: 12.8885x; 1.2808x over previous
//
#include <hip/hip_runtime.h>
#include <hip/hip_bf16.h>

// GraphSAGE decoder, 4 layers. CSR-gather aggregation, bf16 feature tables,
// bf16-MFMA GEMMs with fp32 accumulate.
// Identity: segment_sum(x[src]) @ W == segment_sum((x@W)[src]); aggregate over
// the smaller of {Din, Dout} per layer.
// All activation tables stored bf16 (they'd be rounded to bf16 at the next
// GEMM anyway); gathers accumulate fp32, scale by inv, emit bf16.

#define EPS 1e-5f

typedef unsigned short u16;
typedef short bf16x8_t __attribute__((ext_vector_type(8)));
typedef float f32x4_t __attribute__((ext_vector_type(4)));

__device__ inline unsigned int bfpack(float a, float b) {
    unsigned int ua = __builtin_bit_cast(unsigned int, a);
    unsigned int ub = __builtin_bit_cast(unsigned int, b);
    ua += 0x7fffu + ((ua >> 16) & 1u);
    ub += 0x7fffu + ((ub >> 16) & 1u);
    return (ua >> 16) | (ub & 0xffff0000u);
}

__device__ inline u16 bfr(float a) {
    unsigned int u = __builtin_bit_cast(unsigned int, a);
    u += 0x7fffu + ((u >> 16) & 1u);
    return (u16)(u >> 16);
}

__device__ inline float bf2f(u16 v) {
    unsigned int u = ((unsigned int)v) << 16;
    return __builtin_bit_cast(float, u);
}

// ---------------- zero fill ----------------
__global__ __launch_bounds__(256) void zero_f4(float4* __restrict__ p, int n4) {
    int i = blockIdx.x * 256 + threadIdx.x;
    if (i < n4) p[i] = make_float4(0.f, 0.f, 0.f, 0.f);
}

// ---------------- fp32 -> bf16 cast (4 elems/thread) ----------------
__global__ __launch_bounds__(256) void cast_bf16(const float* __restrict__ x,
                                                 u16* __restrict__ y, int n4) {
    int i = blockIdx.x * 256 + threadIdx.x;
    if (i >= n4) return;
    float4 v = ((const float4*)x)[i];
    ((uint2*)y)[i] = make_uint2(bfpack(v.x, v.y), bfpack(v.z, v.w));
}

// ---------------- weight transpose+cast: W[K][N] fp32 -> WT[N][K] bf16 ----------------
__global__ __launch_bounds__(256) void transpose_cast(const float* __restrict__ W,
                                                      u16* __restrict__ WT, int K, int N) {
    int idx = blockIdx.x * 256 + threadIdx.x;
    if (idx >= K * N) return;
    int k = idx / N, n = idx - k * N;
    WT[(long)n * K + k] = bfr(W[idx]);
}

// ---------------- CSR build ----------------
__global__ __launch_bounds__(256) void count_deg(const int* __restrict__ dst,
                                                 int* __restrict__ deg, int E) {
    int e = blockIdx.x * 256 + threadIdx.x;
    if (e < E) atomicAdd(&deg[dst[e]], 1);
}

__global__ __launch_bounds__(256) void partial_sums(const int* __restrict__ deg,
                                                    int* __restrict__ partials, int N) {
    __shared__ int lds[4];
    int tid = threadIdx.x;
    int base = blockIdx.x * 1024 + tid * 4;
    int s = 0;
    if (base + 3 < N) {
        int4 v = *(const int4*)(deg + base);
        s = v.x + v.y + v.z + v.w;
    } else {
        for (int i = 0; i < 4; ++i)
            if (base + i < N) s += deg[base + i];
    }
#pragma unroll
    for (int m = 32; m >= 1; m >>= 1) s += __shfl_xor(s, m);
    if ((tid & 63) == 0) lds[tid >> 6] = s;
    __syncthreads();
    if (tid == 0) partials[blockIdx.x] = lds[0] + lds[1] + lds[2] + lds[3];
}

__global__ __launch_bounds__(256) void scan_partials(int* __restrict__ partials, int nb) {
    __shared__ int lds[256];
    int tid = threadIdx.x;
    int v = (tid < nb) ? partials[tid] : 0;
    lds[tid] = v;
    __syncthreads();
    for (int off = 1; off < 256; off <<= 1) {
        int t = (tid >= off) ? lds[tid - off] : 0;
        __syncthreads();
        lds[tid] += t;
        __syncthreads();
    }
    if (tid < nb) partials[tid] = lds[tid] - v;
}

__global__ __launch_bounds__(256) void write_rowptr(const int* __restrict__ deg,
                                                    const int* __restrict__ partials,
                                                    int* __restrict__ rowptr,
                                                    int* __restrict__ cursor,
                                                    float* __restrict__ inv, int N, int E) {
    __shared__ int lds[256];
    int tid = threadIdx.x;
    int base = blockIdx.x * 1024 + tid * 4;
    int d[4];
    int s = 0;
#pragma unroll
    for (int i = 0; i < 4; ++i) {
        d[i] = (base + i < N) ? deg[base + i] : 0;
        s += d[i];
    }
    lds[tid] = s;
    __syncthreads();
    for (int off = 1; off < 256; off <<= 1) {
        int t = (tid >= off) ? lds[tid - off] : 0;
        __syncthreads();
        lds[tid] += t;
        __syncthreads();
    }
    int run = partials[blockIdx.x] + lds[tid] - s;
#pragma unroll
    for (int i = 0; i < 4; ++i) {
        int idx = base + i;
        if (idx < N) {
            rowptr[idx] = run;
            cursor[idx] = run;
            inv[idx] = 1.0f / fmaxf((float)d[i], 1.0f);
            run += d[i];
        }
    }
    if (blockIdx.x == 0 && tid == 0) rowptr[N] = E;
}

__global__ __launch_bounds__(256) void fill_csr(const int* __restrict__ src,
                                                const int* __restrict__ dst,
                                                int* __restrict__ cursor,
                                                int* __restrict__ eidx, int E) {
    int e = blockIdx.x * 256 + threadIdx.x;
    if (e >= E) return;
    int p = atomicAdd(&cursor[dst[e]], 1);
    eidx[p] = src[e];
}

// ---------------- gathers over bf16 tables, fp32 accumulate, bf16 out ----------------
// D=256: wave per row, ushort4 (4 elems) per lane. Emits mean (scaled by inv).
__global__ __launch_bounds__(256) void gather_scale256(const u16* __restrict__ x,
                                                       const int* __restrict__ rowptr,
                                                       const int* __restrict__ eidx,
                                                       const float* __restrict__ inv,
                                                       u16* __restrict__ agg, int N) {
    int wave = threadIdx.x >> 6;
    int lane = threadIdx.x & 63;
    int row = blockIdx.x * 4 + wave;
    if (row >= N) return;
    int beg = rowptr[row], end = rowptr[row + 1];
    const ushort4* xv = (const ushort4*)x;
    float a0 = 0.f, a1 = 0.f, a2 = 0.f, a3 = 0.f;
    float c0 = 0.f, c1 = 0.f, c2 = 0.f, c3 = 0.f;
    int j = beg;
    for (; j + 1 < end; j += 2) {
        ushort4 v = xv[(long)eidx[j] * 64 + lane];
        ushort4 w = xv[(long)eidx[j + 1] * 64 + lane];
        a0 += bf2f(v.x); a1 += bf2f(v.y); a2 += bf2f(v.z); a3 += bf2f(v.w);
        c0 += bf2f(w.x); c1 += bf2f(w.y); c2 += bf2f(w.z); c3 += bf2f(w.w);
    }
    if (j < end) {
        ushort4 v = xv[(long)eidx[j] * 64 + lane];
        a0 += bf2f(v.x); a1 += bf2f(v.y); a2 += bf2f(v.z); a3 += bf2f(v.w);
    }
    float s = inv[row];
    a0 = (a0 + c0) * s; a1 = (a1 + c1) * s; a2 = (a2 + c2) * s; a3 = (a3 + c3) * s;
    ((uint2*)agg)[(long)row * 64 + lane] = make_uint2(bfpack(a0, a1), bfpack(a2, a3));
}

// D=128: half-wave per row.
__global__ __launch_bounds__(256) void gather_scale128(const u16* __restrict__ x,
                                                       const int* __restrict__ rowptr,
                                                       const int* __restrict__ eidx,
                                                       const float* __restrict__ inv,
                                                       u16* __restrict__ agg, int N) {
    int half = threadIdx.x >> 5;
    int lane = threadIdx.x & 31;
    int row = blockIdx.x * 8 + half;
    if (row >= N) return;
    int beg = rowptr[row], end = rowptr[row + 1];
    const ushort4* xv = (const ushort4*)x;
    float a0 = 0.f, a1 = 0.f, a2 = 0.f, a3 = 0.f;
    float c0 = 0.f, c1 = 0.f, c2 = 0.f, c3 = 0.f;
    int j = beg;
    for (; j + 1 < end; j += 2) {
        ushort4 v = xv[(long)eidx[j] * 32 + lane];
        ushort4 w = xv[(long)eidx[j + 1] * 32 + lane];
        a0 += bf2f(v.x); a1 += bf2f(v.y); a2 += bf2f(v.z); a3 += bf2f(v.w);
        c0 += bf2f(w.x); c1 += bf2f(w.y); c2 += bf2f(w.z); c3 += bf2f(w.w);
    }
    if (j < end) {
        ushort4 v = xv[(long)eidx[j] * 32 + lane];
        a0 += bf2f(v.x); a1 += bf2f(v.y); a2 += bf2f(v.z); a3 += bf2f(v.w);
    }
    float s = inv[row];
    a0 = (a0 + c0) * s; a1 = (a1 + c1) * s; a2 = (a2 + c2) * s; a3 = (a3 + c3) * s;
    ((uint2*)agg)[(long)row * 32 + lane] = make_uint2(bfpack(a0, a1), bfpack(a2, a3));
}

// L3 fused: h3 = relu(LN(gather_mean(y3) + r3)) * g + be, D=128, half-wave/row.
__global__ __launch_bounds__(256) void gather_add_ln_relu128(const u16* __restrict__ y,
                                                             const int* __restrict__ rowptr,
                                                             const int* __restrict__ eidx,
                                                             const float* __restrict__ inv,
                                                             const u16* __restrict__ r,
                                                             const float* __restrict__ g,
                                                             const float* __restrict__ be,
                                                             u16* __restrict__ out, int N) {
    int half = threadIdx.x >> 5;
    int lane = threadIdx.x & 31;
    int row = blockIdx.x * 8 + half;
    if (row >= N) return;
    int beg = rowptr[row], end = rowptr[row + 1];
    const ushort4* xv = (const ushort4*)y;
    float a0 = 0.f, a1 = 0.f, a2 = 0.f, a3 = 0.f;
    float c0 = 0.f, c1 = 0.f, c2 = 0.f, c3 = 0.f;
    int j = beg;
    for (; j + 1 < end; j += 2) {
        ushort4 v = xv[(long)eidx[j] * 32 + lane];
        ushort4 w = xv[(long)eidx[j + 1] * 32 + lane];
        a0 += bf2f(v.x); a1 += bf2f(v.y); a2 += bf2f(v.z); a3 += bf2f(v.w);
        c0 += bf2f(w.x); c1 += bf2f(w.y); c2 += bf2f(w.z); c3 += bf2f(w.w);
    }
    if (j < end) {
        ushort4 v = xv[(long)eidx[j] * 32 + lane];
        a0 += bf2f(v.x); a1 += bf2f(v.y); a2 += bf2f(v.z); a3 += bf2f(v.w);
    }
    float iv = inv[row];
    ushort4 rr = ((const ushort4*)r)[(long)row * 32 + lane];
    float v0 = (a0 + c0) * iv + bf2f(rr.x);
    float v1 = (a1 + c1) * iv + bf2f(rr.y);
    float v2 = (a2 + c2) * iv + bf2f(rr.z);
    float v3 = (a3 + c3) * iv + bf2f(rr.w);
    float s = v0 + v1 + v2 + v3;
    float ss = v0 * v0 + v1 * v1 + v2 * v2 + v3 * v3;
#pragma unroll
    for (int m = 16; m >= 1; m >>= 1) {  // reduce within 32-lane half
        s += __shfl_xor(s, m);
        ss += __shfl_xor(ss, m);
    }
    float mean = s / 128.f;
    float var = ss / 128.f - mean * mean;
    float rs = rsqrtf(var + EPS);
    int col = lane * 4;
    v0 = fmaxf((v0 - mean) * rs * g[col + 0] + be[col + 0], 0.f);
    v1 = fmaxf((v1 - mean) * rs * g[col + 1] + be[col + 1], 0.f);
    v2 = fmaxf((v2 - mean) * rs * g[col + 2] + be[col + 2], 0.f);
    v3 = fmaxf((v3 - mean) * rs * g[col + 3] + be[col + 3], 0.f);
    ((uint2*)out)[(long)row * 32 + lane] = make_uint2(bfpack(v0, v1), bfpack(v2, v3));
}

__global__ __launch_bounds__(256) void gather9_final(const float* __restrict__ y,
                                                     const int* __restrict__ rowptr,
                                                     const int* __restrict__ eidx,
                                                     const float* __restrict__ inv,
                                                     const float* __restrict__ r,
                                                     float* __restrict__ out, int N) {
    int idx = blockIdx.x * 256 + threadIdx.x;
    int row = idx >> 4;
    int c = idx & 15;
    if (row >= N || c >= 9) return;
    int beg = rowptr[row], end = rowptr[row + 1];
    float a = 0.f;
    for (int j = beg; j < end; ++j) a += y[(long)eidx[j] * 9 + c];
    out[(long)row * 9 + c] = a * inv[row] + r[(long)row * 9 + c];
}

// ---------------- MFMA GEMM (bf16 A, bf16 out): out = A1@W1 [+ A2@W2] + bias ----------
// BM=128, BN=128, BK=32. 4 waves, each 64x64.
__global__ __launch_bounds__(256) void mfma_gemm_bf(const u16* __restrict__ A1,
                                                    const u16* __restrict__ A2,
                                                    const u16* __restrict__ WT1,
                                                    const u16* __restrict__ WT2,
                                                    const float* __restrict__ bias,
                                                    u16* __restrict__ out, int M, int K,
                                                    int Dout, int two_pass) {
    __shared__ u16 As[128 * 40];
    __shared__ u16 Ws[128 * 40];
    const int tid = threadIdx.x;
    const int bm = blockIdx.x * 128;
    const int bn = blockIdx.y * 128;
    const int l = tid & 63;
    const int w = tid >> 6;
    const int wr = (w & 1) * 64;
    const int wc = (w >> 1) * 64;
    const int ln15 = l & 15;
    const int quad = l >> 4;

    f32x4_t acc[4][4];
#pragma unroll
    for (int i = 0; i < 4; ++i)
#pragma unroll
        for (int j = 0; j < 4; ++j) acc[i][j] = (f32x4_t){0.f, 0.f, 0.f, 0.f};

    const int sr = tid >> 1;
    const int kh = (tid & 1) * 16;

    const int npass = two_pass ? 2 : 1;
    for (int pass = 0; pass < npass; ++pass) {
        const u16* A = pass ? A2 : A1;
        const u16* WT = pass ? WT2 : WT1;
        for (int k0 = 0; k0 < K; k0 += 32) {
            uint4 q0 = make_uint4(0, 0, 0, 0), q1 = make_uint4(0, 0, 0, 0);
            int gr = bm + sr;
            if (gr < M) {
                const u16* ap = A + (long)gr * K + k0 + kh;
                q0 = ((const uint4*)ap)[0];
                q1 = ((const uint4*)ap)[1];
            }
            *(uint4*)(As + sr * 40 + kh) = q0;
            *(uint4*)(As + sr * 40 + kh + 8) = q1;
            const u16* wp = WT + (long)(bn + sr) * K + k0 + kh;
            *(uint4*)(Ws + sr * 40 + kh) = ((const uint4*)wp)[0];
            *(uint4*)(Ws + sr * 40 + kh + 8) = ((const uint4*)wp)[1];
            __syncthreads();

            bf16x8_t a[4], b[4];
#pragma unroll
            for (int i = 0; i < 4; ++i)
                a[i] = *(const bf16x8_t*)(As + (wr + i * 16 + ln15) * 40 + quad * 8);
#pragma unroll
            for (int j = 0; j < 4; ++j)
                b[j] = *(const bf16x8_t*)(Ws + (wc + j * 16 + ln15) * 40 + quad * 8);
#pragma unroll
            for (int i = 0; i < 4; ++i)
#pragma unroll
                for (int j = 0; j < 4; ++j)
                    acc[i][j] = __builtin_amdgcn_mfma_f32_16x16x32_bf16(a[i], b[j], acc[i][j], 0, 0, 0);
            __syncthreads();
        }
    }

#pragma unroll
    for (int j = 0; j < 4; ++j) {
        int col = bn + wc + j * 16 + ln15;
        float bv = bias ? bias[col] : 0.f;
#pragma unroll
        for (int i = 0; i < 4; ++i) {
            int row0 = bm + wr + i * 16 + quad * 4;
            f32x4_t c = acc[i][j];
#pragma unroll
            for (int p = 0; p < 4; ++p) {
                int row = row0 + p;
                if (row < M) out[(long)row * Dout + col] = bfr(c[p] + bv);
            }
        }
    }
}

// ---------------- L3 dual GEMM: ya = A@WTa (no bias), yb = A@WTb + bias ----------------
// Same tile as mfma_gemm_bf; blockIdx.y selects (WT, out, bias). Dout=128.
__global__ __launch_bounds__(256) void mfma_gemm_dual(const u16* __restrict__ A,
                                                      const u16* __restrict__ WTa,
                                                      const u16* __restrict__ WTb,
                                                      const float* __restrict__ biasb,
                                                      u16* __restrict__ outa,
                                                      u16* __restrict__ outb, int M, int K) {
    __shared__ u16 As[128 * 40];
    __shared__ u16 Ws[128 * 40];
    const u16* WT = blockIdx.y ? WTb : WTa;
    u16* out = blockIdx.y ? outb : outa;
    const float* bias = blockIdx.y ? biasb : nullptr;
    const int tid = threadIdx.x;
    const int bm = blockIdx.x * 128;
    const int l = tid & 63;
    const int w = tid >> 6;
    const int wr = (w & 1) * 64;
    const int wc = (w >> 1) * 64;
    const int ln15 = l & 15;
    const int quad = l >> 4;

    f32x4_t acc[4][4];
#pragma unroll
    for (int i = 0; i < 4; ++i)
#pragma unroll
        for (int j = 0; j < 4; ++j) acc[i][j] = (f32x4_t){0.f, 0.f, 0.f, 0.f};

    const int sr = tid >> 1;
    const int kh = (tid & 1) * 16;

    for (int k0 = 0; k0 < K; k0 += 32) {
        uint4 q0 = make_uint4(0, 0, 0, 0), q1 = make_uint4(0, 0, 0, 0);
        int gr = bm + sr;
        if (gr < M) {
            const u16* ap = A + (long)gr * K + k0 + kh;
            q0 = ((const uint4*)ap)[0];
            q1 = ((const uint4*)ap)[1];
        }
        *(uint4*)(As + sr * 40 + kh) = q0;
        *(uint4*)(As + sr * 40 + kh + 8) = q1;
        const u16* wp = WT + (long)sr * K + k0 + kh;
        *(uint4*)(Ws + sr * 40 + kh) = ((const uint4*)wp)[0];
        *(uint4*)(Ws + sr * 40 + kh + 8) = ((const uint4*)wp)[1];
        __syncthreads();

        bf16x8_t a[4], b[4];
#pragma unroll
        for (int i = 0; i < 4; ++i)
            a[i] = *(const bf16x8_t*)(As + (wr + i * 16 + ln15) * 40 + quad * 8);
#pragma unroll
        for (int j = 0; j < 4; ++j)
            b[j] = *(const bf16x8_t*)(Ws + (wc + j * 16 + ln15) * 40 + quad * 8);
#pragma unroll
        for (int i = 0; i < 4; ++i)
#pragma unroll
            for (int j = 0; j < 4; ++j)
                acc[i][j] = __builtin_amdgcn_mfma_f32_16x16x32_bf16(a[i], b[j], acc[i][j], 0, 0, 0);
        __syncthreads();
    }

#pragma unroll
    for (int j = 0; j < 4; ++j) {
        int col = wc + j * 16 + ln15;
        float bv = bias ? bias[col] : 0.f;
#pragma unroll
        for (int i = 0; i < 4; ++i) {
            int row0 = bm + wr + i * 16 + quad * 4;
            f32x4_t c = acc[i][j];
#pragma unroll
            for (int p = 0; p < 4; ++p) {
                int row = row0 + p;
                if (row < M) out[(long)row * 128 + col] = bfr(c[p] + bv);
            }
        }
    }
}

// ---------------- MFMA GEMM wide in-place (bf16): out = A1@W1 + A2@W2 + bias ----------
// BM=64, BN=256(=Dout), BK=32. out MAY alias A1 (row ownership).
__global__ __launch_bounds__(256) void mfma_gemm_wide_bf(const u16* A1,
                                                         const u16* __restrict__ A2,
                                                         const u16* __restrict__ WT1,
                                                         const u16* __restrict__ WT2,
                                                         const float* __restrict__ bias,
                                                         u16* out, int M, int K) {
    __shared__ u16 As[64 * 40];
    __shared__ u16 Ws[256 * 40];
    const int tid = threadIdx.x;
    const int bm = blockIdx.x * 64;
    const int l = tid & 63;
    const int w = tid >> 6;
    const int wr = (w & 1) * 32;
    const int wc = (w >> 1) * 128;
    const int ln15 = l & 15;
    const int quad = l >> 4;

    f32x4_t acc[2][8];
#pragma unroll
    for (int i = 0; i < 2; ++i)
#pragma unroll
        for (int j = 0; j < 8; ++j) acc[i][j] = (f32x4_t){0.f, 0.f, 0.f, 0.f};

    const int ar = tid >> 2;
    const int akh = (tid & 3) * 8;

    for (int pass = 0; pass < 2; ++pass) {
        const u16* A = pass ? A2 : A1;
        const u16* WT = pass ? WT2 : WT1;
        for (int k0 = 0; k0 < K; k0 += 32) {
            uint4 q0 = make_uint4(0, 0, 0, 0);
            int gr = bm + ar;
            if (gr < M) q0 = *(const uint4*)(A + (long)gr * K + k0 + akh);
            *(uint4*)(As + ar * 40 + akh) = q0;
            const u16* wp = WT + (long)tid * K + k0;
            *(uint4*)(Ws + tid * 40 + 0) = ((const uint4*)wp)[0];
            *(uint4*)(Ws + tid * 40 + 8) = ((const uint4*)wp)[1];
            *(uint4*)(Ws + tid * 40 + 16) = ((const uint4*)wp)[2];
            *(uint4*)(Ws + tid * 40 + 24) = ((const uint4*)wp)[3];
            __syncthreads();

            bf16x8_t a[2], b[8];
#pragma unroll
            for (int i = 0; i < 2; ++i)
                a[i] = *(const bf16x8_t*)(As + (wr + i * 16 + ln15) * 40 + quad * 8);
#pragma unroll
            for (int j = 0; j < 8; ++j)
                b[j] = *(const bf16x8_t*)(Ws + (wc + j * 16 + ln15) * 40 + quad * 8);
#pragma unroll
            for (int i = 0; i < 2; ++i)
#pragma unroll
                for (int j = 0; j < 8; ++j)
                    acc[i][j] = __builtin_amdgcn_mfma_f32_16x16x32_bf16(a[i], b[j], acc[i][j], 0, 0, 0);
            __syncthreads();
        }
    }

#pragma unroll
    for (int j = 0; j < 8; ++j) {
        int col = wc + j * 16 + ln15;
        float bv = bias[col];
#pragma unroll
        for (int i = 0; i < 2; ++i) {
            int row0 = bm + wr + i * 16 + quad * 4;
            f32x4_t c = acc[i][j];
#pragma unroll
            for (int p = 0; p < 4; ++p) {
                int row = row0 + p;
                if (row < M) out[(long)row * 256 + col] = bfr(c[p] + bv);
            }
        }
    }
}

// ---------------- LayerNorm + ReLU over bf16, wave per row, in place ----------------
__global__ __launch_bounds__(256) void ln_relu_bf256(u16* __restrict__ h,
                                                     const float* __restrict__ g,
                                                     const float* __restrict__ be, int M) {
    int wave = threadIdx.x >> 6;
    int lane = threadIdx.x & 63;
    int row = blockIdx.x * 4 + wave;
    if (row >= M) return;
    u16* p = h + (long)row * 256 + lane * 4;
    ushort4 ld = *(const ushort4*)p;
    float v0 = bf2f(ld.x), v1 = bf2f(ld.y), v2 = bf2f(ld.z), v3 = bf2f(ld.w);
    float s = v0 + v1 + v2 + v3;
    float ss = v0 * v0 + v1 * v1 + v2 * v2 + v3 * v3;
#pragma unroll
    for (int m = 32; m >= 1; m >>= 1) {
        s += __shfl_xor(s, m);
        ss += __shfl_xor(ss, m);
    }
    float mean = s / 256.f;
    float var = ss / 256.f - mean * mean;
    float rs = rsqrtf(var + EPS);
    int col = lane * 4;
    v0 = fmaxf((v0 - mean) * rs * g[col + 0] + be[col + 0], 0.f);
    v1 = fmaxf((v1 - mean) * rs * g[col + 1] + be[col + 1], 0.f);
    v2 = fmaxf((v2 - mean) * rs * g[col + 2] + be[col + 2], 0.f);
    v3 = fmaxf((v3 - mean) * rs * g[col + 3] + be[col + 3], 0.f);
    *(uint2*)p = make_uint2(bfpack(v0, v1), bfpack(v2, v3));
}

// ---------------- layer 4 small GEMM (bf16 x): y = x@wm (Nx9), r = x@wr + b ----------
__global__ __launch_bounds__(320) void gemm4_bf(const u16* __restrict__ x,
                                                const float* __restrict__ wm,
                                                const float* __restrict__ wrt,
                                                const float* __restrict__ b,
                                                float* __restrict__ y, float* __restrict__ r,
                                                int M) {
    __shared__ float xs[16][132];
    __shared__ float ws[128][20];
    int tid = threadIdx.x;
    int m0 = blockIdx.x * 16;
    for (int idx = tid; idx < 16 * 128; idx += 320) {
        int rr = idx >> 7, kk = idx & 127;
        int gm = m0 + rr;
        xs[rr][kk] = (gm < M) ? bf2f(x[(long)gm * 128 + kk]) : 0.f;
    }
    for (int idx = tid; idx < 128 * 18; idx += 320) {
        int kk = idx / 18, cc = idx % 18;
        ws[kk][cc] = (cc < 9) ? wm[kk * 9 + cc] : wrt[kk * 9 + cc - 9];
    }
    __syncthreads();
    if (tid < 288) {
        int rr = tid / 18, cc = tid % 18;
        float acc = 0.f;
#pragma unroll 8
        for (int kk = 0; kk < 128; ++kk) acc += xs[rr][kk] * ws[kk][cc];
        int gm = m0 + rr;
        if (gm < M) {
            if (cc < 9) y[(long)gm * 9 + cc] = acc;
            else r[(long)gm * 9 + cc - 9] = acc + b[cc - 9];
        }
    }
}

static inline int cdiv(long a, long b) { return (int)((a + b - 1) / b); }

extern "C" void kernel_launch(void* const* d_in, const int* in_sizes, int n_in,
                              void* d_out, int out_size, void* d_ws, size_t ws_size,
                              hipStream_t stream) {
    const int N = in_sizes[0] / 128;
    const int E = in_sizes[1] / 2;

    const float* z = (const float*)d_in[0];
    const int* ei = (const int*)d_in[1];
    const int* src = ei;
    const int* dstp = ei + E;
    const float* wm1 = (const float*)d_in[2];
    const float* wr1 = (const float*)d_in[3];
    const float* b1 = (const float*)d_in[4];
    const float* g1 = (const float*)d_in[5];
    const float* be1 = (const float*)d_in[6];
    const float* wm2 = (const float*)d_in[7];
    const float* wr2 = (const float*)d_in[8];
    const float* b2 = (const float*)d_in[9];
    const float* g2 = (const float*)d_in[10];
    const float* be2 = (const float*)d_in[11];
    const float* wm3 = (const float*)d_in[12];
    const float* wr3 = (const float*)d_in[13];
    const float* b3 = (const float*)d_in[14];
    const float* g3 = (const float*)d_in[15];
    const float* be3 = (const float*)d_in[16];
    const float* wm4 = (const float*)d_in[17];
    const float* wr4 = (const float*)d_in[18];
    const float* b4 = (const float*)d_in[19];
    float* out = (float*)d_out;

    // ws layout (u16/float/int; all offsets 16B-aligned):
    // aggh2[N*256 u16] | h1b[N*256 u16] | zb[N*128 u16] | agg1[N*128 u16]
    // | inv[N f32] | deg[N+4] | rowptr[N+4] | cursor[N+4] | partials[256] | eidx[E]
    // | 6x WT bf16
    u16* aggh2 = (u16*)d_ws;
    u16* h1b = aggh2 + (size_t)N * 256;
    u16* zb = h1b + (size_t)N * 256;
    u16* agg1 = zb + (size_t)N * 128;
    float* inv = (float*)(agg1 + (size_t)N * 128);
    int* deg = (int*)(inv + N);
    int* rowptr = deg + N + 4;
    int* cursor = rowptr + N + 4;
    int* partials = cursor + N + 4;
    int* eidx = partials + 256;
    u16* wt1m = (u16*)(eidx + E);
    u16* wt1r = wt1m + 256 * 128;
    u16* wt2m = wt1r + 256 * 128;
    u16* wt2r = wt2m + 256 * 256;
    u16* wt3m = wt2r + 256 * 256;
    u16* wt3r = wt3m + 128 * 256;

    // aliases (liveness-checked):
    u16* y3b = agg1;                  // agg1 dead after GEMM1
    u16* r3b = zb;                    // zb dead after GEMM1
    u16* h3b = h1b;                   // h1b dead after GEMM2
    float* y4 = (float*)aggh2;        // h2 dead after dual GEMM3
    float* r4 = y4 + (size_t)N * 9;

    const int nscan = cdiv(N, 1024);

    // ---- prep: z cast, CSR build, weight transpose/cast ----
    cast_bf16<<<cdiv((long)N * 32, 256), 256, 0, stream>>>(z, zb, N * 32);
    zero_f4<<<cdiv(N, 1024), 256, 0, stream>>>((float4*)deg, cdiv(N, 4));
    count_deg<<<cdiv(E, 256), 256, 0, stream>>>(dstp, deg, E);
    partial_sums<<<nscan, 256, 0, stream>>>(deg, partials, N);
    scan_partials<<<1, 256, 0, stream>>>(partials, nscan);
    write_rowptr<<<nscan, 256, 0, stream>>>(deg, partials, rowptr, cursor, inv, N, E);
    fill_csr<<<cdiv(E, 256), 256, 0, stream>>>(src, dstp, cursor, eidx, E);
    transpose_cast<<<cdiv(128 * 256, 256), 256, 0, stream>>>(wm1, wt1m, 128, 256);
    transpose_cast<<<cdiv(128 * 256, 256), 256, 0, stream>>>(wr1, wt1r, 128, 256);
    transpose_cast<<<cdiv(256 * 256, 256), 256, 0, stream>>>(wm2, wt2m, 256, 256);
    transpose_cast<<<cdiv(256 * 256, 256), 256, 0, stream>>>(wr2, wt2r, 256, 256);
    transpose_cast<<<cdiv(256 * 128, 256), 256, 0, stream>>>(wm3, wt3m, 256, 128);
    transpose_cast<<<cdiv(256 * 128, 256), 256, 0, stream>>>(wr3, wt3r, 256, 128);

    // ---- layer 1 ----
    gather_scale128<<<cdiv(N, 8), 256, 0, stream>>>(zb, rowptr, eidx, inv, agg1, N);
    {
        dim3 g(cdiv(N, 128), 2);
        mfma_gemm_bf<<<g, 256, 0, stream>>>(agg1, zb, wt1m, wt1r, b1, h1b, N, 128, 256, 1);
    }
    ln_relu_bf256<<<cdiv(N, 4), 256, 0, stream>>>(h1b, g1, be1, N);

    // ---- layer 2 (in-place wide GEMM over agg buffer) ----
    gather_scale256<<<cdiv(N, 4), 256, 0, stream>>>(h1b, rowptr, eidx, inv, aggh2, N);
    mfma_gemm_wide_bf<<<cdiv(N, 64), 256, 0, stream>>>(aggh2, h1b, wt2m, wt2r, b2, aggh2, N, 256);
    ln_relu_bf256<<<cdiv(N, 4), 256, 0, stream>>>(aggh2, g2, be2, N);  // h2 = aggh2

    // ---- layer 3: dual GEMM then fused gather+add+LN+ReLU ----
    {
        dim3 g(cdiv(N, 128), 2);
        mfma_gemm_dual<<<g, 256, 0, stream>>>(aggh2, wt3m, wt3r, b3, y3b, r3b, N, 256);
    }
    gather_add_ln_relu128<<<cdiv(N, 8), 256, 0, stream>>>(y3b, rowptr, eidx, inv, r3b, g3, be3, h3b, N);

    // ---- layer 4 ----
    gemm4_bf<<<cdiv(N, 16), 320, 0, stream>>>(h3b, wm4, wr4, b4, y4, r4, N);
    gather9_final<<<cdiv((long)N * 16, 256), 256, 0, stream>>>(y4, rowptr, eidx, inv, r4, out, N);
}

// Round 7
// 891.553 us; speedup vs baseline: 13.4408x; 1.0429x over previous
//
#include <hip/hip_runtime.h>
#include <hip/hip_bf16.h>

// GraphSAGE decoder, 4 layers. CSR-gather aggregation, bf16 feature tables,
// bf16-MFMA GEMMs with fp32 accumulate, LN fused into GEMM epilogues.
// Identity: segment_sum(x[src]) @ W == segment_sum((x@W)[src]); aggregate over
// the smaller of {Din, Dout} per layer.

#define EPS 1e-5f

typedef unsigned short u16;
typedef short bf16x8_t __attribute__((ext_vector_type(8)));
typedef float f32x4_t __attribute__((ext_vector_type(4)));

__device__ inline unsigned int bfpack(float a, float b) {
    unsigned int ua = __builtin_bit_cast(unsigned int, a);
    unsigned int ub = __builtin_bit_cast(unsigned int, b);
    ua += 0x7fffu + ((ua >> 16) & 1u);
    ub += 0x7fffu + ((ub >> 16) & 1u);
    return (ua >> 16) | (ub & 0xffff0000u);
}

__device__ inline u16 bfr(float a) {
    unsigned int u = __builtin_bit_cast(unsigned int, a);
    u += 0x7fffu + ((u >> 16) & 1u);
    return (u16)(u >> 16);
}

__device__ inline float bf2f(u16 v) {
    unsigned int u = ((unsigned int)v) << 16;
    return __builtin_bit_cast(float, u);
}

// ---------------- zero fill ----------------
__global__ __launch_bounds__(256) void zero_f4(float4* __restrict__ p, int n4) {
    int i = blockIdx.x * 256 + threadIdx.x;
    if (i < n4) p[i] = make_float4(0.f, 0.f, 0.f, 0.f);
}

// ---------------- fp32 -> bf16 cast ----------------
__global__ __launch_bounds__(256) void cast_bf16(const float* __restrict__ x,
                                                 u16* __restrict__ y, int n4) {
    int i = blockIdx.x * 256 + threadIdx.x;
    if (i >= n4) return;
    float4 v = ((const float4*)x)[i];
    ((uint2*)y)[i] = make_uint2(bfpack(v.x, v.y), bfpack(v.z, v.w));
}

// ---------------- all 6 weight transposes in one launch ----------------
struct WtJobs {
    const float* W[6];
    u16* WT[6];
    int K[6], N[6];
};
__global__ __launch_bounds__(256) void transpose_cast6(WtJobs jobs) {
    int j = blockIdx.y;
    int idx = blockIdx.x * 256 + threadIdx.x;
    int K = jobs.K[j], Nn = jobs.N[j];
    if (idx >= K * Nn) return;
    int k = idx / Nn, n = idx - k * Nn;
    jobs.WT[j][(long)n * K + k] = bfr(jobs.W[j][idx]);
}

// ---------------- CSR build ----------------
__global__ __launch_bounds__(256) void count_deg(const int* __restrict__ dst,
                                                 int* __restrict__ deg, int E) {
    int e = blockIdx.x * 256 + threadIdx.x;
    if (e < E) atomicAdd(&deg[dst[e]], 1);
}

__global__ __launch_bounds__(256) void partial_sums(const int* __restrict__ deg,
                                                    int* __restrict__ partials, int N) {
    __shared__ int lds[4];
    int tid = threadIdx.x;
    int base = blockIdx.x * 1024 + tid * 4;
    int s = 0;
    if (base + 3 < N) {
        int4 v = *(const int4*)(deg + base);
        s = v.x + v.y + v.z + v.w;
    } else {
        for (int i = 0; i < 4; ++i)
            if (base + i < N) s += deg[base + i];
    }
#pragma unroll
    for (int m = 32; m >= 1; m >>= 1) s += __shfl_xor(s, m);
    if ((tid & 63) == 0) lds[tid >> 6] = s;
    __syncthreads();
    if (tid == 0) partials[blockIdx.x] = lds[0] + lds[1] + lds[2] + lds[3];
}

__global__ __launch_bounds__(256) void scan_partials(int* __restrict__ partials, int nb) {
    __shared__ int lds[256];
    int tid = threadIdx.x;
    int v = (tid < nb) ? partials[tid] : 0;
    lds[tid] = v;
    __syncthreads();
    for (int off = 1; off < 256; off <<= 1) {
        int t = (tid >= off) ? lds[tid - off] : 0;
        __syncthreads();
        lds[tid] += t;
        __syncthreads();
    }
    if (tid < nb) partials[tid] = lds[tid] - v;
}

__global__ __launch_bounds__(256) void write_rowptr(const int* __restrict__ deg,
                                                    const int* __restrict__ partials,
                                                    int* __restrict__ rowptr,
                                                    int* __restrict__ cursor,
                                                    float* __restrict__ inv, int N, int E) {
    __shared__ int lds[256];
    int tid = threadIdx.x;
    int base = blockIdx.x * 1024 + tid * 4;
    int d[4];
    int s = 0;
#pragma unroll
    for (int i = 0; i < 4; ++i) {
        d[i] = (base + i < N) ? deg[base + i] : 0;
        s += d[i];
    }
    lds[tid] = s;
    __syncthreads();
    for (int off = 1; off < 256; off <<= 1) {
        int t = (tid >= off) ? lds[tid - off] : 0;
        __syncthreads();
        lds[tid] += t;
        __syncthreads();
    }
    int run = partials[blockIdx.x] + lds[tid] - s;
#pragma unroll
    for (int i = 0; i < 4; ++i) {
        int idx = base + i;
        if (idx < N) {
            rowptr[idx] = run;
            cursor[idx] = run;
            inv[idx] = 1.0f / fmaxf((float)d[i], 1.0f);
            run += d[i];
        }
    }
    if (blockIdx.x == 0 && tid == 0) rowptr[N] = E;
}

// eidx written via atomicExch: routes through the coherence point, avoiding
// the 16x partial-line L2 write-back amplification a plain store showed (R6).
__global__ __launch_bounds__(256) void fill_csr(const int* __restrict__ src,
                                                const int* __restrict__ dst,
                                                int* __restrict__ cursor,
                                                int* __restrict__ eidx, int E) {
    int e = blockIdx.x * 256 + threadIdx.x;
    if (e >= E) return;
    int p = atomicAdd(&cursor[dst[e]], 1);
    atomicExch(&eidx[p], src[e]);
}

// ---------------- gathers over bf16 tables, fp32 accumulate, bf16 out ----------------
__global__ __launch_bounds__(256) void gather_scale256(const u16* __restrict__ x,
                                                       const int* __restrict__ rowptr,
                                                       const int* __restrict__ eidx,
                                                       const float* __restrict__ inv,
                                                       u16* __restrict__ agg, int N) {
    int wave = threadIdx.x >> 6;
    int lane = threadIdx.x & 63;
    int row = blockIdx.x * 4 + wave;
    if (row >= N) return;
    int beg = rowptr[row], end = rowptr[row + 1];
    const ushort4* xv = (const ushort4*)x;
    float a0 = 0.f, a1 = 0.f, a2 = 0.f, a3 = 0.f;
    float c0 = 0.f, c1 = 0.f, c2 = 0.f, c3 = 0.f;
    int j = beg;
    for (; j + 1 < end; j += 2) {
        ushort4 v = xv[(long)eidx[j] * 64 + lane];
        ushort4 w = xv[(long)eidx[j + 1] * 64 + lane];
        a0 += bf2f(v.x); a1 += bf2f(v.y); a2 += bf2f(v.z); a3 += bf2f(v.w);
        c0 += bf2f(w.x); c1 += bf2f(w.y); c2 += bf2f(w.z); c3 += bf2f(w.w);
    }
    if (j < end) {
        ushort4 v = xv[(long)eidx[j] * 64 + lane];
        a0 += bf2f(v.x); a1 += bf2f(v.y); a2 += bf2f(v.z); a3 += bf2f(v.w);
    }
    float s = inv[row];
    a0 = (a0 + c0) * s; a1 = (a1 + c1) * s; a2 = (a2 + c2) * s; a3 = (a3 + c3) * s;
    ((uint2*)agg)[(long)row * 64 + lane] = make_uint2(bfpack(a0, a1), bfpack(a2, a3));
}

__global__ __launch_bounds__(256) void gather_scale128(const u16* __restrict__ x,
                                                       const int* __restrict__ rowptr,
                                                       const int* __restrict__ eidx,
                                                       const float* __restrict__ inv,
                                                       u16* __restrict__ agg, int N) {
    int half = threadIdx.x >> 5;
    int lane = threadIdx.x & 31;
    int row = blockIdx.x * 8 + half;
    if (row >= N) return;
    int beg = rowptr[row], end = rowptr[row + 1];
    const ushort4* xv = (const ushort4*)x;
    float a0 = 0.f, a1 = 0.f, a2 = 0.f, a3 = 0.f;
    float c0 = 0.f, c1 = 0.f, c2 = 0.f, c3 = 0.f;
    int j = beg;
    for (; j + 1 < end; j += 2) {
        ushort4 v = xv[(long)eidx[j] * 32 + lane];
        ushort4 w = xv[(long)eidx[j + 1] * 32 + lane];
        a0 += bf2f(v.x); a1 += bf2f(v.y); a2 += bf2f(v.z); a3 += bf2f(v.w);
        c0 += bf2f(w.x); c1 += bf2f(w.y); c2 += bf2f(w.z); c3 += bf2f(w.w);
    }
    if (j < end) {
        ushort4 v = xv[(long)eidx[j] * 32 + lane];
        a0 += bf2f(v.x); a1 += bf2f(v.y); a2 += bf2f(v.z); a3 += bf2f(v.w);
    }
    float s = inv[row];
    a0 = (a0 + c0) * s; a1 = (a1 + c1) * s; a2 = (a2 + c2) * s; a3 = (a3 + c3) * s;
    ((uint2*)agg)[(long)row * 32 + lane] = make_uint2(bfpack(a0, a1), bfpack(a2, a3));
}

// L3 fused: h3 = relu(LN(gather_mean(y3) + r3)), D=128, half-wave/row.
__global__ __launch_bounds__(256) void gather_add_ln_relu128(const u16* __restrict__ y,
                                                             const int* __restrict__ rowptr,
                                                             const int* __restrict__ eidx,
                                                             const float* __restrict__ inv,
                                                             const u16* __restrict__ r,
                                                             const float* __restrict__ g,
                                                             const float* __restrict__ be,
                                                             u16* __restrict__ out, int N) {
    int half = threadIdx.x >> 5;
    int lane = threadIdx.x & 31;
    int row = blockIdx.x * 8 + half;
    if (row >= N) return;
    int beg = rowptr[row], end = rowptr[row + 1];
    const ushort4* xv = (const ushort4*)y;
    float a0 = 0.f, a1 = 0.f, a2 = 0.f, a3 = 0.f;
    float c0 = 0.f, c1 = 0.f, c2 = 0.f, c3 = 0.f;
    int j = beg;
    for (; j + 1 < end; j += 2) {
        ushort4 v = xv[(long)eidx[j] * 32 + lane];
        ushort4 w = xv[(long)eidx[j + 1] * 32 + lane];
        a0 += bf2f(v.x); a1 += bf2f(v.y); a2 += bf2f(v.z); a3 += bf2f(v.w);
        c0 += bf2f(w.x); c1 += bf2f(w.y); c2 += bf2f(w.z); c3 += bf2f(w.w);
    }
    if (j < end) {
        ushort4 v = xv[(long)eidx[j] * 32 + lane];
        a0 += bf2f(v.x); a1 += bf2f(v.y); a2 += bf2f(v.z); a3 += bf2f(v.w);
    }
    float iv = inv[row];
    ushort4 rr = ((const ushort4*)r)[(long)row * 32 + lane];
    float v0 = (a0 + c0) * iv + bf2f(rr.x);
    float v1 = (a1 + c1) * iv + bf2f(rr.y);
    float v2 = (a2 + c2) * iv + bf2f(rr.z);
    float v3 = (a3 + c3) * iv + bf2f(rr.w);
    float s = v0 + v1 + v2 + v3;
    float ss = v0 * v0 + v1 * v1 + v2 * v2 + v3 * v3;
#pragma unroll
    for (int m = 16; m >= 1; m >>= 1) {
        s += __shfl_xor(s, m);
        ss += __shfl_xor(ss, m);
    }
    float mean = s / 128.f;
    float var = ss / 128.f - mean * mean;
    float rs = rsqrtf(var + EPS);
    int col = lane * 4;
    v0 = fmaxf((v0 - mean) * rs * g[col + 0] + be[col + 0], 0.f);
    v1 = fmaxf((v1 - mean) * rs * g[col + 1] + be[col + 1], 0.f);
    v2 = fmaxf((v2 - mean) * rs * g[col + 2] + be[col + 2], 0.f);
    v3 = fmaxf((v3 - mean) * rs * g[col + 3] + be[col + 3], 0.f);
    ((uint2*)out)[(long)row * 32 + lane] = make_uint2(bfpack(v0, v1), bfpack(v2, v3));
}

// final: out = gather_sum(y)*inv + r, y bf16, out fp32
__global__ __launch_bounds__(256) void gather9_final(const u16* __restrict__ y,
                                                     const int* __restrict__ rowptr,
                                                     const int* __restrict__ eidx,
                                                     const float* __restrict__ inv,
                                                     const float* __restrict__ r,
                                                     float* __restrict__ out, int N) {
    int idx = blockIdx.x * 256 + threadIdx.x;
    int row = idx >> 4;
    int c = idx & 15;
    if (row >= N || c >= 9) return;
    int beg = rowptr[row], end = rowptr[row + 1];
    float a = 0.f;
    for (int j = beg; j < end; ++j) a += bf2f(y[(long)eidx[j] * 9 + c]);
    out[(long)row * 9 + c] = a * inv[row] + r[(long)row * 9 + c];
}

// ---------------- wide MFMA GEMM + fused bias+LN+ReLU epilogue ----------------
// out = relu(LN(A1@W1 + A2@W2 + bias))*g + be. BM=64, BN=256(=Dout), BK=32.
// out MAY alias A1 (each block owns rows [bm,bm+64) end-to-end).
__global__ __launch_bounds__(256) void mfma_gemm_wide_ln(const u16* A1,
                                                         const u16* __restrict__ A2,
                                                         const u16* __restrict__ WT1,
                                                         const u16* __restrict__ WT2,
                                                         const float* __restrict__ bias,
                                                         const float* __restrict__ g,
                                                         const float* __restrict__ be,
                                                         u16* out, int M, int K) {
    __shared__ __align__(16) u16 smem[64 * 260];  // staging (As+Ws) then C tile
    u16* As = smem;               // 64*40 = 2560 u16
    u16* Ws = smem + 64 * 40;     // 256*40 = 10240 u16 (total 12800 < 16640)
    const int tid = threadIdx.x;
    const int bm = blockIdx.x * 64;
    const int l = tid & 63;
    const int w = tid >> 6;
    const int wr = (w & 1) * 32;
    const int wc = (w >> 1) * 128;
    const int ln15 = l & 15;
    const int quad = l >> 4;

    f32x4_t acc[2][8];
#pragma unroll
    for (int i = 0; i < 2; ++i)
#pragma unroll
        for (int j = 0; j < 8; ++j) acc[i][j] = (f32x4_t){0.f, 0.f, 0.f, 0.f};

    const int ar = tid >> 2;
    const int akh = (tid & 3) * 8;

    for (int pass = 0; pass < 2; ++pass) {
        const u16* A = pass ? A2 : A1;
        const u16* WT = pass ? WT2 : WT1;
        for (int k0 = 0; k0 < K; k0 += 32) {
            uint4 q0 = make_uint4(0, 0, 0, 0);
            int gr = bm + ar;
            if (gr < M) q0 = *(const uint4*)(A + (long)gr * K + k0 + akh);
            *(uint4*)(As + ar * 40 + akh) = q0;
            const u16* wp = WT + (long)tid * K + k0;
            *(uint4*)(Ws + tid * 40 + 0) = ((const uint4*)wp)[0];
            *(uint4*)(Ws + tid * 40 + 8) = ((const uint4*)wp)[1];
            *(uint4*)(Ws + tid * 40 + 16) = ((const uint4*)wp)[2];
            *(uint4*)(Ws + tid * 40 + 24) = ((const uint4*)wp)[3];
            __syncthreads();

            bf16x8_t a[2], b[8];
#pragma unroll
            for (int i = 0; i < 2; ++i)
                a[i] = *(const bf16x8_t*)(As + (wr + i * 16 + ln15) * 40 + quad * 8);
#pragma unroll
            for (int j = 0; j < 8; ++j)
                b[j] = *(const bf16x8_t*)(Ws + (wc + j * 16 + ln15) * 40 + quad * 8);
#pragma unroll
            for (int i = 0; i < 2; ++i)
#pragma unroll
                for (int j = 0; j < 8; ++j)
                    acc[i][j] = __builtin_amdgcn_mfma_f32_16x16x32_bf16(a[i], b[j], acc[i][j], 0, 0, 0);
            __syncthreads();
        }
    }

    // ---- write C (+bias) to LDS as bf16 [64][260] ----
#pragma unroll
    for (int j = 0; j < 8; ++j) {
        int col = wc + j * 16 + ln15;
        float bv = bias[col];
#pragma unroll
        for (int i = 0; i < 2; ++i) {
            int row0 = wr + i * 16 + quad * 4;
            f32x4_t c = acc[i][j];
#pragma unroll
            for (int p = 0; p < 4; ++p) smem[(row0 + p) * 260 + col] = bfr(c[p] + bv);
        }
    }
    __syncthreads();

    // ---- LN+ReLU: wave w handles rows w*16..w*16+16, lane covers 4 cols ----
    float4 g4 = *(const float4*)&g[l * 4];
    float4 be4 = *(const float4*)&be[l * 4];
    for (int rr = 0; rr < 16; ++rr) {
        int lrow = w * 16 + rr;
        int grow = bm + lrow;
        if (grow >= M) break;
        ushort4 ld = *(const ushort4*)(smem + lrow * 260 + l * 4);
        float v0 = bf2f(ld.x), v1 = bf2f(ld.y), v2 = bf2f(ld.z), v3 = bf2f(ld.w);
        float s = v0 + v1 + v2 + v3;
        float ss = v0 * v0 + v1 * v1 + v2 * v2 + v3 * v3;
#pragma unroll
        for (int m = 32; m >= 1; m >>= 1) {
            s += __shfl_xor(s, m);
            ss += __shfl_xor(ss, m);
        }
        float mean = s / 256.f;
        float var = ss / 256.f - mean * mean;
        float rs = rsqrtf(var + EPS);
        v0 = fmaxf((v0 - mean) * rs * g4.x + be4.x, 0.f);
        v1 = fmaxf((v1 - mean) * rs * g4.y + be4.y, 0.f);
        v2 = fmaxf((v2 - mean) * rs * g4.z + be4.z, 0.f);
        v3 = fmaxf((v3 - mean) * rs * g4.w + be4.w, 0.f);
        ((uint2*)out)[(long)grow * 64 + l] = make_uint2(bfpack(v0, v1), bfpack(v2, v3));
    }
}

// ---------------- L3 dual GEMM: ya = A@WTa, yb = A@WTb + bias ----------------
// BM=128, BN=128, BK=32; blockIdx.y selects output. Dout=128.
__global__ __launch_bounds__(256) void mfma_gemm_dual(const u16* __restrict__ A,
                                                      const u16* __restrict__ WTa,
                                                      const u16* __restrict__ WTb,
                                                      const float* __restrict__ biasb,
                                                      u16* __restrict__ outa,
                                                      u16* __restrict__ outb, int M, int K) {
    __shared__ u16 As[128 * 40];
    __shared__ u16 Ws[128 * 40];
    const u16* WT = blockIdx.y ? WTb : WTa;
    u16* out = blockIdx.y ? outb : outa;
    const float* bias = blockIdx.y ? biasb : nullptr;
    const int tid = threadIdx.x;
    const int bm = blockIdx.x * 128;
    const int l = tid & 63;
    const int w = tid >> 6;
    const int wr = (w & 1) * 64;
    const int wc = (w >> 1) * 64;
    const int ln15 = l & 15;
    const int quad = l >> 4;

    f32x4_t acc[4][4];
#pragma unroll
    for (int i = 0; i < 4; ++i)
#pragma unroll
        for (int j = 0; j < 4; ++j) acc[i][j] = (f32x4_t){0.f, 0.f, 0.f, 0.f};

    const int sr = tid >> 1;
    const int kh = (tid & 1) * 16;

    for (int k0 = 0; k0 < K; k0 += 32) {
        uint4 q0 = make_uint4(0, 0, 0, 0), q1 = make_uint4(0, 0, 0, 0);
        int gr = bm + sr;
        if (gr < M) {
            const u16* ap = A + (long)gr * K + k0 + kh;
            q0 = ((const uint4*)ap)[0];
            q1 = ((const uint4*)ap)[1];
        }
        *(uint4*)(As + sr * 40 + kh) = q0;
        *(uint4*)(As + sr * 40 + kh + 8) = q1;
        const u16* wp = WT + (long)sr * K + k0 + kh;
        *(uint4*)(Ws + sr * 40 + kh) = ((const uint4*)wp)[0];
        *(uint4*)(Ws + sr * 40 + kh + 8) = ((const uint4*)wp)[1];
        __syncthreads();

        bf16x8_t a[4], b[4];
#pragma unroll
        for (int i = 0; i < 4; ++i)
            a[i] = *(const bf16x8_t*)(As + (wr + i * 16 + ln15) * 40 + quad * 8);
#pragma unroll
        for (int j = 0; j < 4; ++j)
            b[j] = *(const bf16x8_t*)(Ws + (wc + j * 16 + ln15) * 40 + quad * 8);
#pragma unroll
        for (int i = 0; i < 4; ++i)
#pragma unroll
            for (int j = 0; j < 4; ++j)
                acc[i][j] = __builtin_amdgcn_mfma_f32_16x16x32_bf16(a[i], b[j], acc[i][j], 0, 0, 0);
        __syncthreads();
    }

#pragma unroll
    for (int j = 0; j < 4; ++j) {
        int col = wc + j * 16 + ln15;
        float bv = bias ? bias[col] : 0.f;
#pragma unroll
        for (int i = 0; i < 4; ++i) {
            int row0 = bm + wr + i * 16 + quad * 4;
            f32x4_t c = acc[i][j];
#pragma unroll
            for (int p = 0; p < 4; ++p) {
                int row = row0 + p;
                if (row < M) out[(long)row * 128 + col] = bfr(c[p] + bv);
            }
        }
    }
}

// ---------------- layer 4 small GEMM: y = x@wm (bf16 out), r = x@wr + b (fp32) ------
__global__ __launch_bounds__(320) void gemm4_bf(const u16* __restrict__ x,
                                                const float* __restrict__ wm,
                                                const float* __restrict__ wrt,
                                                const float* __restrict__ b,
                                                u16* __restrict__ y, float* __restrict__ r,
                                                int M) {
    __shared__ float xs[16][132];
    __shared__ float ws[128][20];
    int tid = threadIdx.x;
    int m0 = blockIdx.x * 16;
    for (int idx = tid; idx < 16 * 128; idx += 320) {
        int rr = idx >> 7, kk = idx & 127;
        int gm = m0 + rr;
        xs[rr][kk] = (gm < M) ? bf2f(x[(long)gm * 128 + kk]) : 0.f;
    }
    for (int idx = tid; idx < 128 * 18; idx += 320) {
        int kk = idx / 18, cc = idx % 18;
        ws[kk][cc] = (cc < 9) ? wm[kk * 9 + cc] : wrt[kk * 9 + cc - 9];
    }
    __syncthreads();
    if (tid < 288) {
        int rr = tid / 18, cc = tid % 18;
        float acc = 0.f;
#pragma unroll 8
        for (int kk = 0; kk < 128; ++kk) acc += xs[rr][kk] * ws[kk][cc];
        int gm = m0 + rr;
        if (gm < M) {
            if (cc < 9) y[(long)gm * 9 + cc] = bfr(acc);
            else r[(long)gm * 9 + cc - 9] = acc + b[cc - 9];
        }
    }
}

static inline int cdiv(long a, long b) { return (int)((a + b - 1) / b); }

extern "C" void kernel_launch(void* const* d_in, const int* in_sizes, int n_in,
                              void* d_out, int out_size, void* d_ws, size_t ws_size,
                              hipStream_t stream) {
    const int N = in_sizes[0] / 128;
    const int E = in_sizes[1] / 2;

    const float* z = (const float*)d_in[0];
    const int* ei = (const int*)d_in[1];
    const int* src = ei;
    const int* dstp = ei + E;
    const float* wm1 = (const float*)d_in[2];
    const float* wr1 = (const float*)d_in[3];
    const float* b1 = (const float*)d_in[4];
    const float* g1 = (const float*)d_in[5];
    const float* be1 = (const float*)d_in[6];
    const float* wm2 = (const float*)d_in[7];
    const float* wr2 = (const float*)d_in[8];
    const float* b2 = (const float*)d_in[9];
    const float* g2 = (const float*)d_in[10];
    const float* be2 = (const float*)d_in[11];
    const float* wm3 = (const float*)d_in[12];
    const float* wr3 = (const float*)d_in[13];
    const float* b3 = (const float*)d_in[14];
    const float* g3 = (const float*)d_in[15];
    const float* be3 = (const float*)d_in[16];
    const float* wm4 = (const float*)d_in[17];
    const float* wr4 = (const float*)d_in[18];
    const float* b4 = (const float*)d_in[19];
    float* out = (float*)d_out;

    // ws layout:
    u16* aggh2 = (u16*)d_ws;                     // N*256
    u16* h1b = aggh2 + (size_t)N * 256;          // N*256
    u16* zb = h1b + (size_t)N * 256;             // N*128
    u16* agg1 = zb + (size_t)N * 128;            // N*128
    float* inv = (float*)(agg1 + (size_t)N * 128);
    int* deg = (int*)(inv + N);
    int* rowptr = deg + N + 4;
    int* cursor = rowptr + N + 4;
    int* partials = cursor + N + 4;
    int* eidx = partials + 256;
    u16* wt1m = (u16*)(eidx + E);
    u16* wt1r = wt1m + 256 * 128;
    u16* wt2m = wt1r + 256 * 128;
    u16* wt2r = wt2m + 256 * 256;
    u16* wt3m = wt2r + 256 * 256;
    u16* wt3r = wt3m + 128 * 256;

    // aliases (liveness-checked):
    u16* y3b = agg1;                  // agg1 dead after GEMM1
    u16* r3b = zb;                    // zb dead after GEMM1
    u16* h3b = h1b;                   // h1b dead after GEMM2
    u16* y4 = aggh2;                  // h2 dead after dual GEMM3; N*9 u16
    float* r4 = (float*)(aggh2 + (size_t)N * 16);  // N*9 f32, 16B-aligned

    const int nscan = cdiv(N, 1024);

    // ---- prep ----
    cast_bf16<<<cdiv((long)N * 32, 256), 256, 0, stream>>>(z, zb, N * 32);
    zero_f4<<<cdiv(N, 1024), 256, 0, stream>>>((float4*)deg, cdiv(N, 4));
    count_deg<<<cdiv(E, 256), 256, 0, stream>>>(dstp, deg, E);
    partial_sums<<<nscan, 256, 0, stream>>>(deg, partials, N);
    scan_partials<<<1, 256, 0, stream>>>(partials, nscan);
    write_rowptr<<<nscan, 256, 0, stream>>>(deg, partials, rowptr, cursor, inv, N, E);
    fill_csr<<<cdiv(E, 256), 256, 0, stream>>>(src, dstp, cursor, eidx, E);
    {
        WtJobs jobs;
        jobs.W[0] = wm1; jobs.WT[0] = wt1m; jobs.K[0] = 128; jobs.N[0] = 256;
        jobs.W[1] = wr1; jobs.WT[1] = wt1r; jobs.K[1] = 128; jobs.N[1] = 256;
        jobs.W[2] = wm2; jobs.WT[2] = wt2m; jobs.K[2] = 256; jobs.N[2] = 256;
        jobs.W[3] = wr2; jobs.WT[3] = wt2r; jobs.K[3] = 256; jobs.N[3] = 256;
        jobs.W[4] = wm3; jobs.WT[4] = wt3m; jobs.K[4] = 256; jobs.N[4] = 128;
        jobs.W[5] = wr3; jobs.WT[5] = wt3r; jobs.K[5] = 256; jobs.N[5] = 128;
        dim3 g(256, 6);
        transpose_cast6<<<g, 256, 0, stream>>>(jobs);
    }

    // ---- layer 1: gather z, wide GEMM + fused LN/ReLU -> h1b ----
    gather_scale128<<<cdiv(N, 8), 256, 0, stream>>>(zb, rowptr, eidx, inv, agg1, N);
    mfma_gemm_wide_ln<<<cdiv(N, 64), 256, 0, stream>>>(agg1, zb, wt1m, wt1r, b1, g1, be1,
                                                       h1b, N, 128);

    // ---- layer 2: gather h1, in-place wide GEMM + fused LN/ReLU -> aggh2 (=h2) ----
    gather_scale256<<<cdiv(N, 4), 256, 0, stream>>>(h1b, rowptr, eidx, inv, aggh2, N);
    mfma_gemm_wide_ln<<<cdiv(N, 64), 256, 0, stream>>>(aggh2, h1b, wt2m, wt2r, b2, g2, be2,
                                                       aggh2, N, 256);

    // ---- layer 3: dual GEMM then fused gather+add+LN+ReLU ----
    {
        dim3 g(cdiv(N, 128), 2);
        mfma_gemm_dual<<<g, 256, 0, stream>>>(aggh2, wt3m, wt3r, b3, y3b, r3b, N, 256);
    }
    gather_add_ln_relu128<<<cdiv(N, 8), 256, 0, stream>>>(y3b, rowptr, eidx, inv, r3b, g3,
                                                          be3, h3b, N);

    // ---- layer 4 ----
    gemm4_bf<<<cdiv(N, 16), 320, 0, stream>>>(h3b, wm4, wr4, b4, y4, r4, N);
    gather9_final<<<cdiv((long)N * 16, 256), 256, 0, stream>>>(y4, rowptr, eidx, inv, r4, out, N);
}

// Round 8
// 861.927 us; speedup vs baseline: 13.9028x; 1.0344x over previous
//
#include <hip/hip_runtime.h>
#include <hip/hip_bf16.h>

// GraphSAGE decoder, 4 layers. CSR-gather aggregation, bf16 feature tables,
// bf16-MFMA GEMMs with fp32 accumulate, LN fused into GEMM epilogues.
// CSR fill is bucketed into 8 sequential dst-range passes so the eidx write
// window (~800KB) stays L2-resident -> kills the 16x partial-line write
// amplification R6/R7 measured (100MB HBM writes for a 6.4MB array).

#define EPS 1e-5f

typedef unsigned short u16;
typedef short bf16x8_t __attribute__((ext_vector_type(8)));
typedef float f32x4_t __attribute__((ext_vector_type(4)));

__device__ inline unsigned int bfpack(float a, float b) {
    unsigned int ua = __builtin_bit_cast(unsigned int, a);
    unsigned int ub = __builtin_bit_cast(unsigned int, b);
    ua += 0x7fffu + ((ua >> 16) & 1u);
    ub += 0x7fffu + ((ub >> 16) & 1u);
    return (ua >> 16) | (ub & 0xffff0000u);
}

__device__ inline u16 bfr(float a) {
    unsigned int u = __builtin_bit_cast(unsigned int, a);
    u += 0x7fffu + ((u >> 16) & 1u);
    return (u16)(u >> 16);
}

__device__ inline float bf2f(u16 v) {
    unsigned int u = ((unsigned int)v) << 16;
    return __builtin_bit_cast(float, u);
}

// ---------------- zero fill ----------------
__global__ __launch_bounds__(256) void zero_f4(float4* __restrict__ p, int n4) {
    int i = blockIdx.x * 256 + threadIdx.x;
    if (i < n4) p[i] = make_float4(0.f, 0.f, 0.f, 0.f);
}

// ---------------- fp32 -> bf16 cast ----------------
__global__ __launch_bounds__(256) void cast_bf16(const float* __restrict__ x,
                                                 u16* __restrict__ y, int n4) {
    int i = blockIdx.x * 256 + threadIdx.x;
    if (i >= n4) return;
    float4 v = ((const float4*)x)[i];
    ((uint2*)y)[i] = make_uint2(bfpack(v.x, v.y), bfpack(v.z, v.w));
}

// ---------------- all 6 weight transposes in one launch ----------------
struct WtJobs {
    const float* W[6];
    u16* WT[6];
    int K[6], N[6];
};
__global__ __launch_bounds__(256) void transpose_cast6(WtJobs jobs) {
    int j = blockIdx.y;
    int idx = blockIdx.x * 256 + threadIdx.x;
    int K = jobs.K[j], Nn = jobs.N[j];
    if (idx >= K * Nn) return;
    int k = idx / Nn, n = idx - k * Nn;
    jobs.WT[j][(long)n * K + k] = bfr(jobs.W[j][idx]);
}

// ---------------- CSR build ----------------
__global__ __launch_bounds__(256) void count_deg(const int* __restrict__ dst,
                                                 int* __restrict__ deg, int E) {
    int e = blockIdx.x * 256 + threadIdx.x;
    if (e < E) atomicAdd(&deg[dst[e]], 1);
}

__global__ __launch_bounds__(256) void partial_sums(const int* __restrict__ deg,
                                                    int* __restrict__ partials, int N) {
    __shared__ int lds[4];
    int tid = threadIdx.x;
    int base = blockIdx.x * 1024 + tid * 4;
    int s = 0;
    if (base + 3 < N) {
        int4 v = *(const int4*)(deg + base);
        s = v.x + v.y + v.z + v.w;
    } else {
        for (int i = 0; i < 4; ++i)
            if (base + i < N) s += deg[base + i];
    }
#pragma unroll
    for (int m = 32; m >= 1; m >>= 1) s += __shfl_xor(s, m);
    if ((tid & 63) == 0) lds[tid >> 6] = s;
    __syncthreads();
    if (tid == 0) partials[blockIdx.x] = lds[0] + lds[1] + lds[2] + lds[3];
}

__global__ __launch_bounds__(256) void scan_partials(int* __restrict__ partials, int nb) {
    __shared__ int lds[256];
    int tid = threadIdx.x;
    int v = (tid < nb) ? partials[tid] : 0;
    lds[tid] = v;
    __syncthreads();
    for (int off = 1; off < 256; off <<= 1) {
        int t = (tid >= off) ? lds[tid - off] : 0;
        __syncthreads();
        lds[tid] += t;
        __syncthreads();
    }
    if (tid < nb) partials[tid] = lds[tid] - v;
}

__global__ __launch_bounds__(256) void write_rowptr(const int* __restrict__ deg,
                                                    const int* __restrict__ partials,
                                                    int* __restrict__ rowptr,
                                                    int* __restrict__ cursor,
                                                    float* __restrict__ inv, int N, int E) {
    __shared__ int lds[256];
    int tid = threadIdx.x;
    int base = blockIdx.x * 1024 + tid * 4;
    int d[4];
    int s = 0;
#pragma unroll
    for (int i = 0; i < 4; ++i) {
        d[i] = (base + i < N) ? deg[base + i] : 0;
        s += d[i];
    }
    lds[tid] = s;
    __syncthreads();
    for (int off = 1; off < 256; off <<= 1) {
        int t = (tid >= off) ? lds[tid - off] : 0;
        __syncthreads();
        lds[tid] += t;
        __syncthreads();
    }
    int run = partials[blockIdx.x] + lds[tid] - s;
#pragma unroll
    for (int i = 0; i < 4; ++i) {
        int idx = base + i;
        if (idx < N) {
            rowptr[idx] = run;
            cursor[idx] = run;
            inv[idx] = 1.0f / fmaxf((float)d[i], 1.0f);
            run += d[i];
        }
    }
    if (blockIdx.x == 0 && tid == 0) rowptr[N] = E;
}

// one dst-range bucket per launch: eidx write window stays L2-resident.
__global__ __launch_bounds__(256) void fill_csr_range(const int* __restrict__ src,
                                                      const int* __restrict__ dst,
                                                      int* __restrict__ cursor,
                                                      int* __restrict__ eidx, int E,
                                                      int lo, int bs) {
    int e = blockIdx.x * 256 + threadIdx.x;
    if (e >= E) return;
    int d = dst[e];
    if ((unsigned)(d - lo) < (unsigned)bs) {
        int p = atomicAdd(&cursor[d], 1);
        eidx[p] = src[e];
    }
}

// ---------------- gathers over bf16 tables, fp32 accumulate, bf16 out ----------------
__global__ __launch_bounds__(256) void gather_scale256(const u16* __restrict__ x,
                                                       const int* __restrict__ rowptr,
                                                       const int* __restrict__ eidx,
                                                       const float* __restrict__ inv,
                                                       u16* __restrict__ agg, int N) {
    int wave = threadIdx.x >> 6;
    int lane = threadIdx.x & 63;
    int row = blockIdx.x * 4 + wave;
    if (row >= N) return;
    int beg = rowptr[row], end = rowptr[row + 1];
    const ushort4* xv = (const ushort4*)x;
    float a0 = 0.f, a1 = 0.f, a2 = 0.f, a3 = 0.f;
    float c0 = 0.f, c1 = 0.f, c2 = 0.f, c3 = 0.f;
    int j = beg;
    for (; j + 1 < end; j += 2) {
        ushort4 v = xv[(long)eidx[j] * 64 + lane];
        ushort4 w = xv[(long)eidx[j + 1] * 64 + lane];
        a0 += bf2f(v.x); a1 += bf2f(v.y); a2 += bf2f(v.z); a3 += bf2f(v.w);
        c0 += bf2f(w.x); c1 += bf2f(w.y); c2 += bf2f(w.z); c3 += bf2f(w.w);
    }
    if (j < end) {
        ushort4 v = xv[(long)eidx[j] * 64 + lane];
        a0 += bf2f(v.x); a1 += bf2f(v.y); a2 += bf2f(v.z); a3 += bf2f(v.w);
    }
    float s = inv[row];
    a0 = (a0 + c0) * s; a1 = (a1 + c1) * s; a2 = (a2 + c2) * s; a3 = (a3 + c3) * s;
    ((uint2*)agg)[(long)row * 64 + lane] = make_uint2(bfpack(a0, a1), bfpack(a2, a3));
}

__global__ __launch_bounds__(256) void gather_scale128(const u16* __restrict__ x,
                                                       const int* __restrict__ rowptr,
                                                       const int* __restrict__ eidx,
                                                       const float* __restrict__ inv,
                                                       u16* __restrict__ agg, int N) {
    int half = threadIdx.x >> 5;
    int lane = threadIdx.x & 31;
    int row = blockIdx.x * 8 + half;
    if (row >= N) return;
    int beg = rowptr[row], end = rowptr[row + 1];
    const ushort4* xv = (const ushort4*)x;
    float a0 = 0.f, a1 = 0.f, a2 = 0.f, a3 = 0.f;
    float c0 = 0.f, c1 = 0.f, c2 = 0.f, c3 = 0.f;
    int j = beg;
    for (; j + 1 < end; j += 2) {
        ushort4 v = xv[(long)eidx[j] * 32 + lane];
        ushort4 w = xv[(long)eidx[j + 1] * 32 + lane];
        a0 += bf2f(v.x); a1 += bf2f(v.y); a2 += bf2f(v.z); a3 += bf2f(v.w);
        c0 += bf2f(w.x); c1 += bf2f(w.y); c2 += bf2f(w.z); c3 += bf2f(w.w);
    }
    if (j < end) {
        ushort4 v = xv[(long)eidx[j] * 32 + lane];
        a0 += bf2f(v.x); a1 += bf2f(v.y); a2 += bf2f(v.z); a3 += bf2f(v.w);
    }
    float s = inv[row];
    a0 = (a0 + c0) * s; a1 = (a1 + c1) * s; a2 = (a2 + c2) * s; a3 = (a3 + c3) * s;
    ((uint2*)agg)[(long)row * 32 + lane] = make_uint2(bfpack(a0, a1), bfpack(a2, a3));
}

// L3 fused: h3 = relu(LN(gather_mean(y3) + r3)), D=128, half-wave/row.
__global__ __launch_bounds__(256) void gather_add_ln_relu128(const u16* __restrict__ y,
                                                             const int* __restrict__ rowptr,
                                                             const int* __restrict__ eidx,
                                                             const float* __restrict__ inv,
                                                             const u16* __restrict__ r,
                                                             const float* __restrict__ g,
                                                             const float* __restrict__ be,
                                                             u16* __restrict__ out, int N) {
    int half = threadIdx.x >> 5;
    int lane = threadIdx.x & 31;
    int row = blockIdx.x * 8 + half;
    if (row >= N) return;
    int beg = rowptr[row], end = rowptr[row + 1];
    const ushort4* xv = (const ushort4*)y;
    float a0 = 0.f, a1 = 0.f, a2 = 0.f, a3 = 0.f;
    float c0 = 0.f, c1 = 0.f, c2 = 0.f, c3 = 0.f;
    int j = beg;
    for (; j + 1 < end; j += 2) {
        ushort4 v = xv[(long)eidx[j] * 32 + lane];
        ushort4 w = xv[(long)eidx[j + 1] * 32 + lane];
        a0 += bf2f(v.x); a1 += bf2f(v.y); a2 += bf2f(v.z); a3 += bf2f(v.w);
        c0 += bf2f(w.x); c1 += bf2f(w.y); c2 += bf2f(w.z); c3 += bf2f(w.w);
    }
    if (j < end) {
        ushort4 v = xv[(long)eidx[j] * 32 + lane];
        a0 += bf2f(v.x); a1 += bf2f(v.y); a2 += bf2f(v.z); a3 += bf2f(v.w);
    }
    float iv = inv[row];
    ushort4 rr = ((const ushort4*)r)[(long)row * 32 + lane];
    float v0 = (a0 + c0) * iv + bf2f(rr.x);
    float v1 = (a1 + c1) * iv + bf2f(rr.y);
    float v2 = (a2 + c2) * iv + bf2f(rr.z);
    float v3 = (a3 + c3) * iv + bf2f(rr.w);
    float s = v0 + v1 + v2 + v3;
    float ss = v0 * v0 + v1 * v1 + v2 * v2 + v3 * v3;
#pragma unroll
    for (int m = 16; m >= 1; m >>= 1) {
        s += __shfl_xor(s, m);
        ss += __shfl_xor(ss, m);
    }
    float mean = s / 128.f;
    float var = ss / 128.f - mean * mean;
    float rs = rsqrtf(var + EPS);
    int col = lane * 4;
    v0 = fmaxf((v0 - mean) * rs * g[col + 0] + be[col + 0], 0.f);
    v1 = fmaxf((v1 - mean) * rs * g[col + 1] + be[col + 1], 0.f);
    v2 = fmaxf((v2 - mean) * rs * g[col + 2] + be[col + 2], 0.f);
    v3 = fmaxf((v3 - mean) * rs * g[col + 3] + be[col + 3], 0.f);
    ((uint2*)out)[(long)row * 32 + lane] = make_uint2(bfpack(v0, v1), bfpack(v2, v3));
}

// final: out = gather_sum(y)*inv + r, y bf16, out fp32
__global__ __launch_bounds__(256) void gather9_final(const u16* __restrict__ y,
                                                     const int* __restrict__ rowptr,
                                                     const int* __restrict__ eidx,
                                                     const float* __restrict__ inv,
                                                     const float* __restrict__ r,
                                                     float* __restrict__ out, int N) {
    int idx = blockIdx.x * 256 + threadIdx.x;
    int row = idx >> 4;
    int c = idx & 15;
    if (row >= N || c >= 9) return;
    int beg = rowptr[row], end = rowptr[row + 1];
    float a = 0.f;
    for (int j = beg; j < end; ++j) a += bf2f(y[(long)eidx[j] * 9 + c]);
    out[(long)row * 9 + c] = a * inv[row] + r[(long)row * 9 + c];
}

// ---------------- wide MFMA GEMM + fused bias+LN+ReLU epilogue ----------------
// out = relu(LN(A1@W1 + A2@W2 + bias))*g + be. BM=64, BN=256(=Dout), BK=32.
// out MAY alias A1 (each block owns rows [bm,bm+64) end-to-end).
__global__ __launch_bounds__(256) void mfma_gemm_wide_ln(const u16* A1,
                                                         const u16* __restrict__ A2,
                                                         const u16* __restrict__ WT1,
                                                         const u16* __restrict__ WT2,
                                                         const float* __restrict__ bias,
                                                         const float* __restrict__ g,
                                                         const float* __restrict__ be,
                                                         u16* out, int M, int K) {
    __shared__ __align__(16) u16 smem[64 * 260];
    u16* As = smem;
    u16* Ws = smem + 64 * 40;
    const int tid = threadIdx.x;
    const int bm = blockIdx.x * 64;
    const int l = tid & 63;
    const int w = tid >> 6;
    const int wr = (w & 1) * 32;
    const int wc = (w >> 1) * 128;
    const int ln15 = l & 15;
    const int quad = l >> 4;

    f32x4_t acc[2][8];
#pragma unroll
    for (int i = 0; i < 2; ++i)
#pragma unroll
        for (int j = 0; j < 8; ++j) acc[i][j] = (f32x4_t){0.f, 0.f, 0.f, 0.f};

    const int ar = tid >> 2;
    const int akh = (tid & 3) * 8;

    for (int pass = 0; pass < 2; ++pass) {
        const u16* A = pass ? A2 : A1;
        const u16* WT = pass ? WT2 : WT1;
        for (int k0 = 0; k0 < K; k0 += 32) {
            uint4 q0 = make_uint4(0, 0, 0, 0);
            int gr = bm + ar;
            if (gr < M) q0 = *(const uint4*)(A + (long)gr * K + k0 + akh);
            *(uint4*)(As + ar * 40 + akh) = q0;
            const u16* wp = WT + (long)tid * K + k0;
            *(uint4*)(Ws + tid * 40 + 0) = ((const uint4*)wp)[0];
            *(uint4*)(Ws + tid * 40 + 8) = ((const uint4*)wp)[1];
            *(uint4*)(Ws + tid * 40 + 16) = ((const uint4*)wp)[2];
            *(uint4*)(Ws + tid * 40 + 24) = ((const uint4*)wp)[3];
            __syncthreads();

            bf16x8_t a[2], b[8];
#pragma unroll
            for (int i = 0; i < 2; ++i)
                a[i] = *(const bf16x8_t*)(As + (wr + i * 16 + ln15) * 40 + quad * 8);
#pragma unroll
            for (int j = 0; j < 8; ++j)
                b[j] = *(const bf16x8_t*)(Ws + (wc + j * 16 + ln15) * 40 + quad * 8);
#pragma unroll
            for (int i = 0; i < 2; ++i)
#pragma unroll
                for (int j = 0; j < 8; ++j)
                    acc[i][j] = __builtin_amdgcn_mfma_f32_16x16x32_bf16(a[i], b[j], acc[i][j], 0, 0, 0);
            __syncthreads();
        }
    }

#pragma unroll
    for (int j = 0; j < 8; ++j) {
        int col = wc + j * 16 + ln15;
        float bv = bias[col];
#pragma unroll
        for (int i = 0; i < 2; ++i) {
            int row0 = wr + i * 16 + quad * 4;
            f32x4_t c = acc[i][j];
#pragma unroll
            for (int p = 0; p < 4; ++p) smem[(row0 + p) * 260 + col] = bfr(c[p] + bv);
        }
    }
    __syncthreads();

    float4 g4 = *(const float4*)&g[l * 4];
    float4 be4 = *(const float4*)&be[l * 4];
    for (int rr = 0; rr < 16; ++rr) {
        int lrow = w * 16 + rr;
        int grow = bm + lrow;
        if (grow >= M) break;
        ushort4 ld = *(const ushort4*)(smem + lrow * 260 + l * 4);
        float v0 = bf2f(ld.x), v1 = bf2f(ld.y), v2 = bf2f(ld.z), v3 = bf2f(ld.w);
        float s = v0 + v1 + v2 + v3;
        float ss = v0 * v0 + v1 * v1 + v2 * v2 + v3 * v3;
#pragma unroll
        for (int m = 32; m >= 1; m >>= 1) {
            s += __shfl_xor(s, m);
            ss += __shfl_xor(ss, m);
        }
        float mean = s / 256.f;
        float var = ss / 256.f - mean * mean;
        float rs = rsqrtf(var + EPS);
        v0 = fmaxf((v0 - mean) * rs * g4.x + be4.x, 0.f);
        v1 = fmaxf((v1 - mean) * rs * g4.y + be4.y, 0.f);
        v2 = fmaxf((v2 - mean) * rs * g4.z + be4.z, 0.f);
        v3 = fmaxf((v3 - mean) * rs * g4.w + be4.w, 0.f);
        ((uint2*)out)[(long)grow * 64 + l] = make_uint2(bfpack(v0, v1), bfpack(v2, v3));
    }
}

// ---------------- L3 dual GEMM: ya = A@WTa, yb = A@WTb + bias ----------------
__global__ __launch_bounds__(256) void mfma_gemm_dual(const u16* __restrict__ A,
                                                      const u16* __restrict__ WTa,
                                                      const u16* __restrict__ WTb,
                                                      const float* __restrict__ biasb,
                                                      u16* __restrict__ outa,
                                                      u16* __restrict__ outb, int M, int K) {
    __shared__ u16 As[128 * 40];
    __shared__ u16 Ws[128 * 40];
    const u16* WT = blockIdx.y ? WTb : WTa;
    u16* out = blockIdx.y ? outb : outa;
    const float* bias = blockIdx.y ? biasb : nullptr;
    const int tid = threadIdx.x;
    const int bm = blockIdx.x * 128;
    const int l = tid & 63;
    const int w = tid >> 6;
    const int wr = (w & 1) * 64;
    const int wc = (w >> 1) * 64;
    const int ln15 = l & 15;
    const int quad = l >> 4;

    f32x4_t acc[4][4];
#pragma unroll
    for (int i = 0; i < 4; ++i)
#pragma unroll
        for (int j = 0; j < 4; ++j) acc[i][j] = (f32x4_t){0.f, 0.f, 0.f, 0.f};

    const int sr = tid >> 1;
    const int kh = (tid & 1) * 16;

    for (int k0 = 0; k0 < K; k0 += 32) {
        uint4 q0 = make_uint4(0, 0, 0, 0), q1 = make_uint4(0, 0, 0, 0);
        int gr = bm + sr;
        if (gr < M) {
            const u16* ap = A + (long)gr * K + k0 + kh;
            q0 = ((const uint4*)ap)[0];
            q1 = ((const uint4*)ap)[1];
        }
        *(uint4*)(As + sr * 40 + kh) = q0;
        *(uint4*)(As + sr * 40 + kh + 8) = q1;
        const u16* wp = WT + (long)sr * K + k0 + kh;
        *(uint4*)(Ws + sr * 40 + kh) = ((const uint4*)wp)[0];
        *(uint4*)(Ws + sr * 40 + kh + 8) = ((const uint4*)wp)[1];
        __syncthreads();

        bf16x8_t a[4], b[4];
#pragma unroll
        for (int i = 0; i < 4; ++i)
            a[i] = *(const bf16x8_t*)(As + (wr + i * 16 + ln15) * 40 + quad * 8);
#pragma unroll
        for (int j = 0; j < 4; ++j)
            b[j] = *(const bf16x8_t*)(Ws + (wc + j * 16 + ln15) * 40 + quad * 8);
#pragma unroll
        for (int i = 0; i < 4; ++i)
#pragma unroll
            for (int j = 0; j < 4; ++j)
                acc[i][j] = __builtin_amdgcn_mfma_f32_16x16x32_bf16(a[i], b[j], acc[i][j], 0, 0, 0);
        __syncthreads();
    }

#pragma unroll
    for (int j = 0; j < 4; ++j) {
        int col = wc + j * 16 + ln15;
        float bv = bias ? bias[col] : 0.f;
#pragma unroll
        for (int i = 0; i < 4; ++i) {
            int row0 = bm + wr + i * 16 + quad * 4;
            f32x4_t c = acc[i][j];
#pragma unroll
            for (int p = 0; p < 4; ++p) {
                int row = row0 + p;
                if (row < M) out[(long)row * 128 + col] = bfr(c[p] + bv);
            }
        }
    }
}

// ---------------- layer 4 small GEMM ----------------
__global__ __launch_bounds__(320) void gemm4_bf(const u16* __restrict__ x,
                                                const float* __restrict__ wm,
                                                const float* __restrict__ wrt,
                                                const float* __restrict__ b,
                                                u16* __restrict__ y, float* __restrict__ r,
                                                int M) {
    __shared__ float xs[16][132];
    __shared__ float ws[128][20];
    int tid = threadIdx.x;
    int m0 = blockIdx.x * 16;
    for (int idx = tid; idx < 16 * 128; idx += 320) {
        int rr = idx >> 7, kk = idx & 127;
        int gm = m0 + rr;
        xs[rr][kk] = (gm < M) ? bf2f(x[(long)gm * 128 + kk]) : 0.f;
    }
    for (int idx = tid; idx < 128 * 18; idx += 320) {
        int kk = idx / 18, cc = idx % 18;
        ws[kk][cc] = (cc < 9) ? wm[kk * 9 + cc] : wrt[kk * 9 + cc - 9];
    }
    __syncthreads();
    if (tid < 288) {
        int rr = tid / 18, cc = tid % 18;
        float acc = 0.f;
#pragma unroll 8
        for (int kk = 0; kk < 128; ++kk) acc += xs[rr][kk] * ws[kk][cc];
        int gm = m0 + rr;
        if (gm < M) {
            if (cc < 9) y[(long)gm * 9 + cc] = bfr(acc);
            else r[(long)gm * 9 + cc - 9] = acc + b[cc - 9];
        }
    }
}

static inline int cdiv(long a, long b) { return (int)((a + b - 1) / b); }

extern "C" void kernel_launch(void* const* d_in, const int* in_sizes, int n_in,
                              void* d_out, int out_size, void* d_ws, size_t ws_size,
                              hipStream_t stream) {
    const int N = in_sizes[0] / 128;
    const int E = in_sizes[1] / 2;

    const float* z = (const float*)d_in[0];
    const int* ei = (const int*)d_in[1];
    const int* src = ei;
    const int* dstp = ei + E;
    const float* wm1 = (const float*)d_in[2];
    const float* wr1 = (const float*)d_in[3];
    const float* b1 = (const float*)d_in[4];
    const float* g1 = (const float*)d_in[5];
    const float* be1 = (const float*)d_in[6];
    const float* wm2 = (const float*)d_in[7];
    const float* wr2 = (const float*)d_in[8];
    const float* b2 = (const float*)d_in[9];
    const float* g2 = (const float*)d_in[10];
    const float* be2 = (const float*)d_in[11];
    const float* wm3 = (const float*)d_in[12];
    const float* wr3 = (const float*)d_in[13];
    const float* b3 = (const float*)d_in[14];
    const float* g3 = (const float*)d_in[15];
    const float* be3 = (const float*)d_in[16];
    const float* wm4 = (const float*)d_in[17];
    const float* wr4 = (const float*)d_in[18];
    const float* b4 = (const float*)d_in[19];
    float* out = (float*)d_out;

    // ws layout:
    u16* aggh2 = (u16*)d_ws;                     // N*256
    u16* h1b = aggh2 + (size_t)N * 256;          // N*256
    u16* zb = h1b + (size_t)N * 256;             // N*128
    u16* agg1 = zb + (size_t)N * 128;            // N*128
    float* inv = (float*)(agg1 + (size_t)N * 128);
    int* deg = (int*)(inv + N);
    int* rowptr = deg + N + 4;
    int* cursor = rowptr + N + 4;
    int* partials = cursor + N + 4;
    int* eidx = partials + 256;
    u16* wt1m = (u16*)(eidx + E);
    u16* wt1r = wt1m + 256 * 128;
    u16* wt2m = wt1r + 256 * 128;
    u16* wt2r = wt2m + 256 * 256;
    u16* wt3m = wt2r + 256 * 256;
    u16* wt3r = wt3m + 128 * 256;

    // aliases (liveness-checked):
    u16* y3b = agg1;
    u16* r3b = zb;
    u16* h3b = h1b;
    u16* y4 = aggh2;
    float* r4 = (float*)(aggh2 + (size_t)N * 16);

    const int nscan = cdiv(N, 1024);

    // ---- prep ----
    cast_bf16<<<cdiv((long)N * 32, 256), 256, 0, stream>>>(z, zb, N * 32);
    zero_f4<<<cdiv(N, 1024), 256, 0, stream>>>((float4*)deg, cdiv(N, 4));
    count_deg<<<cdiv(E, 256), 256, 0, stream>>>(dstp, deg, E);
    partial_sums<<<nscan, 256, 0, stream>>>(deg, partials, N);
    scan_partials<<<1, 256, 0, stream>>>(partials, nscan);
    write_rowptr<<<nscan, 256, 0, stream>>>(deg, partials, rowptr, cursor, inv, N, E);
    {
        const int P = 8;
        int bs = cdiv(N, P);
        for (int b = 0; b < P; ++b)
            fill_csr_range<<<cdiv(E, 256), 256, 0, stream>>>(src, dstp, cursor, eidx, E,
                                                             b * bs, bs);
    }
    {
        WtJobs jobs;
        jobs.W[0] = wm1; jobs.WT[0] = wt1m; jobs.K[0] = 128; jobs.N[0] = 256;
        jobs.W[1] = wr1; jobs.WT[1] = wt1r; jobs.K[1] = 128; jobs.N[1] = 256;
        jobs.W[2] = wm2; jobs.WT[2] = wt2m; jobs.K[2] = 256; jobs.N[2] = 256;
        jobs.W[3] = wr2; jobs.WT[3] = wt2r; jobs.K[3] = 256; jobs.N[3] = 256;
        jobs.W[4] = wm3; jobs.WT[4] = wt3m; jobs.K[4] = 256; jobs.N[4] = 128;
        jobs.W[5] = wr3; jobs.WT[5] = wt3r; jobs.K[5] = 256; jobs.N[5] = 128;
        dim3 g(256, 6);
        transpose_cast6<<<g, 256, 0, stream>>>(jobs);
    }

    // ---- layer 1 ----
    gather_scale128<<<cdiv(N, 8), 256, 0, stream>>>(zb, rowptr, eidx, inv, agg1, N);
    mfma_gemm_wide_ln<<<cdiv(N, 64), 256, 0, stream>>>(agg1, zb, wt1m, wt1r, b1, g1, be1,
                                                       h1b, N, 128);

    // ---- layer 2 ----
    gather_scale256<<<cdiv(N, 4), 256, 0, stream>>>(h1b, rowptr, eidx, inv, aggh2, N);
    mfma_gemm_wide_ln<<<cdiv(N, 64), 256, 0, stream>>>(aggh2, h1b, wt2m, wt2r, b2, g2, be2,
                                                       aggh2, N, 256);

    // ---- layer 3 ----
    {
        dim3 g(cdiv(N, 128), 2);
        mfma_gemm_dual<<<g, 256, 0, stream>>>(aggh2, wt3m, wt3r, b3, y3b, r3b, N, 256);
    }
    gather_add_ln_relu128<<<cdiv(N, 8), 256, 0, stream>>>(y3b, rowptr, eidx, inv, r3b, g3,
                                                          be3, h3b, N);

    // ---- layer 4 ----
    gemm4_bf<<<cdiv(N, 16), 320, 0, stream>>>(h3b, wm4, wr4, b4, y4, r4, N);
    gather9_final<<<cdiv((long)N * 16, 256), 256, 0, stream>>>(y4, rowptr, eidx, inv, r4, out, N);
}

// Round 9
// 829.847 us; speedup vs baseline: 14.4403x; 1.0387x over previous
//
#include <hip/hip_runtime.h>
#include <hip/hip_bf16.h>

// GraphSAGE decoder, 4 layers. CSR-gather aggregation, bf16 feature tables,
// bf16-MFMA GEMMs with fp32 accumulate, LN fused into GEMM epilogues.
// Gathers: 16B/lane loads, multi-edge in flight (half/quarter-wave per edge),
// cross-lane merge via shfl_xor. CSR fill bucketed (4 passes, L2-resident
// write window -> no partial-line write-back amplification).

#define EPS 1e-5f

typedef unsigned short u16;
typedef short bf16x8_t __attribute__((ext_vector_type(8)));
typedef float f32x4_t __attribute__((ext_vector_type(4)));

__device__ inline unsigned int bfpack(float a, float b) {
    unsigned int ua = __builtin_bit_cast(unsigned int, a);
    unsigned int ub = __builtin_bit_cast(unsigned int, b);
    ua += 0x7fffu + ((ua >> 16) & 1u);
    ub += 0x7fffu + ((ub >> 16) & 1u);
    return (ua >> 16) | (ub & 0xffff0000u);
}

__device__ inline u16 bfr(float a) {
    unsigned int u = __builtin_bit_cast(unsigned int, a);
    u += 0x7fffu + ((u >> 16) & 1u);
    return (u16)(u >> 16);
}

__device__ inline float bf2f(u16 v) {
    unsigned int u = ((unsigned int)v) << 16;
    return __builtin_bit_cast(float, u);
}

// low/high bf16 of a u32 -> float, 1 VALU op each
__device__ inline float bflo(unsigned int q) { return __builtin_bit_cast(float, q << 16); }
__device__ inline float bfhi(unsigned int q) { return __builtin_bit_cast(float, q & 0xffff0000u); }

#define ACC8(A, Q)                                         \
    A[0] += bflo(Q.x); A[1] += bfhi(Q.x);                  \
    A[2] += bflo(Q.y); A[3] += bfhi(Q.y);                  \
    A[4] += bflo(Q.z); A[5] += bfhi(Q.z);                  \
    A[6] += bflo(Q.w); A[7] += bfhi(Q.w);

// ---------------- zero fill ----------------
__global__ __launch_bounds__(256) void zero_f4(float4* __restrict__ p, int n4) {
    int i = blockIdx.x * 256 + threadIdx.x;
    if (i < n4) p[i] = make_float4(0.f, 0.f, 0.f, 0.f);
}

// ---------------- fp32 -> bf16 cast ----------------
__global__ __launch_bounds__(256) void cast_bf16(const float* __restrict__ x,
                                                 u16* __restrict__ y, int n4) {
    int i = blockIdx.x * 256 + threadIdx.x;
    if (i >= n4) return;
    float4 v = ((const float4*)x)[i];
    ((uint2*)y)[i] = make_uint2(bfpack(v.x, v.y), bfpack(v.z, v.w));
}

// ---------------- all 6 weight transposes in one launch ----------------
struct WtJobs {
    const float* W[6];
    u16* WT[6];
    int K[6], N[6];
};
__global__ __launch_bounds__(256) void transpose_cast6(WtJobs jobs) {
    int j = blockIdx.y;
    int idx = blockIdx.x * 256 + threadIdx.x;
    int K = jobs.K[j], Nn = jobs.N[j];
    if (idx >= K * Nn) return;
    int k = idx / Nn, n = idx - k * Nn;
    jobs.WT[j][(long)n * K + k] = bfr(jobs.W[j][idx]);
}

// ---------------- CSR build ----------------
__global__ __launch_bounds__(256) void count_deg(const int* __restrict__ dst,
                                                 int* __restrict__ deg, int E) {
    int e = blockIdx.x * 256 + threadIdx.x;
    if (e < E) atomicAdd(&deg[dst[e]], 1);
}

__global__ __launch_bounds__(256) void partial_sums(const int* __restrict__ deg,
                                                    int* __restrict__ partials, int N) {
    __shared__ int lds[4];
    int tid = threadIdx.x;
    int base = blockIdx.x * 1024 + tid * 4;
    int s = 0;
    if (base + 3 < N) {
        int4 v = *(const int4*)(deg + base);
        s = v.x + v.y + v.z + v.w;
    } else {
        for (int i = 0; i < 4; ++i)
            if (base + i < N) s += deg[base + i];
    }
#pragma unroll
    for (int m = 32; m >= 1; m >>= 1) s += __shfl_xor(s, m);
    if ((tid & 63) == 0) lds[tid >> 6] = s;
    __syncthreads();
    if (tid == 0) partials[blockIdx.x] = lds[0] + lds[1] + lds[2] + lds[3];
}

__global__ __launch_bounds__(256) void scan_partials(int* __restrict__ partials, int nb) {
    __shared__ int lds[256];
    int tid = threadIdx.x;
    int v = (tid < nb) ? partials[tid] : 0;
    lds[tid] = v;
    __syncthreads();
    for (int off = 1; off < 256; off <<= 1) {
        int t = (tid >= off) ? lds[tid - off] : 0;
        __syncthreads();
        lds[tid] += t;
        __syncthreads();
    }
    if (tid < nb) partials[tid] = lds[tid] - v;
}

__global__ __launch_bounds__(256) void write_rowptr(const int* __restrict__ deg,
                                                    const int* __restrict__ partials,
                                                    int* __restrict__ rowptr,
                                                    int* __restrict__ cursor,
                                                    float* __restrict__ inv, int N, int E) {
    __shared__ int lds[256];
    int tid = threadIdx.x;
    int base = blockIdx.x * 1024 + tid * 4;
    int d[4];
    int s = 0;
#pragma unroll
    for (int i = 0; i < 4; ++i) {
        d[i] = (base + i < N) ? deg[base + i] : 0;
        s += d[i];
    }
    lds[tid] = s;
    __syncthreads();
    for (int off = 1; off < 256; off <<= 1) {
        int t = (tid >= off) ? lds[tid - off] : 0;
        __syncthreads();
        lds[tid] += t;
        __syncthreads();
    }
    int run = partials[blockIdx.x] + lds[tid] - s;
#pragma unroll
    for (int i = 0; i < 4; ++i) {
        int idx = base + i;
        if (idx < N) {
            rowptr[idx] = run;
            cursor[idx] = run;
            inv[idx] = 1.0f / fmaxf((float)d[i], 1.0f);
            run += d[i];
        }
    }
    if (blockIdx.x == 0 && tid == 0) rowptr[N] = E;
}

// one dst-range bucket per launch: eidx write window stays L2-resident.
__global__ __launch_bounds__(256) void fill_csr_range(const int* __restrict__ src,
                                                      const int* __restrict__ dst,
                                                      int* __restrict__ cursor,
                                                      int* __restrict__ eidx, int E,
                                                      int lo, int bs) {
    int e = blockIdx.x * 256 + threadIdx.x;
    if (e >= E) return;
    int d = dst[e];
    if ((unsigned)(d - lo) < (unsigned)bs) {
        int p = atomicAdd(&cursor[d], 1);
        eidx[p] = src[e];
    }
}

// ---------------- gathers: 16B/lane, multi-edge in flight ----------------
// D=256: wave/row, 2 half-waves x 2-unroll = 4 edges in flight.
__global__ __launch_bounds__(256) void gather_scale256(const u16* __restrict__ x,
                                                       const int* __restrict__ rowptr,
                                                       const int* __restrict__ eidx,
                                                       const float* __restrict__ inv,
                                                       u16* __restrict__ agg, int N) {
    int wave = threadIdx.x >> 6;
    int lane = threadIdx.x & 63;
    int half = lane >> 5;
    int sub = lane & 31;
    int row = blockIdx.x * 4 + wave;
    if (row >= N) return;
    int beg = rowptr[row], end = rowptr[row + 1];
    float a[8] = {}, b[8] = {};
    int j = beg + half;
    for (; j + 2 < end; j += 4) {
        uint4 q0 = *(const uint4*)(x + (long)eidx[j] * 256 + sub * 8);
        uint4 q1 = *(const uint4*)(x + (long)eidx[j + 2] * 256 + sub * 8);
        ACC8(a, q0);
        ACC8(b, q1);
    }
    if (j < end) {
        uint4 q = *(const uint4*)(x + (long)eidx[j] * 256 + sub * 8);
        ACC8(a, q);
    }
#pragma unroll
    for (int i = 0; i < 8; ++i) {
        a[i] += b[i];
        a[i] += __shfl_xor(a[i], 32);
    }
    if (half == 0) {
        float s = inv[row];
        uint4 o;
        o.x = bfpack(a[0] * s, a[1] * s);
        o.y = bfpack(a[2] * s, a[3] * s);
        o.z = bfpack(a[4] * s, a[5] * s);
        o.w = bfpack(a[6] * s, a[7] * s);
        *(uint4*)(agg + (long)row * 256 + sub * 8) = o;
    }
}

// D=128: wave/row, 4 quarter-waves x 2-unroll = 8 edges in flight.
__global__ __launch_bounds__(256) void gather_scale128(const u16* __restrict__ x,
                                                       const int* __restrict__ rowptr,
                                                       const int* __restrict__ eidx,
                                                       const float* __restrict__ inv,
                                                       u16* __restrict__ agg, int N) {
    int wave = threadIdx.x >> 6;
    int lane = threadIdx.x & 63;
    int quarter = lane >> 4;
    int sub = lane & 15;
    int row = blockIdx.x * 4 + wave;
    if (row >= N) return;
    int beg = rowptr[row], end = rowptr[row + 1];
    float a[8] = {}, b[8] = {};
    int j = beg + quarter;
    for (; j + 4 < end; j += 8) {
        uint4 q0 = *(const uint4*)(x + (long)eidx[j] * 128 + sub * 8);
        uint4 q1 = *(const uint4*)(x + (long)eidx[j + 4] * 128 + sub * 8);
        ACC8(a, q0);
        ACC8(b, q1);
    }
    if (j < end) {
        uint4 q = *(const uint4*)(x + (long)eidx[j] * 128 + sub * 8);
        ACC8(a, q);
    }
#pragma unroll
    for (int i = 0; i < 8; ++i) {
        a[i] += b[i];
        a[i] += __shfl_xor(a[i], 16);
        a[i] += __shfl_xor(a[i], 32);
    }
    if (quarter == 0) {
        float s = inv[row];
        uint4 o;
        o.x = bfpack(a[0] * s, a[1] * s);
        o.y = bfpack(a[2] * s, a[3] * s);
        o.z = bfpack(a[4] * s, a[5] * s);
        o.w = bfpack(a[6] * s, a[7] * s);
        *(uint4*)(agg + (long)row * 128 + sub * 8) = o;
    }
}

// L3 fused: h3 = relu(LN(gather_mean(y3) + r3)), D=128, wave/row, 8 edges in flight.
__global__ __launch_bounds__(256) void gather_add_ln_relu128(const u16* __restrict__ y,
                                                             const int* __restrict__ rowptr,
                                                             const int* __restrict__ eidx,
                                                             const float* __restrict__ inv,
                                                             const u16* __restrict__ r,
                                                             const float* __restrict__ g,
                                                             const float* __restrict__ be,
                                                             u16* __restrict__ out, int N) {
    int wave = threadIdx.x >> 6;
    int lane = threadIdx.x & 63;
    int quarter = lane >> 4;
    int sub = lane & 15;
    int row = blockIdx.x * 4 + wave;
    if (row >= N) return;
    int beg = rowptr[row], end = rowptr[row + 1];
    float a[8] = {}, b[8] = {};
    int j = beg + quarter;
    for (; j + 4 < end; j += 8) {
        uint4 q0 = *(const uint4*)(y + (long)eidx[j] * 128 + sub * 8);
        uint4 q1 = *(const uint4*)(y + (long)eidx[j + 4] * 128 + sub * 8);
        ACC8(a, q0);
        ACC8(b, q1);
    }
    if (j < end) {
        uint4 q = *(const uint4*)(y + (long)eidx[j] * 128 + sub * 8);
        ACC8(a, q);
    }
#pragma unroll
    for (int i = 0; i < 8; ++i) {
        a[i] += b[i];
        a[i] += __shfl_xor(a[i], 16);
        a[i] += __shfl_xor(a[i], 32);
    }
    float iv = inv[row];
    uint4 rr = *(const uint4*)(r + (long)row * 128 + sub * 8);
    float v[8];
    v[0] = a[0] * iv + bflo(rr.x); v[1] = a[1] * iv + bfhi(rr.x);
    v[2] = a[2] * iv + bflo(rr.y); v[3] = a[3] * iv + bfhi(rr.y);
    v[4] = a[4] * iv + bflo(rr.z); v[5] = a[5] * iv + bfhi(rr.z);
    v[6] = a[6] * iv + bflo(rr.w); v[7] = a[7] * iv + bfhi(rr.w);
    float s = 0.f, ss = 0.f;
#pragma unroll
    for (int i = 0; i < 8; ++i) { s += v[i]; ss += v[i] * v[i]; }
#pragma unroll
    for (int m = 8; m >= 1; m >>= 1) {  // reduce over 16-lane sub-group
        s += __shfl_xor(s, m);
        ss += __shfl_xor(ss, m);
    }
    float mean = s / 128.f;
    float var = ss / 128.f - mean * mean;
    float rs = rsqrtf(var + EPS);
    if (quarter == 0) {
        int col = sub * 8;
        float4 g0 = *(const float4*)&g[col];
        float4 g1 = *(const float4*)&g[col + 4];
        float4 e0 = *(const float4*)&be[col];
        float4 e1 = *(const float4*)&be[col + 4];
        float o0 = fmaxf((v[0] - mean) * rs * g0.x + e0.x, 0.f);
        float o1 = fmaxf((v[1] - mean) * rs * g0.y + e0.y, 0.f);
        float o2 = fmaxf((v[2] - mean) * rs * g0.z + e0.z, 0.f);
        float o3 = fmaxf((v[3] - mean) * rs * g0.w + e0.w, 0.f);
        float o4 = fmaxf((v[4] - mean) * rs * g1.x + e1.x, 0.f);
        float o5 = fmaxf((v[5] - mean) * rs * g1.y + e1.y, 0.f);
        float o6 = fmaxf((v[6] - mean) * rs * g1.z + e1.z, 0.f);
        float o7 = fmaxf((v[7] - mean) * rs * g1.w + e1.w, 0.f);
        uint4 o;
        o.x = bfpack(o0, o1);
        o.y = bfpack(o2, o3);
        o.z = bfpack(o4, o5);
        o.w = bfpack(o6, o7);
        *(uint4*)(out + (long)row * 128 + sub * 8) = o;
    }
}

// final: out = gather_sum(y)*inv + r, y bf16, out fp32
__global__ __launch_bounds__(256) void gather9_final(const u16* __restrict__ y,
                                                     const int* __restrict__ rowptr,
                                                     const int* __restrict__ eidx,
                                                     const float* __restrict__ inv,
                                                     const float* __restrict__ r,
                                                     float* __restrict__ out, int N) {
    int idx = blockIdx.x * 256 + threadIdx.x;
    int row = idx >> 4;
    int c = idx & 15;
    if (row >= N || c >= 9) return;
    int beg = rowptr[row], end = rowptr[row + 1];
    float a = 0.f;
    for (int j = beg; j < end; ++j) a += bf2f(y[(long)eidx[j] * 9 + c]);
    out[(long)row * 9 + c] = a * inv[row] + r[(long)row * 9 + c];
}

// ---------------- wide MFMA GEMM + fused bias+LN+ReLU epilogue ----------------
__global__ __launch_bounds__(256) void mfma_gemm_wide_ln(const u16* A1,
                                                         const u16* __restrict__ A2,
                                                         const u16* __restrict__ WT1,
                                                         const u16* __restrict__ WT2,
                                                         const float* __restrict__ bias,
                                                         const float* __restrict__ g,
                                                         const float* __restrict__ be,
                                                         u16* out, int M, int K) {
    __shared__ __align__(16) u16 smem[64 * 260];
    u16* As = smem;
    u16* Ws = smem + 64 * 40;
    const int tid = threadIdx.x;
    const int bm = blockIdx.x * 64;
    const int l = tid & 63;
    const int w = tid >> 6;
    const int wr = (w & 1) * 32;
    const int wc = (w >> 1) * 128;
    const int ln15 = l & 15;
    const int quad = l >> 4;

    f32x4_t acc[2][8];
#pragma unroll
    for (int i = 0; i < 2; ++i)
#pragma unroll
        for (int j = 0; j < 8; ++j) acc[i][j] = (f32x4_t){0.f, 0.f, 0.f, 0.f};

    const int ar = tid >> 2;
    const int akh = (tid & 3) * 8;

    for (int pass = 0; pass < 2; ++pass) {
        const u16* A = pass ? A2 : A1;
        const u16* WT = pass ? WT2 : WT1;
        for (int k0 = 0; k0 < K; k0 += 32) {
            uint4 q0 = make_uint4(0, 0, 0, 0);
            int gr = bm + ar;
            if (gr < M) q0 = *(const uint4*)(A + (long)gr * K + k0 + akh);
            *(uint4*)(As + ar * 40 + akh) = q0;
            const u16* wp = WT + (long)tid * K + k0;
            *(uint4*)(Ws + tid * 40 + 0) = ((const uint4*)wp)[0];
            *(uint4*)(Ws + tid * 40 + 8) = ((const uint4*)wp)[1];
            *(uint4*)(Ws + tid * 40 + 16) = ((const uint4*)wp)[2];
            *(uint4*)(Ws + tid * 40 + 24) = ((const uint4*)wp)[3];
            __syncthreads();

            bf16x8_t a[2], b[8];
#pragma unroll
            for (int i = 0; i < 2; ++i)
                a[i] = *(const bf16x8_t*)(As + (wr + i * 16 + ln15) * 40 + quad * 8);
#pragma unroll
            for (int j = 0; j < 8; ++j)
                b[j] = *(const bf16x8_t*)(Ws + (wc + j * 16 + ln15) * 40 + quad * 8);
#pragma unroll
            for (int i = 0; i < 2; ++i)
#pragma unroll
                for (int j = 0; j < 8; ++j)
                    acc[i][j] = __builtin_amdgcn_mfma_f32_16x16x32_bf16(a[i], b[j], acc[i][j], 0, 0, 0);
            __syncthreads();
        }
    }

#pragma unroll
    for (int j = 0; j < 8; ++j) {
        int col = wc + j * 16 + ln15;
        float bv = bias[col];
#pragma unroll
        for (int i = 0; i < 2; ++i) {
            int row0 = wr + i * 16 + quad * 4;
            f32x4_t c = acc[i][j];
#pragma unroll
            for (int p = 0; p < 4; ++p) smem[(row0 + p) * 260 + col] = bfr(c[p] + bv);
        }
    }
    __syncthreads();

    float4 g4 = *(const float4*)&g[l * 4];
    float4 be4 = *(const float4*)&be[l * 4];
    for (int rr = 0; rr < 16; ++rr) {
        int lrow = w * 16 + rr;
        int grow = bm + lrow;
        if (grow >= M) break;
        ushort4 ld = *(const ushort4*)(smem + lrow * 260 + l * 4);
        float v0 = bf2f(ld.x), v1 = bf2f(ld.y), v2 = bf2f(ld.z), v3 = bf2f(ld.w);
        float s = v0 + v1 + v2 + v3;
        float ss = v0 * v0 + v1 * v1 + v2 * v2 + v3 * v3;
#pragma unroll
        for (int m = 32; m >= 1; m >>= 1) {
            s += __shfl_xor(s, m);
            ss += __shfl_xor(ss, m);
        }
        float mean = s / 256.f;
        float var = ss / 256.f - mean * mean;
        float rs = rsqrtf(var + EPS);
        v0 = fmaxf((v0 - mean) * rs * g4.x + be4.x, 0.f);
        v1 = fmaxf((v1 - mean) * rs * g4.y + be4.y, 0.f);
        v2 = fmaxf((v2 - mean) * rs * g4.z + be4.z, 0.f);
        v3 = fmaxf((v3 - mean) * rs * g4.w + be4.w, 0.f);
        ((uint2*)out)[(long)grow * 64 + l] = make_uint2(bfpack(v0, v1), bfpack(v2, v3));
    }
}

// ---------------- L3 dual GEMM: ya = A@WTa, yb = A@WTb + bias ----------------
__global__ __launch_bounds__(256) void mfma_gemm_dual(const u16* __restrict__ A,
                                                      const u16* __restrict__ WTa,
                                                      const u16* __restrict__ WTb,
                                                      const float* __restrict__ biasb,
                                                      u16* __restrict__ outa,
                                                      u16* __restrict__ outb, int M, int K) {
    __shared__ u16 As[128 * 40];
    __shared__ u16 Ws[128 * 40];
    const u16* WT = blockIdx.y ? WTb : WTa;
    u16* out = blockIdx.y ? outb : outa;
    const float* bias = blockIdx.y ? biasb : nullptr;
    const int tid = threadIdx.x;
    const int bm = blockIdx.x * 128;
    const int l = tid & 63;
    const int w = tid >> 6;
    const int wr = (w & 1) * 64;
    const int wc = (w >> 1) * 64;
    const int ln15 = l & 15;
    const int quad = l >> 4;

    f32x4_t acc[4][4];
#pragma unroll
    for (int i = 0; i < 4; ++i)
#pragma unroll
        for (int j = 0; j < 4; ++j) acc[i][j] = (f32x4_t){0.f, 0.f, 0.f, 0.f};

    const int sr = tid >> 1;
    const int kh = (tid & 1) * 16;

    for (int k0 = 0; k0 < K; k0 += 32) {
        uint4 q0 = make_uint4(0, 0, 0, 0), q1 = make_uint4(0, 0, 0, 0);
        int gr = bm + sr;
        if (gr < M) {
            const u16* ap = A + (long)gr * K + k0 + kh;
            q0 = ((const uint4*)ap)[0];
            q1 = ((const uint4*)ap)[1];
        }
        *(uint4*)(As + sr * 40 + kh) = q0;
        *(uint4*)(As + sr * 40 + kh + 8) = q1;
        const u16* wp = WT + (long)sr * K + k0 + kh;
        *(uint4*)(Ws + sr * 40 + kh) = ((const uint4*)wp)[0];
        *(uint4*)(Ws + sr * 40 + kh + 8) = ((const uint4*)wp)[1];
        __syncthreads();

        bf16x8_t a[4], b[4];
#pragma unroll
        for (int i = 0; i < 4; ++i)
            a[i] = *(const bf16x8_t*)(As + (wr + i * 16 + ln15) * 40 + quad * 8);
#pragma unroll
        for (int j = 0; j < 4; ++j)
            b[j] = *(const bf16x8_t*)(Ws + (wc + j * 16 + ln15) * 40 + quad * 8);
#pragma unroll
        for (int i = 0; i < 4; ++i)
#pragma unroll
            for (int j = 0; j < 4; ++j)
                acc[i][j] = __builtin_amdgcn_mfma_f32_16x16x32_bf16(a[i], b[j], acc[i][j], 0, 0, 0);
        __syncthreads();
    }

#pragma unroll
    for (int j = 0; j < 4; ++j) {
        int col = wc + j * 16 + ln15;
        float bv = bias ? bias[col] : 0.f;
#pragma unroll
        for (int i = 0; i < 4; ++i) {
            int row0 = bm + wr + i * 16 + quad * 4;
            f32x4_t c = acc[i][j];
#pragma unroll
            for (int p = 0; p < 4; ++p) {
                int row = row0 + p;
                if (row < M) out[(long)row * 128 + col] = bfr(c[p] + bv);
            }
        }
    }
}

// ---------------- layer 4 small GEMM ----------------
__global__ __launch_bounds__(320) void gemm4_bf(const u16* __restrict__ x,
                                                const float* __restrict__ wm,
                                                const float* __restrict__ wrt,
                                                const float* __restrict__ b,
                                                u16* __restrict__ y, float* __restrict__ r,
                                                int M) {
    __shared__ float xs[16][132];
    __shared__ float ws[128][20];
    int tid = threadIdx.x;
    int m0 = blockIdx.x * 16;
    for (int idx = tid; idx < 16 * 128; idx += 320) {
        int rr = idx >> 7, kk = idx & 127;
        int gm = m0 + rr;
        xs[rr][kk] = (gm < M) ? bf2f(x[(long)gm * 128 + kk]) : 0.f;
    }
    for (int idx = tid; idx < 128 * 18; idx += 320) {
        int kk = idx / 18, cc = idx % 18;
        ws[kk][cc] = (cc < 9) ? wm[kk * 9 + cc] : wrt[kk * 9 + cc - 9];
    }
    __syncthreads();
    if (tid < 288) {
        int rr = tid / 18, cc = tid % 18;
        float acc = 0.f;
#pragma unroll 8
        for (int kk = 0; kk < 128; ++kk) acc += xs[rr][kk] * ws[kk][cc];
        int gm = m0 + rr;
        if (gm < M) {
            if (cc < 9) y[(long)gm * 9 + cc] = bfr(acc);
            else r[(long)gm * 9 + cc - 9] = acc + b[cc - 9];
        }
    }
}

static inline int cdiv(long a, long b) { return (int)((a + b - 1) / b); }

extern "C" void kernel_launch(void* const* d_in, const int* in_sizes, int n_in,
                              void* d_out, int out_size, void* d_ws, size_t ws_size,
                              hipStream_t stream) {
    const int N = in_sizes[0] / 128;
    const int E = in_sizes[1] / 2;

    const float* z = (const float*)d_in[0];
    const int* ei = (const int*)d_in[1];
    const int* src = ei;
    const int* dstp = ei + E;
    const float* wm1 = (const float*)d_in[2];
    const float* wr1 = (const float*)d_in[3];
    const float* b1 = (const float*)d_in[4];
    const float* g1 = (const float*)d_in[5];
    const float* be1 = (const float*)d_in[6];
    const float* wm2 = (const float*)d_in[7];
    const float* wr2 = (const float*)d_in[8];
    const float* b2 = (const float*)d_in[9];
    const float* g2 = (const float*)d_in[10];
    const float* be2 = (const float*)d_in[11];
    const float* wm3 = (const float*)d_in[12];
    const float* wr3 = (const float*)d_in[13];
    const float* b3 = (const float*)d_in[14];
    const float* g3 = (const float*)d_in[15];
    const float* be3 = (const float*)d_in[16];
    const float* wm4 = (const float*)d_in[17];
    const float* wr4 = (const float*)d_in[18];
    const float* b4 = (const float*)d_in[19];
    float* out = (float*)d_out;

    // ws layout:
    u16* aggh2 = (u16*)d_ws;                     // N*256
    u16* h1b = aggh2 + (size_t)N * 256;          // N*256
    u16* zb = h1b + (size_t)N * 256;             // N*128
    u16* agg1 = zb + (size_t)N * 128;            // N*128
    float* inv = (float*)(agg1 + (size_t)N * 128);
    int* deg = (int*)(inv + N);
    int* rowptr = deg + N + 4;
    int* cursor = rowptr + N + 4;
    int* partials = cursor + N + 4;
    int* eidx = partials + 256;
    u16* wt1m = (u16*)(eidx + E);
    u16* wt1r = wt1m + 256 * 128;
    u16* wt2m = wt1r + 256 * 128;
    u16* wt2r = wt2m + 256 * 256;
    u16* wt3m = wt2r + 256 * 256;
    u16* wt3r = wt3m + 128 * 256;

    // aliases (liveness-checked):
    u16* y3b = agg1;
    u16* r3b = zb;
    u16* h3b = h1b;
    u16* y4 = aggh2;
    float* r4 = (float*)(aggh2 + (size_t)N * 16);

    const int nscan = cdiv(N, 1024);

    // ---- prep ----
    cast_bf16<<<cdiv((long)N * 32, 256), 256, 0, stream>>>(z, zb, N * 32);
    zero_f4<<<cdiv(N, 1024), 256, 0, stream>>>((float4*)deg, cdiv(N, 4));
    count_deg<<<cdiv(E, 256), 256, 0, stream>>>(dstp, deg, E);
    partial_sums<<<nscan, 256, 0, stream>>>(deg, partials, N);
    scan_partials<<<1, 256, 0, stream>>>(partials, nscan);
    write_rowptr<<<nscan, 256, 0, stream>>>(deg, partials, rowptr, cursor, inv, N, E);
    {
        const int P = 4;
        int bs = cdiv(N, P);
        for (int b = 0; b < P; ++b)
            fill_csr_range<<<cdiv(E, 256), 256, 0, stream>>>(src, dstp, cursor, eidx, E,
                                                             b * bs, bs);
    }
    {
        WtJobs jobs;
        jobs.W[0] = wm1; jobs.WT[0] = wt1m; jobs.K[0] = 128; jobs.N[0] = 256;
        jobs.W[1] = wr1; jobs.WT[1] = wt1r; jobs.K[1] = 128; jobs.N[1] = 256;
        jobs.W[2] = wm2; jobs.WT[2] = wt2m; jobs.K[2] = 256; jobs.N[2] = 256;
        jobs.W[3] = wr2; jobs.WT[3] = wt2r; jobs.K[3] = 256; jobs.N[3] = 256;
        jobs.W[4] = wm3; jobs.WT[4] = wt3m; jobs.K[4] = 256; jobs.N[4] = 128;
        jobs.W[5] = wr3; jobs.WT[5] = wt3r; jobs.K[5] = 256; jobs.N[5] = 128;
        dim3 g(256, 6);
        transpose_cast6<<<g, 256, 0, stream>>>(jobs);
    }

    // ---- layer 1 ----
    gather_scale128<<<cdiv(N, 4), 256, 0, stream>>>(zb, rowptr, eidx, inv, agg1, N);
    mfma_gemm_wide_ln<<<cdiv(N, 64), 256, 0, stream>>>(agg1, zb, wt1m, wt1r, b1, g1, be1,
                                                       h1b, N, 128);

    // ---- layer 2 ----
    gather_scale256<<<cdiv(N, 4), 256, 0, stream>>>(h1b, rowptr, eidx, inv, aggh2, N);
    mfma_gemm_wide_ln<<<cdiv(N, 64), 256, 0, stream>>>(aggh2, h1b, wt2m, wt2r, b2, g2, be2,
                                                       aggh2, N, 256);

    // ---- layer 3 ----
    {
        dim3 g(cdiv(N, 128), 2);
        mfma_gemm_dual<<<g, 256, 0, stream>>>(aggh2, wt3m, wt3r, b3, y3b, r3b, N, 256);
    }
    gather_add_ln_relu128<<<cdiv(N, 4), 256, 0, stream>>>(y3b, rowptr, eidx, inv, r3b, g3,
                                                          be3, h3b, N);

    // ---- layer 4 ----
    gemm4_bf<<<cdiv(N, 16), 320, 0, stream>>>(h3b, wm4, wr4, b4, y4, r4, N);
    gather9_final<<<cdiv((long)N * 16, 256), 256, 0, stream>>>(y4, rowptr, eidx, inv, r4, out, N);
}